// Round 8
// baseline (767.129 us; speedup 1.0000x reference)
//
#include <hip/hip_runtime.h>
#include <hip/hip_bf16.h>
#include <hip/hip_fp16.h>
#include <cstdint>

// ---------------------------------------------------------------------------
// LinearAttention (random-feature cos kernel + softmax attention), MI355X.
// out = softmax(cos(q@Wq@Wr + br) @ cos(v@Wk@Wr + br)^T) @ (v@Wv + bv)
// B=4, S=4096, D=U=F=1024.  All heavy math in fp16 MFMA with fp32 accum.
// probs GEMM: 256x256 tile / 8 waves / BK=32 dbuf / counted vmcnt.
// Other GEMMs: 128x128 tile 2-phase (round-7 structure).
// Softmax: tile-local max in QK^T epilogue + alpha/l folded into PV.
// ---------------------------------------------------------------------------

typedef _Float16 f16;
typedef _Float16 f16x8 __attribute__((ext_vector_type(8)));
typedef _Float16 f16x4 __attribute__((ext_vector_type(4)));
typedef float f32x4 __attribute__((ext_vector_type(4)));

typedef __attribute__((address_space(1))) unsigned int uas1;
typedef __attribute__((address_space(3))) unsigned int uas3;

#define NB 4
#define SEQ 4096
#define DIM 1024

// async 16B/lane global->LDS. LDS dest must be wave-uniform base (+lane*16).
__device__ __forceinline__ void async_copy16(void* lds, const void* g) {
  __builtin_amdgcn_global_load_lds((uas1*)(uintptr_t)g, (uas3*)(uintptr_t)lds,
                                   16, 0, 0);
}

// ----------------------------- small kernels ------------------------------

__global__ __launch_bounds__(256) void f2h(const float* __restrict__ in,
                                           f16* __restrict__ out, int n4) {
  int i = blockIdx.x * 256 + threadIdx.x;
  if (i < n4) {
    float4 v = ((const float4*)in)[i];
    f16x4 h = {(f16)v.x, (f16)v.y, (f16)v.z, (f16)v.w};
    ((f16x4*)out)[i] = h;
  }
}

__global__ __launch_bounds__(256) void f2h_split(const float* __restrict__ in,
                                                 f16* __restrict__ hi,
                                                 f16* __restrict__ lo, int n4) {
  int i = blockIdx.x * 256 + threadIdx.x;
  if (i < n4) {
    float4 v = ((const float4*)in)[i];
    f16 h0 = (f16)v.x, h1 = (f16)v.y, h2 = (f16)v.z, h3 = (f16)v.w;
    f16x4 hv = {h0, h1, h2, h3};
    f16x4 lv = {(f16)(v.x - (float)h0), (f16)(v.y - (float)h1),
                (f16)(v.z - (float)h2), (f16)(v.w - (float)h3)};
    ((f16x4*)hi)[i] = hv;
    ((f16x4*)lo)[i] = lv;
  }
}

__global__ void tr_h(const f16* __restrict__ in, f16* __restrict__ out, int R,
                     int C) {
  __shared__ f16 tile[32][33];
  int c0 = blockIdx.x * 32, r0 = blockIdx.y * 32;
  tile[threadIdx.y][threadIdx.x] =
      in[(long)(r0 + threadIdx.y) * C + c0 + threadIdx.x];
  __syncthreads();
  out[(long)(c0 + threadIdx.y) * R + r0 + threadIdx.x] =
      tile[threadIdx.x][threadIdx.y];
}

// bias_eff[f] = br[f] + sum_u bvec[u] * Wr[u][f]   (fp32 exact)
__global__ __launch_bounds__(256) void bias_fold(const float* __restrict__ br,
                                                 const float* __restrict__ bvec,
                                                 const float* __restrict__ Wr,
                                                 float* __restrict__ outb) {
  int f = blockIdx.x * 256 + threadIdx.x;
  float s = br[f];
  for (int u = 0; u < DIM; ++u) s = fmaf(bvec[u], Wr[(long)u * DIM + f], s);
  outb[f] = s;
}

// per (z2,row): m = max_t m_t; l = sum_t l_t exp(m_t-m);
// scl[t][row] = exp(m_t-m)/l  (f16).  16 tiles of 256 cols.
__global__ __launch_bounds__(256) void merge_pair(const float* __restrict__ ml,
                                                  const float* __restrict__ ll,
                                                  f16* __restrict__ scl) {
  int i = blockIdx.x * 256 + threadIdx.x;  // 0..8191 = z2*4096 + row
  int z2 = i >> 12, row = i & 4095;
  const float* m = ml + z2 * 65536 + row;
  const float* lp = ll + z2 * 65536 + row;
  float a[16];
  float mg = -1e30f;
#pragma unroll 16
  for (int t = 0; t < 16; ++t) mg = fmaxf(mg, m[t * 4096]);
  float l = 0.f;
#pragma unroll 16
  for (int t = 0; t < 16; ++t) {
    a[t] = __expf(m[t * 4096] - mg);
    l += lp[t * 4096] * a[t];
  }
  float li = 1.0f / l;
#pragma unroll 16
  for (int t = 0; t < 16; ++t)
    scl[z2 * 65536 + t * 4096 + row] = (f16)(a[t] * li);
}

__global__ void sentinel(float* out) { out[0] = 12345.0f; }

// ----------------- probs GEMM: 256x256 tile, 8 waves, BK=32 -----------------
// P[z,row,col] = exp(S - rowmax_tile), S = A@B^T (M=N=4096, K=1024).
// Writes mout/lout per (z, tn, row);  column tiles are 256 wide (16 tiles).
__global__ __launch_bounds__(512, 2) void qk_softmax256(
    const f16* __restrict__ A, const f16* __restrict__ B, f16* __restrict__ P,
    float* __restrict__ mout, float* __restrict__ lout, long sA, long sB,
    long sP) {
  constexpr int LD = 1024, LDC = 4096, K = 1024;
  constexpr int TILE_B = 256 * 32 * 2;  // 16 KB per operand tile
  __shared__ __align__(16) char smem[2 * 2 * TILE_B];  // dbuf x (A,B)
  __shared__ float red[4][256];
  const int z = blockIdx.z, tn = blockIdx.x, tm = blockIdx.y;
  const int t = threadIdx.x, w = t >> 6, l = t & 63;
  const int l4 = l >> 4, l15 = l & 15;
  const int wm = w & 1, wn = w >> 1;  // 2 x 4 wave grid; wave = 128x64 out
  f32x4 acc[8][4] = {};
  const f16* Az = A + (long)z * sA;
  const f16* Bz = B + (long)z * sB;

  auto STAGE = [&](int buf, int kk) {
    char* base = smem + buf * (2 * TILE_B);
#pragma unroll
    for (int j = 0; j < 2; ++j) {
      const int cb = j * 512 + w * 64;  // wave-uniform chunk base
      const int c = cb + l;             // 16B chunk id, 1024 per operand
      const int r = c >> 2, pp = c & 3;
      const int sc = pp ^ ((r >> 1) & 3);  // bank-spread swizzle
      async_copy16(base + cb * 16, Az + (long)(tm * 256 + r) * LD + kk + sc * 8);
      async_copy16(base + TILE_B + cb * 16,
                   Bz + (long)(tn * 256 + r) * LD + kk + sc * 8);
    }
  };

  STAGE(0, 0);
  asm volatile("s_waitcnt vmcnt(0)" ::: "memory");
  __syncthreads();
  int cur = 0;
  for (int tt = 0; tt < K / 32; ++tt) {
    if (tt + 1 < K / 32) {
      STAGE(cur ^ 1, (tt + 1) * 32);
      asm volatile("s_waitcnt vmcnt(4)" ::: "memory");
    } else {
      asm volatile("s_waitcnt vmcnt(0)" ::: "memory");
    }
    __syncthreads();
    const f16* As = (const f16*)(smem + cur * (2 * TILE_B));
    const f16* Bs = (const f16*)((const char*)As + TILE_B);
    f16x8 af[8], bf[4];
#pragma unroll
    for (int i = 0; i < 8; ++i) {
      const int ra = wm * 128 + i * 16 + l15;
      af[i] = *(const f16x8*)&As[ra * 32 + (l4 ^ ((ra >> 1) & 3)) * 8];
    }
#pragma unroll
    for (int jn = 0; jn < 4; ++jn) {
      const int rb = wn * 64 + jn * 16 + l15;
      bf[jn] = *(const f16x8*)&Bs[rb * 32 + (l4 ^ ((rb >> 1) & 3)) * 8];
    }
#pragma unroll
    for (int i = 0; i < 8; ++i)
#pragma unroll
      for (int jn = 0; jn < 4; ++jn)
        acc[i][jn] = __builtin_amdgcn_mfma_f32_16x16x32_f16(af[i], bf[jn],
                                                            acc[i][jn], 0, 0, 0);
    __syncthreads();
    cur ^= 1;
  }

  // ---- tile-local softmax over this 256-col tile ----
  float mrow[32];
#pragma unroll
  for (int i = 0; i < 8; ++i)
#pragma unroll
    for (int r = 0; r < 4; ++r) {
      float v = fmaxf(fmaxf(acc[i][0][r], acc[i][1][r]),
                      fmaxf(acc[i][2][r], acc[i][3][r]));
      v = fmaxf(v, __shfl_xor(v, 1));
      v = fmaxf(v, __shfl_xor(v, 2));
      v = fmaxf(v, __shfl_xor(v, 4));
      v = fmaxf(v, __shfl_xor(v, 8));
      if (l15 == 0) red[wn][wm * 128 + i * 16 + l4 * 4 + r] = v;
    }
  __syncthreads();
#pragma unroll
  for (int i = 0; i < 8; ++i)
#pragma unroll
    for (int r = 0; r < 4; ++r) {
      const int rin = wm * 128 + i * 16 + l4 * 4 + r;
      mrow[i * 4 + r] = fmaxf(fmaxf(red[0][rin], red[1][rin]),
                              fmaxf(red[2][rin], red[3][rin]));
    }
  __syncthreads();
#pragma unroll
  for (int i = 0; i < 8; ++i)
#pragma unroll
    for (int r = 0; r < 4; ++r) {
      const float mn = mrow[i * 4 + r];
      float s = 0.f;
#pragma unroll
      for (int jn = 0; jn < 4; ++jn) {
        float e = __expf(acc[i][jn][r] - mn);
        acc[i][jn][r] = e;
        s += e;
      }
      s += __shfl_xor(s, 1);
      s += __shfl_xor(s, 2);
      s += __shfl_xor(s, 4);
      s += __shfl_xor(s, 8);
      if (l15 == 0) red[wn][wm * 128 + i * 16 + l4 * 4 + r] = s;
    }
  __syncthreads();
  if (wn == 0 && l15 == 0) {
#pragma unroll
    for (int i = 0; i < 8; ++i)
#pragma unroll
      for (int r = 0; r < 4; ++r) {
        const int rin = wm * 128 + i * 16 + l4 * 4 + r;
        const int gidx = z * 65536 + tn * 4096 + tm * 256 + rin;
        mout[gidx] = mrow[i * 4 + r];
        lout[gidx] = red[0][rin] + red[1][rin] + red[2][rin] + red[3][rin];
      }
  }
  // ---- write unnormalized probs (f16) ----
#pragma unroll
  for (int i = 0; i < 8; ++i) {
    const int row0 = tm * 256 + wm * 128 + i * 16 + l4 * 4;
#pragma unroll
    for (int jn = 0; jn < 4; ++jn) {
      const int col = tn * 256 + wn * 64 + jn * 16 + l15;
#pragma unroll
      for (int r = 0; r < 4; ++r)
        P[(long)z * sP + (long)(row0 + r) * LDC + col] = (f16)acc[i][jn][r];
    }
  }
}

// ------------------------------- main GEMM --------------------------------
// C[M,N] = epilogue( A@B^T [+ A@Bl^T if DB] [+ Al@B^T if DA] )
// B stored row-major [N,K].  128x128 tile, 4 waves, 4x4 16x16x32 frags/wave.
// Double-buffered LDS, 2-phase pipeline, counted vmcnt (never 0 in loop).
// EPI: 1 f16 __cosf(v+aux[col]) | 2 f16 v+aux[row] | 5 f32 plain
//      7 f32 plain, A-fragments scaled by ascl[ktile256][arow] (LDS-staged)
template <int EPI, bool DA, bool DB, int BK>
__global__ __launch_bounds__(256) void gemm_bt(
    const f16* __restrict__ Ah, const f16* __restrict__ Al,
    const f16* __restrict__ Bh, const f16* __restrict__ Bl,
    void* __restrict__ Cv, const float* __restrict__ aux,
    const f16* __restrict__ ascl, long sAscl, int M, int N, int K, int lda,
    int ldb, int ldc, long sC, long sA, long sB, int sAux) {
  constexpr int NSTAGE = 2 + (DA ? 1 : 0) + (DB ? 1 : 0);
  constexpr int TILE = 128 * BK * 2;    // bytes per operand tile
  constexpr int CPR = BK / 8;           // 16B chunks per row
  constexpr int CH = 128 * CPR;         // chunks per operand tile
  constexpr int NL = NSTAGE * BK / 16;  // per-thread vmem issues per tile
  static_assert(NL == 6 || NL == 8, "vmcnt literal");
  constexpr int SCLB = (EPI == 7) ? 4096 : 0;
  __shared__ __align__(16) char smem[2 * NSTAGE * TILE + SCLB];

  const int z = blockIdx.z;
  const int tn = blockIdx.x, tm = blockIdx.y;
  const int t = threadIdx.x, w = t >> 6, l = t & 63;
  const int l4 = l >> 4, l15 = l & 15;
  const int wm = w & 1, wn = w >> 1;
  f32x4 acc[4][4] = {};

  const f16* Az = Ah + (long)z * sA;
  const f16* Bz = Bh + (long)z * sB;
  const f16* Alz = nullptr;
  const f16* Blz = nullptr;
  if constexpr (DA) Alz = Al + (long)z * sA;
  if constexpr (DB) Blz = Bl + (long)z * sB;
  f16* sclLds = (f16*)(smem + 2 * NSTAGE * TILE);

  auto swz = [](int r, int p) -> int {
    if constexpr (BK == 64) return p ^ (r & 7);
    else return p ^ ((r >> 1) & 3);
  };

  auto STAGE = [&](int buf, int kk) {
    char* base = smem + buf * (NSTAGE * TILE);
#pragma unroll
    for (int j = 0; j < CH / 256; ++j) {
      const int cb = j * 256 + w * 64;  // wave-uniform chunk base
      const int c = cb + l;
      const int r = c / CPR, pp = c % CPR;
      const int sc = swz(r, pp);
      const long ra = (long)(tm * 128 + r) * lda + kk + sc * 8;
      const long rb = (long)(tn * 128 + r) * ldb + kk + sc * 8;
      async_copy16(base + cb * 16, Az + ra);
      async_copy16(base + TILE + cb * 16, Bz + rb);
      if constexpr (DA) async_copy16(base + 2 * TILE + cb * 16, Alz + ra);
      if constexpr (DB)
        async_copy16(base + (2 + (DA ? 1 : 0)) * TILE + cb * 16, Blz + rb);
    }
  };

  // ---- prologue: stage tile 0 (+ scl table for EPI 7), drain, barrier ----
  STAGE(0, 0);
  if constexpr (EPI == 7) {
    const f16* asclz = ascl + (long)z * sAscl;
    // 16 k-tiles x 128 rows f16 -> 256 chunks; LDS idx c*8 = tile*128 + row
    const int cb = w * 64;
    const int c = cb + l;
    async_copy16(sclLds + cb * 8,
                 asclz + (long)(c >> 4) * M + tm * 128 + (c & 15) * 8);
  }
  asm volatile("s_waitcnt vmcnt(0)" ::: "memory");
  __syncthreads();

  const int nt = K / BK;
  int cur = 0;
  for (int tt = 0; tt < nt; ++tt) {
    const int kk = tt * BK;
    if (tt + 1 < nt) {
      STAGE(cur ^ 1, kk + BK);
      if constexpr (NL == 6)
        asm volatile("s_waitcnt vmcnt(6)" ::: "memory");
      else
        asm volatile("s_waitcnt vmcnt(8)" ::: "memory");
    } else {
      asm volatile("s_waitcnt vmcnt(0)" ::: "memory");
    }
    __syncthreads();

    const f16* As = (const f16*)(smem + cur * (NSTAGE * TILE));
    const f16* Bs = As + TILE / 2;
    const f16* Als = Bs + TILE / 2;
    const f16* Bls = Als + (DA ? TILE / 2 : 0);

    f16 sA4[4];
    if constexpr (EPI == 7) {
      const int tile = kk >> 8;  // 256-wide k-tiles
#pragma unroll
      for (int i = 0; i < 4; ++i)
        sA4[i] = sclLds[tile * 128 + wm * 64 + i * 16 + l15];
    }

#pragma unroll
    for (int ks = 0; ks < BK / 32; ++ks) {
      f16x8 af[4], bf[4];
#pragma unroll
      for (int i = 0; i < 4; ++i) {
        const int ra = wm * 64 + i * 16 + l15;
        const int rb = wn * 64 + i * 16 + l15;
        af[i] = *(const f16x8*)&As[ra * BK + swz(ra, ks * 4 + l4) * 8];
        bf[i] = *(const f16x8*)&Bs[rb * BK + swz(rb, ks * 4 + l4) * 8];
      }
      if constexpr (EPI == 7) {
#pragma unroll
        for (int i = 0; i < 4; ++i) af[i] = af[i] * sA4[i];
      }
#pragma unroll
      for (int i = 0; i < 4; ++i)
#pragma unroll
        for (int jn = 0; jn < 4; ++jn)
          acc[i][jn] = __builtin_amdgcn_mfma_f32_16x16x32_f16(af[i], bf[jn],
                                                              acc[i][jn], 0, 0, 0);
      if constexpr (DB) {
        f16x8 bl[4];
#pragma unroll
        for (int i = 0; i < 4; ++i) {
          const int rb = wn * 64 + i * 16 + l15;
          bl[i] = *(const f16x8*)&Bls[rb * BK + swz(rb, ks * 4 + l4) * 8];
        }
#pragma unroll
        for (int i = 0; i < 4; ++i)
#pragma unroll
          for (int jn = 0; jn < 4; ++jn)
            acc[i][jn] = __builtin_amdgcn_mfma_f32_16x16x32_f16(
                af[i], bl[jn], acc[i][jn], 0, 0, 0);
      }
      if constexpr (DA) {
        f16x8 al[4];
#pragma unroll
        for (int i = 0; i < 4; ++i) {
          const int ra = wm * 64 + i * 16 + l15;
          al[i] = *(const f16x8*)&Als[ra * BK + swz(ra, ks * 4 + l4) * 8];
        }
#pragma unroll
        for (int i = 0; i < 4; ++i)
#pragma unroll
          for (int jn = 0; jn < 4; ++jn)
            acc[i][jn] = __builtin_amdgcn_mfma_f32_16x16x32_f16(
                al[i], bf[jn], acc[i][jn], 0, 0, 0);
      }
    }
    __syncthreads();
    cur ^= 1;
  }

  const float* auxp = aux + (long)z * sAux;

  if constexpr (EPI == 1 || EPI == 2) {
    // ---- f16 output via LDS repack: [64][136] per half ----
    f16* rep = (f16*)smem;
#pragma unroll
    for (int hh = 0; hh < 2; ++hh) {
      __syncthreads();
#pragma unroll
      for (int ii = 0; ii < 2; ++ii) {
        const int i = hh * 2 + ii;
        const int lrow0 = wm * 32 + ii * 16 + l4 * 4;
#pragma unroll
        for (int jn = 0; jn < 4; ++jn) {
          const int col = wn * 64 + jn * 16 + l15;
#pragma unroll
          for (int r = 0; r < 4; ++r) {
            float v = acc[i][jn][r];
            f16 hv;
            if constexpr (EPI == 1)
              hv = (f16)__cosf(v + auxp[tn * 128 + col]);
            else
              hv = (f16)(v + auxp[tm * 128 + wm * 64 + i * 16 + l4 * 4 + r]);
            rep[(lrow0 + r) * 136 + col] = hv;
          }
        }
      }
      __syncthreads();
#pragma unroll
      for (int pp = 0; pp < 4; ++pp) {
        const int lrow = pp * 16 + (t >> 4);
        const int grow = tm * 128 + (lrow >> 5) * 64 + hh * 32 + (lrow & 31);
        const int gcol = tn * 128 + (t & 15) * 8;
        *(f16x8*)&((f16*)Cv)[(long)z * sC + (long)grow * ldc + gcol] =
            *(const f16x8*)&rep[lrow * 136 + (t & 15) * 8];
      }
    }
  } else {
    // ---- f32 output via LDS repack: [32][132] per i-group ----
    float* rep = (float*)smem;
#pragma unroll
    for (int i = 0; i < 4; ++i) {
      __syncthreads();
      const int lrow0 = wm * 16 + l4 * 4;
#pragma unroll
      for (int jn = 0; jn < 4; ++jn) {
        const int col = wn * 64 + jn * 16 + l15;
#pragma unroll
        for (int r = 0; r < 4; ++r) rep[(lrow0 + r) * 132 + col] = acc[i][jn][r];
      }
      __syncthreads();
#pragma unroll
      for (int pp = 0; pp < 4; ++pp) {
        const int lrow = pp * 8 + (t >> 5);
        const int grow = tm * 128 + (lrow >> 4) * 64 + i * 16 + (lrow & 15);
        const int gcol = tn * 128 + (t & 31) * 4;
        *(float4*)&((float*)Cv)[(long)z * sC + (long)grow * ldc + gcol] =
            *(const float4*)&rep[lrow * 132 + (t & 31) * 4];
      }
    }
  }
}

// --------------------------------- driver ----------------------------------

extern "C" void kernel_launch(void* const* d_in, const int* in_sizes, int n_in,
                              void* d_out, int out_size, void* d_ws,
                              size_t ws_size, hipStream_t stream) {
  const float* query = (const float*)d_in[0];
  const float* value = (const float*)d_in[1];
  const float* Wq = (const float*)d_in[2];
  const float* bq = (const float*)d_in[3];
  const float* Wk = (const float*)d_in[4];
  const float* bk = (const float*)d_in[5];
  const float* Wv = (const float*)d_in[6];
  const float* bv = (const float*)d_in[7];
  const float* Wr = (const float*)d_in[8];
  const float* br = (const float*)d_in[9];
  float* out = (float*)d_out;

  if (ws_size < 169000000ull) {
    sentinel<<<1, 1, 0, stream>>>(out);
    return;
  }

  char* p = (char*)d_ws;
  auto alloc = [&](size_t bytes) {
    char* r = p;
    p += (bytes + 255) & ~(size_t)255;
    return r;
  };
  const size_t QV = 16777216ull;  // B*S*D elements
  const size_t WW = 1048576ull;   // 1024*1024 elements
  char* bufA = alloc(QV * 2);  // q16 -> Khat
  char* bufB = alloc(QV * 2);  // v16 -> probs z-even (32MB)
  char* bufC = alloc(QV * 2);  // Qhat
  char* bufD = alloc(QV * 2);  // VT
  f16* q16 = (f16*)bufA;
  f16* Khat = (f16*)bufA;
  f16* v16 = (f16*)bufB;
  f16* probs0 = (f16*)bufB;  // pair slot 0; slot 1 = weights region (+96MB)
  f16* Qhat = (f16*)bufC;
  f16* VT = (f16*)bufD;
  // weights region: 32 MB from Wq_h onward is reused as probs slot 1
  f16* Wq_h = (f16*)alloc(WW * 2);
  f16* Wq_l = (f16*)alloc(WW * 2);
  f16* Wk_h = (f16*)alloc(WW * 2);
  f16* Wk_l = (f16*)alloc(WW * 2);
  f16* Wr_h = (f16*)alloc(WW * 2);
  f16* Wr_l = (f16*)alloc(WW * 2);
  f16* Wv16 = (f16*)alloc(WW * 2);
  f16* WrT_h = (f16*)alloc(WW * 2);
  f16* WrT_l = (f16*)alloc(WW * 2);
  f16* WvT = (f16*)alloc(WW * 2);
  float* Wtmp32 = (float*)alloc(WW * 8);  // [2][1024][1024] f32
  f16* WqrT_h = (f16*)alloc(WW * 2);
  f16* WqrT_l = (f16*)alloc(WW * 2);
  f16* WkrT_h = (f16*)alloc(WW * 2);
  f16* WkrT_l = (f16*)alloc(WW * 2);
  float* brq = (float*)alloc(1024 * 4);
  float* brk = (float*)alloc(1024 * 4);
  float* m_loc = (float*)alloc(2 * 16 * 4096 * 4);  // [z2][tn256][row]
  float* l_loc = (float*)alloc(2 * 16 * 4096 * 4);
  f16* scl = (f16*)alloc(2 * 16 * 4096 * 2);  // [z2][tile256][row] = alpha/l
  const long PSTRIDE = 50331648;  // f16 elems between probs slot 0 and slot 1

  // fp32 -> fp16 conversions (split for W matrices feeding Wqr/Wkr)
  f2h<<<16384, 256, 0, stream>>>(query, q16, 4194304);
  f2h<<<16384, 256, 0, stream>>>(value, v16, 4194304);
  f2h_split<<<1024, 256, 0, stream>>>(Wq, Wq_h, Wq_l, 262144);
  f2h_split<<<1024, 256, 0, stream>>>(Wk, Wk_h, Wk_l, 262144);
  f2h_split<<<1024, 256, 0, stream>>>(Wr, Wr_h, Wr_l, 262144);
  f2h<<<1024, 256, 0, stream>>>(Wv, Wv16, 262144);
  tr_h<<<dim3(32, 32), dim3(32, 32), 0, stream>>>(Wr_h, WrT_h, 1024, 1024);
  tr_h<<<dim3(32, 32), dim3(32, 32), 0, stream>>>(Wr_l, WrT_l, 1024, 1024);
  tr_h<<<dim3(32, 32), dim3(32, 32), 0, stream>>>(Wv16, WvT, 1024, 1024);
  bias_fold<<<4, 256, 0, stream>>>(br, bq, Wr, brq);
  bias_fold<<<4, 256, 0, stream>>>(br, bk, Wr, brk);

  // W{q,k}rT = Wr^T @ W{q,k}^T in ~fp32 (Ah@Bh + Ah@Bl + Al@Bh), one z=2 pass
  gemm_bt<5, true, true, 32><<<dim3(8, 8, 2), 256, 0, stream>>>(
      WrT_h, WrT_l, Wq_h, Wq_l, Wtmp32, nullptr, nullptr, 0, 1024, 1024, 1024,
      1024, 1024, 1024, 1048576, 0, 2097152, 0);
  f2h_split<<<1024, 256, 0, stream>>>(Wtmp32, WqrT_h, WqrT_l, 262144);
  f2h_split<<<1024, 256, 0, stream>>>(Wtmp32 + 1048576, WkrT_h, WkrT_l, 262144);

  // Qhat = cos(query @ Wqr + brq)   [bufC]  (B = hi + lo, fused dual-B)
  gemm_bt<1, false, true, 32><<<dim3(8, 128, 1), 256, 0, stream>>>(
      q16, nullptr, WqrT_h, WqrT_l, Qhat, brq, nullptr, 0, 16384, 1024, 1024,
      1024, 1024, 1024, 0, 0, 0, 0);
  // Khat = cos(value @ Wkr + brk)   [bufA — q16 dead from here]
  gemm_bt<1, false, true, 32><<<dim3(8, 128, 1), 256, 0, stream>>>(
      v16, nullptr, WkrT_h, WkrT_l, Khat, brk, nullptr, 0, 16384, 1024, 1024,
      1024, 1024, 1024, 0, 0, 0, 0);
  // VT[u][s] = (value @ Wv + bv)^T = Wv^T @ value^T  (row bias bv)  [bufD]
  gemm_bt<2, false, false, 64><<<dim3(128, 8, 1), 256, 0, stream>>>(
      WvT, nullptr, v16, nullptr, VT, bv, nullptr, 0, 1024, 16384, 1024, 1024,
      1024, 16384, 0, 0, 0, 0);

  // per batch-pair: probs = exp(S - m_tile) + stats; merge; PV (scale folded)
  for (int zb = 0; zb < NB; zb += 2) {
    qk_softmax256<<<dim3(16, 16, 2), 512, 0, stream>>>(
        Qhat + (long)zb * 4194304, Khat + (long)zb * 4194304, probs0, m_loc,
        l_loc, 4194304, 4194304, PSTRIDE);
    merge_pair<<<32, 256, 0, stream>>>(m_loc, l_loc, scl);
    gemm_bt<7, false, false, 64><<<dim3(8, 32, 2), 256, 0, stream>>>(
        probs0, nullptr, VT + (long)zb * 4096, nullptr, out + (long)zb * 4194304,
        nullptr, scl, 65536, 4096, 1024, 4096, 4096, 16384, 1024, 4194304,
        PSTRIDE, 4096, 0);
  }
}

// Round 9
// 737.679 us; speedup vs baseline: 1.0399x; 1.0399x over previous
//
#include <hip/hip_runtime.h>
#include <hip/hip_bf16.h>
#include <hip/hip_fp16.h>
#include <cstdint>

// ---------------------------------------------------------------------------
// LinearAttention (random-feature cos kernel + softmax attention), MI355X.
// out = softmax(cos(q@Wq@Wr + br) @ cos(v@Wk@Wr + br)^T) @ (v@Wv + bv)
// B=4, S=4096, D=U=F=1024.  All heavy math in fp16 MFMA with fp32 accum.
// probs GEMM: 256x256 / 8 waves / BK=64 / 8-phase schedule, counted vmcnt(4),
// B-frags register-resident, half-tile prefetch (m201 template).
// Other GEMMs: 128x128 2-phase (round-7 structure).
// Softmax: tile-local max in QK^T epilogue + alpha/l folded into PV.
// ---------------------------------------------------------------------------

typedef _Float16 f16;
typedef _Float16 f16x8 __attribute__((ext_vector_type(8)));
typedef _Float16 f16x4 __attribute__((ext_vector_type(4)));
typedef float f32x4 __attribute__((ext_vector_type(4)));

typedef __attribute__((address_space(1))) unsigned int uas1;
typedef __attribute__((address_space(3))) unsigned int uas3;

#define NB 4
#define SEQ 4096
#define DIM 1024

// async 16B/lane global->LDS. LDS dest must be wave-uniform base (+lane*16).
__device__ __forceinline__ void async_copy16(void* lds, const void* g) {
  __builtin_amdgcn_global_load_lds((uas1*)(uintptr_t)g, (uas3*)(uintptr_t)lds,
                                   16, 0, 0);
}

// ----------------------------- small kernels ------------------------------

__global__ __launch_bounds__(256) void f2h(const float* __restrict__ in,
                                           f16* __restrict__ out, int n4) {
  int i = blockIdx.x * 256 + threadIdx.x;
  if (i < n4) {
    float4 v = ((const float4*)in)[i];
    f16x4 h = {(f16)v.x, (f16)v.y, (f16)v.z, (f16)v.w};
    ((f16x4*)out)[i] = h;
  }
}

__global__ __launch_bounds__(256) void f2h_split(const float* __restrict__ in,
                                                 f16* __restrict__ hi,
                                                 f16* __restrict__ lo, int n4) {
  int i = blockIdx.x * 256 + threadIdx.x;
  if (i < n4) {
    float4 v = ((const float4*)in)[i];
    f16 h0 = (f16)v.x, h1 = (f16)v.y, h2 = (f16)v.z, h3 = (f16)v.w;
    f16x4 hv = {h0, h1, h2, h3};
    f16x4 lv = {(f16)(v.x - (float)h0), (f16)(v.y - (float)h1),
                (f16)(v.z - (float)h2), (f16)(v.w - (float)h3)};
    ((f16x4*)hi)[i] = hv;
    ((f16x4*)lo)[i] = lv;
  }
}

__global__ void tr_h(const f16* __restrict__ in, f16* __restrict__ out, int R,
                     int C) {
  __shared__ f16 tile[32][33];
  int c0 = blockIdx.x * 32, r0 = blockIdx.y * 32;
  tile[threadIdx.y][threadIdx.x] =
      in[(long)(r0 + threadIdx.y) * C + c0 + threadIdx.x];
  __syncthreads();
  out[(long)(c0 + threadIdx.y) * R + r0 + threadIdx.x] =
      tile[threadIdx.x][threadIdx.y];
}

// bias_eff[f] = br[f] + sum_u bvec[u] * Wr[u][f]   (fp32 exact)
__global__ __launch_bounds__(256) void bias_fold(const float* __restrict__ br,
                                                 const float* __restrict__ bvec,
                                                 const float* __restrict__ Wr,
                                                 float* __restrict__ outb) {
  int f = blockIdx.x * 256 + threadIdx.x;
  float s = br[f];
  for (int u = 0; u < DIM; ++u) s = fmaf(bvec[u], Wr[(long)u * DIM + f], s);
  outb[f] = s;
}

// per (z2,row): m = max_t m_t; l = sum_t l_t exp(m_t-m);
// scl[t][row] = exp(m_t-m)/l  (f16).  16 tiles of 256 cols.
__global__ __launch_bounds__(256) void merge_pair(const float* __restrict__ ml,
                                                  const float* __restrict__ ll,
                                                  f16* __restrict__ scl) {
  int i = blockIdx.x * 256 + threadIdx.x;  // 0..8191 = z2*4096 + row
  int z2 = i >> 12, row = i & 4095;
  const float* m = ml + z2 * 65536 + row;
  const float* lp = ll + z2 * 65536 + row;
  float a[16];
  float mg = -1e30f;
#pragma unroll 16
  for (int t = 0; t < 16; ++t) mg = fmaxf(mg, m[t * 4096]);
  float l = 0.f;
#pragma unroll 16
  for (int t = 0; t < 16; ++t) {
    a[t] = __expf(m[t * 4096] - mg);
    l += lp[t * 4096] * a[t];
  }
  float li = 1.0f / l;
#pragma unroll 16
  for (int t = 0; t < 16; ++t)
    scl[z2 * 65536 + t * 4096 + row] = (f16)(a[t] * li);
}

__global__ void sentinel(float* out) { out[0] = 12345.0f; }

// ------------- probs GEMM: 256x256, 8 waves, BK=64, 8-phase ---------------
// P[z,row,col] = exp(S - rowmax_tile), S = A@B^T (M=N=4096, K=1024).
// Writes mout/lout per (z, tn, row);  column tiles are 256 wide (16 tiles).
__global__ __launch_bounds__(512, 2) void qk_softmax256(
    const f16* __restrict__ A, const f16* __restrict__ B, f16* __restrict__ P,
    float* __restrict__ mout, float* __restrict__ lout, long sA, long sB,
    long sP) {
  constexpr int LD = 1024, LDC = 4096, K = 1024;
  constexpr int NT = K / 64;  // 16 K-tiles, BK=64
  constexpr int BUF = 65536;  // 64KB per dbuf: A(32KB)+B(32KB)
  __shared__ __align__(16) char smem[2 * BUF];
  __shared__ float red[4][256];
  // XCD-bijective swizzle over the 256 (tm,tn) blocks of each z
  int lin = blockIdx.x + (blockIdx.y << 4);
  lin = ((lin & 7) << 5) | (lin >> 3);
  const int tn = lin & 15, tm = lin >> 4;
  const int z = blockIdx.z;
  const int t = threadIdx.x, w = t >> 6, l = t & 63;
  const int l4 = l >> 4, l15 = l & 15;
  const int wm = w >> 2, wn = w & 3;  // 2 x 4 waves; wave out = 128 x 64
  f32x4 acc[8][4] = {};
  const f16* Az = A + (long)z * sA;
  const f16* Bz = B + (long)z * sB;

  // half-tile stage: ht 0=A0,1=A1,2=B0,3=B1 ; 1024 chunks, 2 per thread
  auto STAGE_HT = [&](int buf, int tt, int ht) {
    const f16* src = (ht < 2) ? Az : Bz;
    const int row0 = ((ht < 2) ? tm : tn) * 256 + (ht & 1) * 128;
    char* base = smem + buf * BUF + (ht >> 1) * 32768 + (ht & 1) * 16384;
    const int kk = tt * 64;
#pragma unroll
    for (int j = 0; j < 2; ++j) {
      const int cb = j * 512 + w * 64;  // wave-uniform chunk base
      const int c = cb + l;
      const int r = c >> 3, s = c & 7;
      async_copy16(base + cb * 16,
                   src + (long)(row0 + r) * LD + kk + (s ^ (r & 7)) * 8);
    }
  };

  // prologue: tile0 full + B halves of tile1;  vmcnt(4) -> tile0 resident
  STAGE_HT(0, 0, 0);
  STAGE_HT(0, 0, 1);
  STAGE_HT(0, 0, 2);
  STAGE_HT(0, 0, 3);
  STAGE_HT(1, 1, 2);
  STAGE_HT(1, 1, 3);
  asm volatile("s_waitcnt vmcnt(4)" ::: "memory");
  __builtin_amdgcn_s_barrier();

  for (int it = 0; it < NT / 2; ++it) {
    const int tt = 2 * it;
    const bool more = (tt + 2) < NT;  // tt+2 and tt+3 validity coincide (NT even)
    // ---- phases 1-4: compute tile tt from buf0 ----
    {
      const f16* Ab = (const f16*)(smem);
      const f16* Bb = Ab + 16384;  // +32KB
      f16x8 bfp[4][2];
#pragma unroll
      for (int q = 0; q < 4; ++q) {
        if (q == 0) {
#pragma unroll
          for (int jn = 0; jn < 4; ++jn)
#pragma unroll
            for (int ks = 0; ks < 2; ++ks) {
              const int rb = wn * 64 + jn * 16 + l15;
              const int p = ks * 4 + l4;
              bfp[jn][ks] = *(const f16x8*)&Bb[rb * 64 + (p ^ (rb & 7)) * 8];
            }
        }
        f16x8 af[2][2];
#pragma unroll
        for (int i2 = 0; i2 < 2; ++i2)
#pragma unroll
          for (int ks = 0; ks < 2; ++ks) {
            const int ra = wm * 128 + (q * 2 + i2) * 16 + l15;
            const int p = ks * 4 + l4;
            af[i2][ks] = *(const f16x8*)&Ab[ra * 64 + (p ^ (ra & 7)) * 8];
          }
        if (q == 0) STAGE_HT(1, tt + 1, 0);
        if (q == 1) STAGE_HT(1, tt + 1, 1);
        if (q == 2 && more) STAGE_HT(0, tt + 2, 2);
        if (q == 3) {
          if (more) {
            STAGE_HT(0, tt + 2, 3);
            asm volatile("s_waitcnt vmcnt(4)" ::: "memory");
          } else {
            asm volatile("s_waitcnt vmcnt(0)" ::: "memory");
          }
        }
        __builtin_amdgcn_s_barrier();
        asm volatile("s_waitcnt lgkmcnt(0)" ::: "memory");
        __builtin_amdgcn_s_setprio(1);
#pragma unroll
        for (int i2 = 0; i2 < 2; ++i2)
#pragma unroll
          for (int jn = 0; jn < 4; ++jn)
#pragma unroll
            for (int ks = 0; ks < 2; ++ks)
              acc[q * 2 + i2][jn] = __builtin_amdgcn_mfma_f32_16x16x32_f16(
                  af[i2][ks], bfp[jn][ks], acc[q * 2 + i2][jn], 0, 0, 0);
        __builtin_amdgcn_s_setprio(0);
        __builtin_amdgcn_s_barrier();
      }
    }
    // ---- phases 5-8: compute tile tt+1 from buf1 ----
    {
      const f16* Ab = (const f16*)(smem + BUF);
      const f16* Bb = Ab + 16384;
      f16x8 bfp[4][2];
#pragma unroll
      for (int q = 0; q < 4; ++q) {
        if (q == 0) {
#pragma unroll
          for (int jn = 0; jn < 4; ++jn)
#pragma unroll
            for (int ks = 0; ks < 2; ++ks) {
              const int rb = wn * 64 + jn * 16 + l15;
              const int p = ks * 4 + l4;
              bfp[jn][ks] = *(const f16x8*)&Bb[rb * 64 + (p ^ (rb & 7)) * 8];
            }
        }
        f16x8 af[2][2];
#pragma unroll
        for (int i2 = 0; i2 < 2; ++i2)
#pragma unroll
          for (int ks = 0; ks < 2; ++ks) {
            const int ra = wm * 128 + (q * 2 + i2) * 16 + l15;
            const int p = ks * 4 + l4;
            af[i2][ks] = *(const f16x8*)&Ab[ra * 64 + (p ^ (ra & 7)) * 8];
          }
        if (q == 0 && more) STAGE_HT(0, tt + 2, 0);
        if (q == 1 && more) STAGE_HT(0, tt + 2, 1);
        if (q == 2 && more) STAGE_HT(1, tt + 3, 2);
        if (q == 3) {
          if (more) {
            STAGE_HT(1, tt + 3, 3);
            asm volatile("s_waitcnt vmcnt(4)" ::: "memory");
          } else {
            asm volatile("s_waitcnt vmcnt(0)" ::: "memory");
          }
        }
        __builtin_amdgcn_s_barrier();
        asm volatile("s_waitcnt lgkmcnt(0)" ::: "memory");
        __builtin_amdgcn_s_setprio(1);
#pragma unroll
        for (int i2 = 0; i2 < 2; ++i2)
#pragma unroll
          for (int jn = 0; jn < 4; ++jn)
#pragma unroll
            for (int ks = 0; ks < 2; ++ks)
              acc[q * 2 + i2][jn] = __builtin_amdgcn_mfma_f32_16x16x32_f16(
                  af[i2][ks], bfp[jn][ks], acc[q * 2 + i2][jn], 0, 0, 0);
        __builtin_amdgcn_s_setprio(0);
        __builtin_amdgcn_s_barrier();
      }
    }
  }

  // ---- tile-local softmax over this 256-col tile ----
  float mrow[32];
#pragma unroll
  for (int i = 0; i < 8; ++i)
#pragma unroll
    for (int r = 0; r < 4; ++r) {
      float v = fmaxf(fmaxf(acc[i][0][r], acc[i][1][r]),
                      fmaxf(acc[i][2][r], acc[i][3][r]));
      v = fmaxf(v, __shfl_xor(v, 1));
      v = fmaxf(v, __shfl_xor(v, 2));
      v = fmaxf(v, __shfl_xor(v, 4));
      v = fmaxf(v, __shfl_xor(v, 8));
      if (l15 == 0) red[wn][wm * 128 + i * 16 + l4 * 4 + r] = v;
    }
  __syncthreads();
#pragma unroll
  for (int i = 0; i < 8; ++i)
#pragma unroll
    for (int r = 0; r < 4; ++r) {
      const int rin = wm * 128 + i * 16 + l4 * 4 + r;
      mrow[i * 4 + r] = fmaxf(fmaxf(red[0][rin], red[1][rin]),
                              fmaxf(red[2][rin], red[3][rin]));
    }
  __syncthreads();
#pragma unroll
  for (int i = 0; i < 8; ++i)
#pragma unroll
    for (int r = 0; r < 4; ++r) {
      const float mn = mrow[i * 4 + r];
      float s = 0.f;
#pragma unroll
      for (int jn = 0; jn < 4; ++jn) {
        float e = __expf(acc[i][jn][r] - mn);
        acc[i][jn][r] = e;
        s += e;
      }
      s += __shfl_xor(s, 1);
      s += __shfl_xor(s, 2);
      s += __shfl_xor(s, 4);
      s += __shfl_xor(s, 8);
      if (l15 == 0) red[wn][wm * 128 + i * 16 + l4 * 4 + r] = s;
    }
  __syncthreads();
  if (wn == 0 && l15 == 0) {
#pragma unroll
    for (int i = 0; i < 8; ++i)
#pragma unroll
      for (int r = 0; r < 4; ++r) {
        const int rin = wm * 128 + i * 16 + l4 * 4 + r;
        const int gidx = z * 65536 + tn * 4096 + tm * 256 + rin;
        mout[gidx] = mrow[i * 4 + r];
        lout[gidx] = red[0][rin] + red[1][rin] + red[2][rin] + red[3][rin];
      }
  }
  // ---- write unnormalized probs (f16) ----
#pragma unroll
  for (int i = 0; i < 8; ++i) {
    const int row0 = tm * 256 + wm * 128 + i * 16 + l4 * 4;
#pragma unroll
    for (int jn = 0; jn < 4; ++jn) {
      const int col = tn * 256 + wn * 64 + jn * 16 + l15;
#pragma unroll
      for (int r = 0; r < 4; ++r)
        P[(long)z * sP + (long)(row0 + r) * LDC + col] = (f16)acc[i][jn][r];
    }
  }
}

// ------------------------------- main GEMM --------------------------------
// C[M,N] = epilogue( A@B^T [+ A@Bl^T if DB] [+ Al@B^T if DA] )
// B stored row-major [N,K].  128x128 tile, 4 waves, 4x4 16x16x32 frags/wave.
// Double-buffered LDS, 2-phase pipeline, counted vmcnt (never 0 in loop).
// EPI: 1 f16 __cosf(v+aux[col]) | 2 f16 v+aux[row] | 5 f32 plain
//      7 f32 plain, A-fragments scaled by ascl[ktile256][arow] (LDS-staged)
template <int EPI, bool DA, bool DB, int BK>
__global__ __launch_bounds__(256) void gemm_bt(
    const f16* __restrict__ Ah, const f16* __restrict__ Al,
    const f16* __restrict__ Bh, const f16* __restrict__ Bl,
    void* __restrict__ Cv, const float* __restrict__ aux,
    const f16* __restrict__ ascl, long sAscl, int M, int N, int K, int lda,
    int ldb, int ldc, long sC, long sA, long sB, int sAux) {
  constexpr int NSTAGE = 2 + (DA ? 1 : 0) + (DB ? 1 : 0);
  constexpr int TILE = 128 * BK * 2;    // bytes per operand tile
  constexpr int CPR = BK / 8;           // 16B chunks per row
  constexpr int CH = 128 * CPR;         // chunks per operand tile
  constexpr int NL = NSTAGE * BK / 16;  // per-thread vmem issues per tile
  static_assert(NL == 6 || NL == 8, "vmcnt literal");
  constexpr int SCLB = (EPI == 7) ? 4096 : 0;
  __shared__ __align__(16) char smem[2 * NSTAGE * TILE + SCLB];

  const int z = blockIdx.z;
  const int tn = blockIdx.x, tm = blockIdx.y;
  const int t = threadIdx.x, w = t >> 6, l = t & 63;
  const int l4 = l >> 4, l15 = l & 15;
  const int wm = w & 1, wn = w >> 1;
  f32x4 acc[4][4] = {};

  const f16* Az = Ah + (long)z * sA;
  const f16* Bz = Bh + (long)z * sB;
  const f16* Alz = nullptr;
  const f16* Blz = nullptr;
  if constexpr (DA) Alz = Al + (long)z * sA;
  if constexpr (DB) Blz = Bl + (long)z * sB;
  f16* sclLds = (f16*)(smem + 2 * NSTAGE * TILE);

  auto swz = [](int r, int p) -> int {
    if constexpr (BK == 64) return p ^ (r & 7);
    else return p ^ ((r >> 1) & 3);
  };

  auto STAGE = [&](int buf, int kk) {
    char* base = smem + buf * (NSTAGE * TILE);
#pragma unroll
    for (int j = 0; j < CH / 256; ++j) {
      const int cb = j * 256 + w * 64;  // wave-uniform chunk base
      const int c = cb + l;
      const int r = c / CPR, pp = c % CPR;
      const int sc = swz(r, pp);
      const long ra = (long)(tm * 128 + r) * lda + kk + sc * 8;
      const long rb = (long)(tn * 128 + r) * ldb + kk + sc * 8;
      async_copy16(base + cb * 16, Az + ra);
      async_copy16(base + TILE + cb * 16, Bz + rb);
      if constexpr (DA) async_copy16(base + 2 * TILE + cb * 16, Alz + ra);
      if constexpr (DB)
        async_copy16(base + (2 + (DA ? 1 : 0)) * TILE + cb * 16, Blz + rb);
    }
  };

  // ---- prologue: stage tile 0 (+ scl table for EPI 7), drain, barrier ----
  STAGE(0, 0);
  if constexpr (EPI == 7) {
    const f16* asclz = ascl + (long)z * sAscl;
    // 16 k-tiles x 128 rows f16 -> 256 chunks; LDS idx c*8 = tile*128 + row
    const int cb = w * 64;
    const int c = cb + l;
    async_copy16(sclLds + cb * 8,
                 asclz + (long)(c >> 4) * M + tm * 128 + (c & 15) * 8);
  }
  asm volatile("s_waitcnt vmcnt(0)" ::: "memory");
  __syncthreads();

  const int nt = K / BK;
  int cur = 0;
  for (int tt = 0; tt < nt; ++tt) {
    const int kk = tt * BK;
    if (tt + 1 < nt) {
      STAGE(cur ^ 1, kk + BK);
      if constexpr (NL == 6)
        asm volatile("s_waitcnt vmcnt(6)" ::: "memory");
      else
        asm volatile("s_waitcnt vmcnt(8)" ::: "memory");
    } else {
      asm volatile("s_waitcnt vmcnt(0)" ::: "memory");
    }
    __syncthreads();

    const f16* As = (const f16*)(smem + cur * (NSTAGE * TILE));
    const f16* Bs = As + TILE / 2;
    const f16* Als = Bs + TILE / 2;
    const f16* Bls = Als + (DA ? TILE / 2 : 0);

    f16 sA4[4];
    if constexpr (EPI == 7) {
      const int tile = kk >> 8;  // 256-wide k-tiles
#pragma unroll
      for (int i = 0; i < 4; ++i)
        sA4[i] = sclLds[tile * 128 + wm * 64 + i * 16 + l15];
    }

#pragma unroll
    for (int ks = 0; ks < BK / 32; ++ks) {
      f16x8 af[4], bf[4];
#pragma unroll
      for (int i = 0; i < 4; ++i) {
        const int ra = wm * 64 + i * 16 + l15;
        const int rb = wn * 64 + i * 16 + l15;
        af[i] = *(const f16x8*)&As[ra * BK + swz(ra, ks * 4 + l4) * 8];
        bf[i] = *(const f16x8*)&Bs[rb * BK + swz(rb, ks * 4 + l4) * 8];
      }
      if constexpr (EPI == 7) {
#pragma unroll
        for (int i = 0; i < 4; ++i) af[i] = af[i] * sA4[i];
      }
#pragma unroll
      for (int i = 0; i < 4; ++i)
#pragma unroll
        for (int jn = 0; jn < 4; ++jn)
          acc[i][jn] = __builtin_amdgcn_mfma_f32_16x16x32_f16(af[i], bf[jn],
                                                              acc[i][jn], 0, 0, 0);
      if constexpr (DB) {
        f16x8 bl[4];
#pragma unroll
        for (int i = 0; i < 4; ++i) {
          const int rb = wn * 64 + i * 16 + l15;
          bl[i] = *(const f16x8*)&Bls[rb * BK + swz(rb, ks * 4 + l4) * 8];
        }
#pragma unroll
        for (int i = 0; i < 4; ++i)
#pragma unroll
          for (int jn = 0; jn < 4; ++jn)
            acc[i][jn] = __builtin_amdgcn_mfma_f32_16x16x32_f16(
                af[i], bl[jn], acc[i][jn], 0, 0, 0);
      }
      if constexpr (DA) {
        f16x8 al[4];
#pragma unroll
        for (int i = 0; i < 4; ++i) {
          const int ra = wm * 64 + i * 16 + l15;
          al[i] = *(const f16x8*)&Als[ra * BK + swz(ra, ks * 4 + l4) * 8];
        }
#pragma unroll
        for (int i = 0; i < 4; ++i)
#pragma unroll
          for (int jn = 0; jn < 4; ++jn)
            acc[i][jn] = __builtin_amdgcn_mfma_f32_16x16x32_f16(
                al[i], bf[jn], acc[i][jn], 0, 0, 0);
      }
    }
    __syncthreads();
    cur ^= 1;
  }

  const float* auxp = aux + (long)z * sAux;

  if constexpr (EPI == 1 || EPI == 2) {
    // ---- f16 output via LDS repack: [64][136] per half ----
    f16* rep = (f16*)smem;
#pragma unroll
    for (int hh = 0; hh < 2; ++hh) {
      __syncthreads();
#pragma unroll
      for (int ii = 0; ii < 2; ++ii) {
        const int i = hh * 2 + ii;
        const int lrow0 = wm * 32 + ii * 16 + l4 * 4;
#pragma unroll
        for (int jn = 0; jn < 4; ++jn) {
          const int col = wn * 64 + jn * 16 + l15;
#pragma unroll
          for (int r = 0; r < 4; ++r) {
            float v = acc[i][jn][r];
            f16 hv;
            if constexpr (EPI == 1)
              hv = (f16)__cosf(v + auxp[tn * 128 + col]);
            else
              hv = (f16)(v + auxp[tm * 128 + wm * 64 + i * 16 + l4 * 4 + r]);
            rep[(lrow0 + r) * 136 + col] = hv;
          }
        }
      }
      __syncthreads();
#pragma unroll
      for (int pp = 0; pp < 4; ++pp) {
        const int lrow = pp * 16 + (t >> 4);
        const int grow = tm * 128 + (lrow >> 5) * 64 + hh * 32 + (lrow & 31);
        const int gcol = tn * 128 + (t & 15) * 8;
        *(f16x8*)&((f16*)Cv)[(long)z * sC + (long)grow * ldc + gcol] =
            *(const f16x8*)&rep[lrow * 136 + (t & 15) * 8];
      }
    }
  } else {
    // ---- f32 output via LDS repack: [32][132] per i-group ----
    float* rep = (float*)smem;
#pragma unroll
    for (int i = 0; i < 4; ++i) {
      __syncthreads();
      const int lrow0 = wm * 16 + l4 * 4;
#pragma unroll
      for (int jn = 0; jn < 4; ++jn) {
        const int col = wn * 64 + jn * 16 + l15;
#pragma unroll
        for (int r = 0; r < 4; ++r) rep[(lrow0 + r) * 132 + col] = acc[i][jn][r];
      }
      __syncthreads();
#pragma unroll
      for (int pp = 0; pp < 4; ++pp) {
        const int lrow = pp * 8 + (t >> 5);
        const int grow = tm * 128 + (lrow >> 4) * 64 + i * 16 + (lrow & 15);
        const int gcol = tn * 128 + (t & 31) * 4;
        *(float4*)&((float*)Cv)[(long)z * sC + (long)grow * ldc + gcol] =
            *(const float4*)&rep[lrow * 132 + (t & 31) * 4];
      }
    }
  }
}

// --------------------------------- driver ----------------------------------

extern "C" void kernel_launch(void* const* d_in, const int* in_sizes, int n_in,
                              void* d_out, int out_size, void* d_ws,
                              size_t ws_size, hipStream_t stream) {
  const float* query = (const float*)d_in[0];
  const float* value = (const float*)d_in[1];
  const float* Wq = (const float*)d_in[2];
  const float* bq = (const float*)d_in[3];
  const float* Wk = (const float*)d_in[4];
  const float* bk = (const float*)d_in[5];
  const float* Wv = (const float*)d_in[6];
  const float* bv = (const float*)d_in[7];
  const float* Wr = (const float*)d_in[8];
  const float* br = (const float*)d_in[9];
  float* out = (float*)d_out;

  if (ws_size < 169000000ull) {
    sentinel<<<1, 1, 0, stream>>>(out);
    return;
  }

  char* p = (char*)d_ws;
  auto alloc = [&](size_t bytes) {
    char* r = p;
    p += (bytes + 255) & ~(size_t)255;
    return r;
  };
  const size_t QV = 16777216ull;  // B*S*D elements
  const size_t WW = 1048576ull;   // 1024*1024 elements
  char* bufA = alloc(QV * 2);  // q16 -> Khat
  char* bufB = alloc(QV * 2);  // v16 -> probs z-even (32MB)
  char* bufC = alloc(QV * 2);  // Qhat
  char* bufD = alloc(QV * 2);  // VT
  f16* q16 = (f16*)bufA;
  f16* Khat = (f16*)bufA;
  f16* v16 = (f16*)bufB;
  f16* probs0 = (f16*)bufB;  // pair slot 0; slot 1 = weights region (+96MB)
  f16* Qhat = (f16*)bufC;
  f16* VT = (f16*)bufD;
  // weights region: 32 MB from Wq_h onward is reused as probs slot 1
  f16* Wq_h = (f16*)alloc(WW * 2);
  f16* Wq_l = (f16*)alloc(WW * 2);
  f16* Wk_h = (f16*)alloc(WW * 2);
  f16* Wk_l = (f16*)alloc(WW * 2);
  f16* Wr_h = (f16*)alloc(WW * 2);
  f16* Wr_l = (f16*)alloc(WW * 2);
  f16* Wv16 = (f16*)alloc(WW * 2);
  f16* WrT_h = (f16*)alloc(WW * 2);
  f16* WrT_l = (f16*)alloc(WW * 2);
  f16* WvT = (f16*)alloc(WW * 2);
  float* Wtmp32 = (float*)alloc(WW * 8);  // [2][1024][1024] f32
  f16* WqrT_h = (f16*)alloc(WW * 2);
  f16* WqrT_l = (f16*)alloc(WW * 2);
  f16* WkrT_h = (f16*)alloc(WW * 2);
  f16* WkrT_l = (f16*)alloc(WW * 2);
  float* brq = (float*)alloc(1024 * 4);
  float* brk = (float*)alloc(1024 * 4);
  float* m_loc = (float*)alloc(2 * 16 * 4096 * 4);  // [z2][tn256][row]
  float* l_loc = (float*)alloc(2 * 16 * 4096 * 4);
  f16* scl = (f16*)alloc(2 * 16 * 4096 * 2);  // [z2][tile256][row] = alpha/l
  const long PSTRIDE = 50331648;  // f16 elems between probs slot 0 and slot 1

  // fp32 -> fp16 conversions (split for W matrices feeding Wqr/Wkr)
  f2h<<<16384, 256, 0, stream>>>(query, q16, 4194304);
  f2h<<<16384, 256, 0, stream>>>(value, v16, 4194304);
  f2h_split<<<1024, 256, 0, stream>>>(Wq, Wq_h, Wq_l, 262144);
  f2h_split<<<1024, 256, 0, stream>>>(Wk, Wk_h, Wk_l, 262144);
  f2h_split<<<1024, 256, 0, stream>>>(Wr, Wr_h, Wr_l, 262144);
  f2h<<<1024, 256, 0, stream>>>(Wv, Wv16, 262144);
  tr_h<<<dim3(32, 32), dim3(32, 32), 0, stream>>>(Wr_h, WrT_h, 1024, 1024);
  tr_h<<<dim3(32, 32), dim3(32, 32), 0, stream>>>(Wr_l, WrT_l, 1024, 1024);
  tr_h<<<dim3(32, 32), dim3(32, 32), 0, stream>>>(Wv16, WvT, 1024, 1024);
  bias_fold<<<4, 256, 0, stream>>>(br, bq, Wr, brq);
  bias_fold<<<4, 256, 0, stream>>>(br, bk, Wr, brk);

  // W{q,k}rT = Wr^T @ W{q,k}^T in ~fp32 (Ah@Bh + Ah@Bl + Al@Bh), one z=2 pass
  gemm_bt<5, true, true, 32><<<dim3(8, 8, 2), 256, 0, stream>>>(
      WrT_h, WrT_l, Wq_h, Wq_l, Wtmp32, nullptr, nullptr, 0, 1024, 1024, 1024,
      1024, 1024, 1024, 1048576, 0, 2097152, 0);
  f2h_split<<<1024, 256, 0, stream>>>(Wtmp32, WqrT_h, WqrT_l, 262144);
  f2h_split<<<1024, 256, 0, stream>>>(Wtmp32 + 1048576, WkrT_h, WkrT_l, 262144);

  // Qhat = cos(query @ Wqr + brq)   [bufC]  (B = hi + lo, fused dual-B)
  gemm_bt<1, false, true, 32><<<dim3(8, 128, 1), 256, 0, stream>>>(
      q16, nullptr, WqrT_h, WqrT_l, Qhat, brq, nullptr, 0, 16384, 1024, 1024,
      1024, 1024, 1024, 0, 0, 0, 0);
  // Khat = cos(value @ Wkr + brk)   [bufA — q16 dead from here]
  gemm_bt<1, false, true, 32><<<dim3(8, 128, 1), 256, 0, stream>>>(
      v16, nullptr, WkrT_h, WkrT_l, Khat, brk, nullptr, 0, 16384, 1024, 1024,
      1024, 1024, 1024, 0, 0, 0, 0);
  // VT[u][s] = (value @ Wv + bv)^T = Wv^T @ value^T  (row bias bv)  [bufD]
  gemm_bt<2, false, false, 64><<<dim3(128, 8, 1), 256, 0, stream>>>(
      WvT, nullptr, v16, nullptr, VT, bv, nullptr, 0, 1024, 16384, 1024, 1024,
      1024, 16384, 0, 0, 0, 0);

  // per batch-pair: probs = exp(S - m_tile) + stats; merge; PV (scale folded)
  for (int zb = 0; zb < NB; zb += 2) {
    qk_softmax256<<<dim3(16, 16, 2), 512, 0, stream>>>(
        Qhat + (long)zb * 4194304, Khat + (long)zb * 4194304, probs0, m_loc,
        l_loc, 4194304, 4194304, PSTRIDE);
    merge_pair<<<32, 256, 0, stream>>>(m_loc, l_loc, scl);
    gemm_bt<7, false, false, 64><<<dim3(8, 32, 2), 256, 0, stream>>>(
        probs0, nullptr, VT + (long)zb * 4096, nullptr, out + (long)zb * 4194304,
        nullptr, scl, 65536, 4096, 1024, 4096, 4096, 16384, 1024, 4194304,
        PSTRIDE, 4096, 0);
  }
}

// Round 10
// 684.866 us; speedup vs baseline: 1.1201x; 1.0771x over previous
//
#include <hip/hip_runtime.h>
#include <hip/hip_bf16.h>
#include <hip/hip_fp16.h>
#include <cstdint>

// ---------------------------------------------------------------------------
// LinearAttention (random-feature cos kernel + softmax attention), MI355X.
// out = softmax(cos(q@Wq@Wr + br) @ cos(v@Wk@Wr + br)^T) @ (v@Wv + bv)
// B=4, S=4096, D=U=F=1024.  All heavy math in fp16 MFMA with fp32 accum.
// qk + Qhat/Khat: 256x256 / 8 waves / BK=64 / 8-phase, counted vmcnt(4).
//   Qhat/Khat use K-concat: [A A] @ [Wh;Wl]^T  (K'=2048, A wraps mod 1024).
// PV/VT/Wqr: 128x128 2-phase counted-vmcnt (round-7 structure).
// Softmax: tile-local max in QK^T epilogue + alpha/l folded into PV.
// ---------------------------------------------------------------------------

typedef _Float16 f16;
typedef _Float16 f16x8 __attribute__((ext_vector_type(8)));
typedef _Float16 f16x4 __attribute__((ext_vector_type(4)));
typedef float f32x4 __attribute__((ext_vector_type(4)));

typedef __attribute__((address_space(1))) unsigned int uas1;
typedef __attribute__((address_space(3))) unsigned int uas3;

#define NB 4
#define SEQ 4096
#define DIM 1024

// async 16B/lane global->LDS. LDS dest must be wave-uniform base (+lane*16).
__device__ __forceinline__ void async_copy16(void* lds, const void* g) {
  __builtin_amdgcn_global_load_lds((uas1*)(uintptr_t)g, (uas3*)(uintptr_t)lds,
                                   16, 0, 0);
}

// ----------------------------- small kernels ------------------------------

__global__ __launch_bounds__(256) void f2h(const float* __restrict__ in,
                                           f16* __restrict__ out, int n4) {
  int i = blockIdx.x * 256 + threadIdx.x;
  if (i < n4) {
    float4 v = ((const float4*)in)[i];
    f16x4 h = {(f16)v.x, (f16)v.y, (f16)v.z, (f16)v.w};
    ((f16x4*)out)[i] = h;
  }
}

__global__ __launch_bounds__(256) void f2h_split(const float* __restrict__ in,
                                                 f16* __restrict__ hi,
                                                 f16* __restrict__ lo, int n4) {
  int i = blockIdx.x * 256 + threadIdx.x;
  if (i < n4) {
    float4 v = ((const float4*)in)[i];
    f16 h0 = (f16)v.x, h1 = (f16)v.y, h2 = (f16)v.z, h3 = (f16)v.w;
    f16x4 hv = {h0, h1, h2, h3};
    f16x4 lv = {(f16)(v.x - (float)h0), (f16)(v.y - (float)h1),
                (f16)(v.z - (float)h2), (f16)(v.w - (float)h3)};
    ((f16x4*)hi)[i] = hv;
    ((f16x4*)lo)[i] = lv;
  }
}

// split to hi/lo CONCATENATED along K: w2[n][k]=hi, w2[n][1024+k]=lo
__global__ __launch_bounds__(256) void f2h_split2(const float* __restrict__ in,
                                                  f16* __restrict__ w2, int n4) {
  int i = blockIdx.x * 256 + threadIdx.x;
  if (i < n4) {
    float4 v = ((const float4*)in)[i];
    f16 h0 = (f16)v.x, h1 = (f16)v.y, h2 = (f16)v.z, h3 = (f16)v.w;
    f16x4 hv = {h0, h1, h2, h3};
    f16x4 lv = {(f16)(v.x - (float)h0), (f16)(v.y - (float)h1),
                (f16)(v.z - (float)h2), (f16)(v.w - (float)h3)};
    const int n = i >> 8, k4 = i & 255;
    ((f16x4*)(w2 + (long)n * 2048))[k4] = hv;
    ((f16x4*)(w2 + (long)n * 2048 + 1024))[k4] = lv;
  }
}

__global__ void tr_h(const f16* __restrict__ in, f16* __restrict__ out, int R,
                     int C) {
  __shared__ f16 tile[32][33];
  int c0 = blockIdx.x * 32, r0 = blockIdx.y * 32;
  tile[threadIdx.y][threadIdx.x] =
      in[(long)(r0 + threadIdx.y) * C + c0 + threadIdx.x];
  __syncthreads();
  out[(long)(c0 + threadIdx.y) * R + r0 + threadIdx.x] =
      tile[threadIdx.x][threadIdx.y];
}

// bias_eff[f] = br[f] + sum_u bvec[u] * Wr[u][f]   (fp32 exact)
__global__ __launch_bounds__(256) void bias_fold(const float* __restrict__ br,
                                                 const float* __restrict__ bvec,
                                                 const float* __restrict__ Wr,
                                                 float* __restrict__ outb) {
  int f = blockIdx.x * 256 + threadIdx.x;
  float s = br[f];
  for (int u = 0; u < DIM; ++u) s = fmaf(bvec[u], Wr[(long)u * DIM + f], s);
  outb[f] = s;
}

// per (z2,row): m = max_t m_t; l = sum_t l_t exp(m_t-m);
// scl[t][row] = exp(m_t-m)/l  (f16).  16 tiles of 256 cols.
__global__ __launch_bounds__(256) void merge_pair(const float* __restrict__ ml,
                                                  const float* __restrict__ ll,
                                                  f16* __restrict__ scl) {
  int i = blockIdx.x * 256 + threadIdx.x;  // 0..8191 = z2*4096 + row
  int z2 = i >> 12, row = i & 4095;
  const float* m = ml + z2 * 65536 + row;
  const float* lp = ll + z2 * 65536 + row;
  float a[16];
  float mg = -1e30f;
#pragma unroll 16
  for (int t = 0; t < 16; ++t) mg = fmaxf(mg, m[t * 4096]);
  float l = 0.f;
#pragma unroll 16
  for (int t = 0; t < 16; ++t) {
    a[t] = __expf(m[t * 4096] - mg);
    l += lp[t * 4096] * a[t];
  }
  float li = 1.0f / l;
#pragma unroll 16
  for (int t = 0; t < 16; ++t)
    scl[z2 * 65536 + t * 4096 + row] = (f16)(a[t] * li);
}

__global__ void sentinel(float* out) { out[0] = 12345.0f; }

// ------------- 8-phase 256x256 GEMM template (8 waves, BK=64) --------------
// C = epi(A @ B^T), B row-major [N][ldb].  NT = K/64 tiles.  If WRAPA, A's
// k-index wraps mod 1024 (K-concat dual-precision B).  GX = gridDim.x.
// EPI 6: probs = exp(S - rowmax_tile) f16 + mout/lout per (z,tn,row)
// EPI 1: f16 __cosf(v + aux[col])
template <int EPI, int NT, bool WRAPA, int GX>
__global__ __launch_bounds__(512, 2) void g8p(
    const f16* __restrict__ A, const f16* __restrict__ B,
    void* __restrict__ Cv, const float* __restrict__ aux,
    float* __restrict__ mout, float* __restrict__ lout, long sA, long sB,
    long sC, int lda, int ldb, int ldc) {
  constexpr int BUF = 65536;  // 64KB per dbuf: A(32KB)+B(32KB)
  __shared__ __align__(16) char smem[2 * BUF];
  __shared__ float red[EPI == 6 ? 4 : 1][EPI == 6 ? 256 : 1];
  // XCD-bijective swizzle over the 256 (tm,tn) blocks
  int lin = blockIdx.x + blockIdx.y * GX;
  lin = ((lin & 7) << 5) | (lin >> 3);
  const int tn = lin % GX, tm = lin / GX;
  const int z = blockIdx.z;
  const int t = threadIdx.x, w = t >> 6, l = t & 63;
  const int l4 = l >> 4, l15 = l & 15;
  const int wm = w >> 2, wn = w & 3;  // 2 x 4 waves; wave out = 128 x 64
  f32x4 acc[8][4] = {};
  const f16* Az = A + (long)z * sA;
  const f16* Bz = B + (long)z * sB;

  // half-tile stage: ht 0=A0,1=A1,2=B0,3=B1 ; 1024 chunks, 2 per thread
  auto STAGE_HT = [&](int buf, int tt, int ht) {
    const bool isA = (ht < 2);
    const f16* src = isA ? Az : Bz;
    const int ld = isA ? lda : ldb;
    const int row0 = (isA ? tm : tn) * 256 + (ht & 1) * 128;
    char* base = smem + buf * BUF + (ht >> 1) * 32768 + (ht & 1) * 16384;
    int kk = tt * 64;
    if (WRAPA && isA) kk &= 1023;
#pragma unroll
    for (int j = 0; j < 2; ++j) {
      const int cb = j * 512 + w * 64;  // wave-uniform chunk base
      const int c = cb + l;
      const int r = c >> 3, s = c & 7;
      async_copy16(base + cb * 16,
                   src + (long)(row0 + r) * ld + kk + (s ^ (r & 7)) * 8);
    }
  };

  // prologue: tile0 full + B halves of tile1;  vmcnt(4) -> tile0 resident
  STAGE_HT(0, 0, 0);
  STAGE_HT(0, 0, 1);
  STAGE_HT(0, 0, 2);
  STAGE_HT(0, 0, 3);
  STAGE_HT(1, 1, 2);
  STAGE_HT(1, 1, 3);
  asm volatile("s_waitcnt vmcnt(4)" ::: "memory");
  __builtin_amdgcn_s_barrier();

  for (int it = 0; it < NT / 2; ++it) {
    const int tt = 2 * it;
    const bool more = (tt + 2) < NT;
    // ---- phases 1-4: compute tile tt from buf0 ----
    {
      const f16* Ab = (const f16*)(smem);
      const f16* Bb = Ab + 16384;  // +32KB
      f16x8 bfp[4][2];
#pragma unroll
      for (int q = 0; q < 4; ++q) {
        if (q == 0) {
#pragma unroll
          for (int jn = 0; jn < 4; ++jn)
#pragma unroll
            for (int ks = 0; ks < 2; ++ks) {
              const int rb = wn * 64 + jn * 16 + l15;
              const int p = ks * 4 + l4;
              bfp[jn][ks] = *(const f16x8*)&Bb[rb * 64 + (p ^ (rb & 7)) * 8];
            }
        }
        f16x8 af[2][2];
#pragma unroll
        for (int i2 = 0; i2 < 2; ++i2)
#pragma unroll
          for (int ks = 0; ks < 2; ++ks) {
            const int ra = wm * 128 + (q * 2 + i2) * 16 + l15;
            const int p = ks * 4 + l4;
            af[i2][ks] = *(const f16x8*)&Ab[ra * 64 + (p ^ (ra & 7)) * 8];
          }
        if (q == 0) STAGE_HT(1, tt + 1, 0);
        if (q == 1) STAGE_HT(1, tt + 1, 1);
        if (q == 2 && more) STAGE_HT(0, tt + 2, 2);
        if (q == 3) {
          if (more) {
            STAGE_HT(0, tt + 2, 3);
            asm volatile("s_waitcnt vmcnt(4)" ::: "memory");
          } else {
            asm volatile("s_waitcnt vmcnt(0)" ::: "memory");
          }
        }
        __builtin_amdgcn_s_barrier();
        asm volatile("s_waitcnt lgkmcnt(0)" ::: "memory");
        __builtin_amdgcn_s_setprio(1);
#pragma unroll
        for (int i2 = 0; i2 < 2; ++i2)
#pragma unroll
          for (int jn = 0; jn < 4; ++jn)
#pragma unroll
            for (int ks = 0; ks < 2; ++ks)
              acc[q * 2 + i2][jn] = __builtin_amdgcn_mfma_f32_16x16x32_f16(
                  af[i2][ks], bfp[jn][ks], acc[q * 2 + i2][jn], 0, 0, 0);
        __builtin_amdgcn_s_setprio(0);
        __builtin_amdgcn_s_barrier();
      }
    }
    // ---- phases 5-8: compute tile tt+1 from buf1 ----
    {
      const f16* Ab = (const f16*)(smem + BUF);
      const f16* Bb = Ab + 16384;
      f16x8 bfp[4][2];
#pragma unroll
      for (int q = 0; q < 4; ++q) {
        if (q == 0) {
#pragma unroll
          for (int jn = 0; jn < 4; ++jn)
#pragma unroll
            for (int ks = 0; ks < 2; ++ks) {
              const int rb = wn * 64 + jn * 16 + l15;
              const int p = ks * 4 + l4;
              bfp[jn][ks] = *(const f16x8*)&Bb[rb * 64 + (p ^ (rb & 7)) * 8];
            }
        }
        f16x8 af[2][2];
#pragma unroll
        for (int i2 = 0; i2 < 2; ++i2)
#pragma unroll
          for (int ks = 0; ks < 2; ++ks) {
            const int ra = wm * 128 + (q * 2 + i2) * 16 + l15;
            const int p = ks * 4 + l4;
            af[i2][ks] = *(const f16x8*)&Ab[ra * 64 + (p ^ (ra & 7)) * 8];
          }
        if (q == 0 && more) STAGE_HT(0, tt + 2, 0);
        if (q == 1 && more) STAGE_HT(0, tt + 2, 1);
        if (q == 2 && more) STAGE_HT(1, tt + 3, 2);
        if (q == 3) {
          if (more) {
            STAGE_HT(1, tt + 3, 3);
            asm volatile("s_waitcnt vmcnt(4)" ::: "memory");
          } else {
            asm volatile("s_waitcnt vmcnt(0)" ::: "memory");
          }
        }
        __builtin_amdgcn_s_barrier();
        asm volatile("s_waitcnt lgkmcnt(0)" ::: "memory");
        __builtin_amdgcn_s_setprio(1);
#pragma unroll
        for (int i2 = 0; i2 < 2; ++i2)
#pragma unroll
          for (int jn = 0; jn < 4; ++jn)
#pragma unroll
            for (int ks = 0; ks < 2; ++ks)
              acc[q * 2 + i2][jn] = __builtin_amdgcn_mfma_f32_16x16x32_f16(
                  af[i2][ks], bfp[jn][ks], acc[q * 2 + i2][jn], 0, 0, 0);
        __builtin_amdgcn_s_setprio(0);
        __builtin_amdgcn_s_barrier();
      }
    }
  }

  if constexpr (EPI == 1) {
#pragma unroll
    for (int i = 0; i < 8; ++i) {
      const int row0 = tm * 256 + wm * 128 + i * 16 + l4 * 4;
#pragma unroll
      for (int jn = 0; jn < 4; ++jn) {
        const int col = tn * 256 + wn * 64 + jn * 16 + l15;
#pragma unroll
        for (int r = 0; r < 4; ++r)
          ((f16*)Cv)[(long)z * sC + (long)(row0 + r) * ldc + col] =
              (f16)__cosf(acc[i][jn][r] + aux[col]);
      }
    }
    return;
  }

  // ---- EPI 6: tile-local softmax over this 256-col tile ----
  float mrow[32];
#pragma unroll
  for (int i = 0; i < 8; ++i)
#pragma unroll
    for (int r = 0; r < 4; ++r) {
      float v = fmaxf(fmaxf(acc[i][0][r], acc[i][1][r]),
                      fmaxf(acc[i][2][r], acc[i][3][r]));
      v = fmaxf(v, __shfl_xor(v, 1));
      v = fmaxf(v, __shfl_xor(v, 2));
      v = fmaxf(v, __shfl_xor(v, 4));
      v = fmaxf(v, __shfl_xor(v, 8));
      if (l15 == 0) red[wn][wm * 128 + i * 16 + l4 * 4 + r] = v;
    }
  __syncthreads();
#pragma unroll
  for (int i = 0; i < 8; ++i)
#pragma unroll
    for (int r = 0; r < 4; ++r) {
      const int rin = wm * 128 + i * 16 + l4 * 4 + r;
      mrow[i * 4 + r] = fmaxf(fmaxf(red[0][rin], red[1][rin]),
                              fmaxf(red[2][rin], red[3][rin]));
    }
  __syncthreads();
#pragma unroll
  for (int i = 0; i < 8; ++i)
#pragma unroll
    for (int r = 0; r < 4; ++r) {
      const float mn = mrow[i * 4 + r];
      float s = 0.f;
#pragma unroll
      for (int jn = 0; jn < 4; ++jn) {
        float e = __expf(acc[i][jn][r] - mn);
        acc[i][jn][r] = e;
        s += e;
      }
      s += __shfl_xor(s, 1);
      s += __shfl_xor(s, 2);
      s += __shfl_xor(s, 4);
      s += __shfl_xor(s, 8);
      if (l15 == 0) red[wn][wm * 128 + i * 16 + l4 * 4 + r] = s;
    }
  __syncthreads();
  if (wn == 0 && l15 == 0) {
#pragma unroll
    for (int i = 0; i < 8; ++i)
#pragma unroll
      for (int r = 0; r < 4; ++r) {
        const int rin = wm * 128 + i * 16 + l4 * 4 + r;
        const int gidx = z * 65536 + tn * 4096 + tm * 256 + rin;
        mout[gidx] = mrow[i * 4 + r];
        lout[gidx] = red[0][rin] + red[1][rin] + red[2][rin] + red[3][rin];
      }
  }
#pragma unroll
  for (int i = 0; i < 8; ++i) {
    const int row0 = tm * 256 + wm * 128 + i * 16 + l4 * 4;
#pragma unroll
    for (int jn = 0; jn < 4; ++jn) {
      const int col = tn * 256 + wn * 64 + jn * 16 + l15;
#pragma unroll
      for (int r = 0; r < 4; ++r)
        ((f16*)Cv)[(long)z * sC + (long)(row0 + r) * ldc + col] =
            (f16)acc[i][jn][r];
    }
  }
}

// ------------------------------- main GEMM --------------------------------
// C[M,N] = epilogue( A@B^T [+ A@Bl^T if DB] [+ Al@B^T if DA] )
// B stored row-major [N,K].  128x128 tile, 4 waves, 4x4 16x16x32 frags/wave.
// Double-buffered LDS, 2-phase pipeline, counted vmcnt (never 0 in loop).
// EPI: 2 f16 v+aux[row] | 5 f32 plain
//      7 f32 plain, A-fragments scaled by ascl[ktile256][arow] (LDS-staged)
template <int EPI, bool DA, bool DB, int BK>
__global__ __launch_bounds__(256) void gemm_bt(
    const f16* __restrict__ Ah, const f16* __restrict__ Al,
    const f16* __restrict__ Bh, const f16* __restrict__ Bl,
    void* __restrict__ Cv, const float* __restrict__ aux,
    const f16* __restrict__ ascl, long sAscl, int M, int N, int K, int lda,
    int ldb, int ldc, long sC, long sA, long sB, int sAux) {
  constexpr int NSTAGE = 2 + (DA ? 1 : 0) + (DB ? 1 : 0);
  constexpr int TILE = 128 * BK * 2;    // bytes per operand tile
  constexpr int CPR = BK / 8;           // 16B chunks per row
  constexpr int CH = 128 * CPR;         // chunks per operand tile
  constexpr int NL = NSTAGE * BK / 16;  // per-thread vmem issues per tile
  static_assert(NL == 6 || NL == 8, "vmcnt literal");
  constexpr int SCLB = (EPI == 7) ? 4096 : 0;
  __shared__ __align__(16) char smem[2 * NSTAGE * TILE + SCLB];

  const int z = blockIdx.z;
  const int tn = blockIdx.x, tm = blockIdx.y;
  const int t = threadIdx.x, w = t >> 6, l = t & 63;
  const int l4 = l >> 4, l15 = l & 15;
  const int wm = w & 1, wn = w >> 1;
  f32x4 acc[4][4] = {};

  const f16* Az = Ah + (long)z * sA;
  const f16* Bz = Bh + (long)z * sB;
  const f16* Alz = nullptr;
  const f16* Blz = nullptr;
  if constexpr (DA) Alz = Al + (long)z * sA;
  if constexpr (DB) Blz = Bl + (long)z * sB;
  f16* sclLds = (f16*)(smem + 2 * NSTAGE * TILE);

  auto swz = [](int r, int p) -> int {
    if constexpr (BK == 64) return p ^ (r & 7);
    else return p ^ ((r >> 1) & 3);
  };

  auto STAGE = [&](int buf, int kk) {
    char* base = smem + buf * (NSTAGE * TILE);
#pragma unroll
    for (int j = 0; j < CH / 256; ++j) {
      const int cb = j * 256 + w * 64;  // wave-uniform chunk base
      const int c = cb + l;
      const int r = c / CPR, pp = c % CPR;
      const int sc = swz(r, pp);
      const long ra = (long)(tm * 128 + r) * lda + kk + sc * 8;
      const long rb = (long)(tn * 128 + r) * ldb + kk + sc * 8;
      async_copy16(base + cb * 16, Az + ra);
      async_copy16(base + TILE + cb * 16, Bz + rb);
      if constexpr (DA) async_copy16(base + 2 * TILE + cb * 16, Alz + ra);
      if constexpr (DB)
        async_copy16(base + (2 + (DA ? 1 : 0)) * TILE + cb * 16, Blz + rb);
    }
  };

  // ---- prologue: stage tile 0 (+ scl table for EPI 7), drain, barrier ----
  STAGE(0, 0);
  if constexpr (EPI == 7) {
    const f16* asclz = ascl + (long)z * sAscl;
    // 16 k-tiles x 128 rows f16 -> 256 chunks; LDS idx c*8 = tile*128 + row
    const int cb = w * 64;
    const int c = cb + l;
    async_copy16(sclLds + cb * 8,
                 asclz + (long)(c >> 4) * M + tm * 128 + (c & 15) * 8);
  }
  asm volatile("s_waitcnt vmcnt(0)" ::: "memory");
  __syncthreads();

  const int nt = K / BK;
  int cur = 0;
  for (int tt = 0; tt < nt; ++tt) {
    const int kk = tt * BK;
    if (tt + 1 < nt) {
      STAGE(cur ^ 1, kk + BK);
      if constexpr (NL == 6)
        asm volatile("s_waitcnt vmcnt(6)" ::: "memory");
      else
        asm volatile("s_waitcnt vmcnt(8)" ::: "memory");
    } else {
      asm volatile("s_waitcnt vmcnt(0)" ::: "memory");
    }
    __syncthreads();

    const f16* As = (const f16*)(smem + cur * (NSTAGE * TILE));
    const f16* Bs = As + TILE / 2;
    const f16* Als = Bs + TILE / 2;
    const f16* Bls = Als + (DA ? TILE / 2 : 0);

    f16 sA4[4];
    if constexpr (EPI == 7) {
      const int tile = kk >> 8;  // 256-wide k-tiles
#pragma unroll
      for (int i = 0; i < 4; ++i)
        sA4[i] = sclLds[tile * 128 + wm * 64 + i * 16 + l15];
    }

#pragma unroll
    for (int ks = 0; ks < BK / 32; ++ks) {
      f16x8 af[4], bf[4];
#pragma unroll
      for (int i = 0; i < 4; ++i) {
        const int ra = wm * 64 + i * 16 + l15;
        const int rb = wn * 64 + i * 16 + l15;
        af[i] = *(const f16x8*)&As[ra * BK + swz(ra, ks * 4 + l4) * 8];
        bf[i] = *(const f16x8*)&Bs[rb * BK + swz(rb, ks * 4 + l4) * 8];
      }
      if constexpr (EPI == 7) {
#pragma unroll
        for (int i = 0; i < 4; ++i) af[i] = af[i] * sA4[i];
      }
#pragma unroll
      for (int i = 0; i < 4; ++i)
#pragma unroll
        for (int jn = 0; jn < 4; ++jn)
          acc[i][jn] = __builtin_amdgcn_mfma_f32_16x16x32_f16(af[i], bf[jn],
                                                              acc[i][jn], 0, 0, 0);
      if constexpr (DB) {
        f16x8 bl[4];
#pragma unroll
        for (int i = 0; i < 4; ++i) {
          const int rb = wn * 64 + i * 16 + l15;
          bl[i] = *(const f16x8*)&Bls[rb * BK + swz(rb, ks * 4 + l4) * 8];
        }
#pragma unroll
        for (int i = 0; i < 4; ++i)
#pragma unroll
          for (int jn = 0; jn < 4; ++jn)
            acc[i][jn] = __builtin_amdgcn_mfma_f32_16x16x32_f16(
                af[i], bl[jn], acc[i][jn], 0, 0, 0);
      }
      if constexpr (DA) {
        f16x8 al[4];
#pragma unroll
        for (int i = 0; i < 4; ++i) {
          const int ra = wm * 64 + i * 16 + l15;
          al[i] = *(const f16x8*)&Als[ra * BK + swz(ra, ks * 4 + l4) * 8];
        }
#pragma unroll
        for (int i = 0; i < 4; ++i)
#pragma unroll
          for (int jn = 0; jn < 4; ++jn)
            acc[i][jn] = __builtin_amdgcn_mfma_f32_16x16x32_f16(
                al[i], bf[jn], acc[i][jn], 0, 0, 0);
      }
    }
    __syncthreads();
    cur ^= 1;
  }

  const float* auxp = aux + (long)z * sAux;

  if constexpr (EPI == 2) {
    // ---- f16 output via LDS repack: [64][136] per half ----
    f16* rep = (f16*)smem;
#pragma unroll
    for (int hh = 0; hh < 2; ++hh) {
      __syncthreads();
#pragma unroll
      for (int ii = 0; ii < 2; ++ii) {
        const int i = hh * 2 + ii;
        const int lrow0 = wm * 32 + ii * 16 + l4 * 4;
#pragma unroll
        for (int jn = 0; jn < 4; ++jn) {
          const int col = wn * 64 + jn * 16 + l15;
#pragma unroll
          for (int r = 0; r < 4; ++r) {
            float v = acc[i][jn][r];
            f16 hv = (f16)(v + auxp[tm * 128 + wm * 64 + i * 16 + l4 * 4 + r]);
            rep[(lrow0 + r) * 136 + col] = hv;
          }
        }
      }
      __syncthreads();
#pragma unroll
      for (int pp = 0; pp < 4; ++pp) {
        const int lrow = pp * 16 + (t >> 4);
        const int grow = tm * 128 + (lrow >> 5) * 64 + hh * 32 + (lrow & 31);
        const int gcol = tn * 128 + (t & 15) * 8;
        *(f16x8*)&((f16*)Cv)[(long)z * sC + (long)grow * ldc + gcol] =
            *(const f16x8*)&rep[lrow * 136 + (t & 15) * 8];
      }
    }
  } else {
    // ---- f32 output via LDS repack: [32][132] per i-group ----
    float* rep = (float*)smem;
#pragma unroll
    for (int i = 0; i < 4; ++i) {
      __syncthreads();
      const int lrow0 = wm * 16 + l4 * 4;
#pragma unroll
      for (int jn = 0; jn < 4; ++jn) {
        const int col = wn * 64 + jn * 16 + l15;
#pragma unroll
        for (int r = 0; r < 4; ++r) rep[(lrow0 + r) * 132 + col] = acc[i][jn][r];
      }
      __syncthreads();
#pragma unroll
      for (int pp = 0; pp < 4; ++pp) {
        const int lrow = pp * 8 + (t >> 5);
        const int grow = tm * 128 + (lrow >> 4) * 64 + i * 16 + (lrow & 15);
        const int gcol = tn * 128 + (t & 31) * 4;
        *(float4*)&((float*)Cv)[(long)z * sC + (long)grow * ldc + gcol] =
            *(const float4*)&rep[lrow * 132 + (t & 31) * 4];
      }
    }
  }
}

// --------------------------------- driver ----------------------------------

extern "C" void kernel_launch(void* const* d_in, const int* in_sizes, int n_in,
                              void* d_out, int out_size, void* d_ws,
                              size_t ws_size, hipStream_t stream) {
  const float* query = (const float*)d_in[0];
  const float* value = (const float*)d_in[1];
  const float* Wq = (const float*)d_in[2];
  const float* bq = (const float*)d_in[3];
  const float* Wk = (const float*)d_in[4];
  const float* bk = (const float*)d_in[5];
  const float* Wv = (const float*)d_in[6];
  const float* bv = (const float*)d_in[7];
  const float* Wr = (const float*)d_in[8];
  const float* br = (const float*)d_in[9];
  float* out = (float*)d_out;

  if (ws_size < 169000000ull) {
    sentinel<<<1, 1, 0, stream>>>(out);
    return;
  }

  char* p = (char*)d_ws;
  auto alloc = [&](size_t bytes) {
    char* r = p;
    p += (bytes + 255) & ~(size_t)255;
    return r;
  };
  const size_t QV = 16777216ull;  // B*S*D elements
  const size_t WW = 1048576ull;   // 1024*1024 elements
  char* bufA = alloc(QV * 2);  // q16 -> Khat
  char* bufB = alloc(QV * 2);  // v16 -> probs z-even (32MB)
  char* bufC = alloc(QV * 2);  // Qhat
  char* bufD = alloc(QV * 2);  // VT
  f16* q16 = (f16*)bufA;
  f16* Khat = (f16*)bufA;
  f16* v16 = (f16*)bufB;
  f16* probs0 = (f16*)bufB;  // pair slot 0; slot 1 = weights region (+96MB)
  f16* Qhat = (f16*)bufC;
  f16* VT = (f16*)bufD;
  // weights region: 32 MB from Wq_h onward is reused as probs slot 1
  f16* Wq_h = (f16*)alloc(WW * 2);
  f16* Wq_l = (f16*)alloc(WW * 2);
  f16* Wk_h = (f16*)alloc(WW * 2);
  f16* Wk_l = (f16*)alloc(WW * 2);
  f16* Wr_h = (f16*)alloc(WW * 2);
  f16* Wr_l = (f16*)alloc(WW * 2);
  f16* Wv16 = (f16*)alloc(WW * 2);
  f16* WrT_h = (f16*)alloc(WW * 2);
  f16* WrT_l = (f16*)alloc(WW * 2);
  f16* WvT = (f16*)alloc(WW * 2);
  float* Wtmp32 = (float*)alloc(WW * 8);   // [2][1024][1024] f32
  f16* WqrT2 = (f16*)alloc(WW * 4);        // [1024][2048] hi|lo concat
  f16* WkrT2 = (f16*)alloc(WW * 4);
  float* brq = (float*)alloc(1024 * 4);
  float* brk = (float*)alloc(1024 * 4);
  float* m_loc = (float*)alloc(2 * 16 * 4096 * 4);  // [z2][tn256][row]
  float* l_loc = (float*)alloc(2 * 16 * 4096 * 4);
  f16* scl = (f16*)alloc(2 * 16 * 4096 * 2);  // [z2][tile256][row] = alpha/l
  const long PSTRIDE = 50331648;  // f16 elems between probs slot 0 and slot 1

  // fp32 -> fp16 conversions (split for W matrices feeding Wqr/Wkr)
  f2h<<<16384, 256, 0, stream>>>(query, q16, 4194304);
  f2h<<<16384, 256, 0, stream>>>(value, v16, 4194304);
  f2h_split<<<1024, 256, 0, stream>>>(Wq, Wq_h, Wq_l, 262144);
  f2h_split<<<1024, 256, 0, stream>>>(Wk, Wk_h, Wk_l, 262144);
  f2h_split<<<1024, 256, 0, stream>>>(Wr, Wr_h, Wr_l, 262144);
  f2h<<<1024, 256, 0, stream>>>(Wv, Wv16, 262144);
  tr_h<<<dim3(32, 32), dim3(32, 32), 0, stream>>>(Wr_h, WrT_h, 1024, 1024);
  tr_h<<<dim3(32, 32), dim3(32, 32), 0, stream>>>(Wr_l, WrT_l, 1024, 1024);
  tr_h<<<dim3(32, 32), dim3(32, 32), 0, stream>>>(Wv16, WvT, 1024, 1024);
  bias_fold<<<4, 256, 0, stream>>>(br, bq, Wr, brq);
  bias_fold<<<4, 256, 0, stream>>>(br, bk, Wr, brk);

  // W{q,k}rT = Wr^T @ W{q,k}^T in ~fp32 (Ah@Bh + Ah@Bl + Al@Bh), one z=2 pass
  gemm_bt<5, true, true, 32><<<dim3(8, 8, 2), 256, 0, stream>>>(
      WrT_h, WrT_l, Wq_h, Wq_l, Wtmp32, nullptr, nullptr, 0, 1024, 1024, 1024,
      1024, 1024, 1024, 1048576, 0, 2097152, 0);
  f2h_split2<<<1024, 256, 0, stream>>>(Wtmp32, WqrT2, 262144);
  f2h_split2<<<1024, 256, 0, stream>>>(Wtmp32 + 1048576, WkrT2, 262144);

  // Qhat = cos(query @ Wqr + brq)   [bufC]  (K-concat dual-B, K'=2048)
  g8p<1, 32, true, 4><<<dim3(4, 64, 1), 512, 0, stream>>>(
      q16, WqrT2, Qhat, brq, nullptr, nullptr, 0, 0, 0, 1024, 2048, 1024);
  // Khat = cos(value @ Wkr + brk)   [bufA — q16 dead from here]
  g8p<1, 32, true, 4><<<dim3(4, 64, 1), 512, 0, stream>>>(
      v16, WkrT2, Khat, brk, nullptr, nullptr, 0, 0, 0, 1024, 2048, 1024);
  // VT[u][s] = (value @ Wv + bv)^T = Wv^T @ value^T  (row bias bv)  [bufD]
  gemm_bt<2, false, false, 64><<<dim3(128, 8, 1), 256, 0, stream>>>(
      WvT, nullptr, v16, nullptr, VT, bv, nullptr, 0, 1024, 16384, 1024, 1024,
      1024, 16384, 0, 0, 0, 0);

  // per batch-pair: probs = exp(S - m_tile) + stats; merge; PV (scale folded)
  for (int zb = 0; zb < NB; zb += 2) {
    g8p<6, 16, false, 16><<<dim3(16, 16, 2), 512, 0, stream>>>(
        Qhat + (long)zb * 4194304, Khat + (long)zb * 4194304, probs0, nullptr,
        m_loc, l_loc, 4194304, 4194304, PSTRIDE, 1024, 1024, 4096);
    merge_pair<<<32, 256, 0, stream>>>(m_loc, l_loc, scl);
    gemm_bt<7, false, false, 64><<<dim3(8, 32, 2), 256, 0, stream>>>(
        probs0, nullptr, VT + (long)zb * 4096, nullptr, out + (long)zb * 4194304,
        nullptr, scl, 65536, 4096, 1024, 4096, 4096, 16384, 1024, 4194304,
        PSTRIDE, 4096, 0);
  }
}

// Round 11
// 621.233 us; speedup vs baseline: 1.2348x; 1.1024x over previous
//
#include <hip/hip_runtime.h>
#include <hip/hip_bf16.h>
#include <hip/hip_fp16.h>
#include <cstdint>

// ---------------------------------------------------------------------------
// LinearAttention (random-feature cos kernel + softmax attention), MI355X.
// out = softmax(cos(q@Wq@Wr + br) @ cos(v@Wk@Wr + br)^T) @ (v@Wv + bv)
// B=4, S=4096, D=U=F=1024.  All heavy math in fp16 MFMA with fp32 accum.
// qk + Qhat/Khat: 256x256 / 8 waves / BK=64 / 8-phase, counted vmcnt(4),
//   vectorized epilogue via LDS repack (full-line f16x8 stores).
// PV/VT/Wqr: 128x128 2-phase counted-vmcnt.
// Softmax: tile-local max in QK^T epilogue + alpha/l folded into PV.
// ---------------------------------------------------------------------------

typedef _Float16 f16;
typedef _Float16 f16x8 __attribute__((ext_vector_type(8)));
typedef _Float16 f16x4 __attribute__((ext_vector_type(4)));
typedef float f32x4 __attribute__((ext_vector_type(4)));

typedef __attribute__((address_space(1))) unsigned int uas1;
typedef __attribute__((address_space(3))) unsigned int uas3;

#define NB 4
#define SEQ 4096
#define DIM 1024

// async 16B/lane global->LDS. LDS dest must be wave-uniform base (+lane*16).
__device__ __forceinline__ void async_copy16(void* lds, const void* g) {
  __builtin_amdgcn_global_load_lds((uas1*)(uintptr_t)g, (uas3*)(uintptr_t)lds,
                                   16, 0, 0);
}

// ----------------------------- small kernels ------------------------------

// query+value -> f16 in one dispatch (grid 32768)
__global__ __launch_bounds__(256) void f2h_qv(const float* __restrict__ a,
                                              const float* __restrict__ b,
                                              f16* __restrict__ oa,
                                              f16* __restrict__ ob) {
  const int bid = blockIdx.x;
  const float* in = bid < 16384 ? a : b;
  f16* out = bid < 16384 ? oa : ob;
  const int i = (bid & 16383) * 256 + threadIdx.x;
  float4 v = ((const float4*)in)[i];
  f16x4 h = {(f16)v.x, (f16)v.y, (f16)v.z, (f16)v.w};
  ((f16x4*)out)[i] = h;
}

__global__ __launch_bounds__(256) void f2h(const float* __restrict__ in,
                                           f16* __restrict__ out, int n4) {
  int i = blockIdx.x * 256 + threadIdx.x;
  if (i < n4) {
    float4 v = ((const float4*)in)[i];
    f16x4 h = {(f16)v.x, (f16)v.y, (f16)v.z, (f16)v.w};
    ((f16x4*)out)[i] = h;
  }
}

__global__ __launch_bounds__(256) void f2h_split(const float* __restrict__ in,
                                                 f16* __restrict__ hi,
                                                 f16* __restrict__ lo, int n4) {
  int i = blockIdx.x * 256 + threadIdx.x;
  if (i < n4) {
    float4 v = ((const float4*)in)[i];
    f16 h0 = (f16)v.x, h1 = (f16)v.y, h2 = (f16)v.z, h3 = (f16)v.w;
    f16x4 hv = {h0, h1, h2, h3};
    f16x4 lv = {(f16)(v.x - (float)h0), (f16)(v.y - (float)h1),
                (f16)(v.z - (float)h2), (f16)(v.w - (float)h3)};
    ((f16x4*)hi)[i] = hv;
    ((f16x4*)lo)[i] = lv;
  }
}

// split to hi/lo CONCATENATED along K: w2[n][k]=hi, w2[n][1024+k]=lo
__global__ __launch_bounds__(256) void f2h_split2(const float* __restrict__ in,
                                                  f16* __restrict__ w2, int n4) {
  int i = blockIdx.x * 256 + threadIdx.x;
  if (i < n4) {
    float4 v = ((const float4*)in)[i];
    f16 h0 = (f16)v.x, h1 = (f16)v.y, h2 = (f16)v.z, h3 = (f16)v.w;
    f16x4 hv = {h0, h1, h2, h3};
    f16x4 lv = {(f16)(v.x - (float)h0), (f16)(v.y - (float)h1),
                (f16)(v.z - (float)h2), (f16)(v.w - (float)h3)};
    const int n = i >> 8, k4 = i & 255;
    ((f16x4*)(w2 + (long)n * 2048))[k4] = hv;
    ((f16x4*)(w2 + (long)n * 2048 + 1024))[k4] = lv;
  }
}

// 3 transposes (1024x1024 f16) in one dispatch; z selects pair
__global__ void tr3(const f16* __restrict__ i0, f16* __restrict__ o0,
                    const f16* __restrict__ i1, f16* __restrict__ o1,
                    const f16* __restrict__ i2, f16* __restrict__ o2) {
  __shared__ f16 tile[32][33];
  const f16* in = blockIdx.z == 0 ? i0 : blockIdx.z == 1 ? i1 : i2;
  f16* out = blockIdx.z == 0 ? o0 : blockIdx.z == 1 ? o1 : o2;
  int c0 = blockIdx.x * 32, r0 = blockIdx.y * 32;
  tile[threadIdx.y][threadIdx.x] =
      in[(long)(r0 + threadIdx.y) * 1024 + c0 + threadIdx.x];
  __syncthreads();
  out[(long)(c0 + threadIdx.y) * 1024 + r0 + threadIdx.x] =
      tile[threadIdx.x][threadIdx.y];
}

// bias_eff = br + bvec @ Wr, deterministic 2-stage (partials then reduce)
__global__ __launch_bounds__(256) void bias_part(const float* __restrict__ bq,
                                                 const float* __restrict__ bk,
                                                 const float* __restrict__ Wr,
                                                 float* __restrict__ part) {
  const float* bvec = blockIdx.z ? bk : bq;
  const int f = blockIdx.x * 256 + threadIdx.x;
  const int u0 = blockIdx.y * 64;
  float s = 0.f;
#pragma unroll 8
  for (int u = 0; u < 64; ++u)
    s = fmaf(bvec[u0 + u], Wr[(long)(u0 + u) * DIM + f], s);
  part[(blockIdx.z * 16 + blockIdx.y) * 1024 + f] = s;
}

__global__ __launch_bounds__(256) void bias_red(const float* __restrict__ br,
                                                const float* __restrict__ part,
                                                float* __restrict__ brq,
                                                float* __restrict__ brk) {
  const int f = blockIdx.x * 256 + threadIdx.x;
  float* outb = blockIdx.z ? brk : brq;
  float s = br[f];
#pragma unroll 16
  for (int j = 0; j < 16; ++j) s += part[(blockIdx.z * 16 + j) * 1024 + f];
  outb[f] = s;
}

// per (z2,row): m = max_t m_t; l = sum_t l_t exp(m_t-m);
// scl[t][row] = exp(m_t-m)/l  (f16).  16 tiles of 256 cols.
__global__ __launch_bounds__(256) void merge_pair(const float* __restrict__ ml,
                                                  const float* __restrict__ ll,
                                                  f16* __restrict__ scl) {
  int i = blockIdx.x * 256 + threadIdx.x;  // 0..8191 = z2*4096 + row
  int z2 = i >> 12, row = i & 4095;
  const float* m = ml + z2 * 65536 + row;
  const float* lp = ll + z2 * 65536 + row;
  float a[16];
  float mg = -1e30f;
#pragma unroll 16
  for (int t = 0; t < 16; ++t) mg = fmaxf(mg, m[t * 4096]);
  float l = 0.f;
#pragma unroll 16
  for (int t = 0; t < 16; ++t) {
    a[t] = __expf(m[t * 4096] - mg);
    l += lp[t * 4096] * a[t];
  }
  float li = 1.0f / l;
#pragma unroll 16
  for (int t = 0; t < 16; ++t)
    scl[z2 * 65536 + t * 4096 + row] = (f16)(a[t] * li);
}

__global__ void sentinel(float* out) { out[0] = 12345.0f; }

// ------------- 8-phase 256x256 GEMM template (8 waves, BK=64) --------------
// C = epi(A @ B^T), B row-major [N][ldb].  NT = K/64 tiles.  If WRAPA, A's
// k-index wraps mod 1024 (K-concat dual-precision B).  GX = gridDim.x.
// EPI 6: probs = exp(S - rowmax_tile) f16 + mout/lout per (z,tn,row)
// EPI 1: f16 __cosf(v + aux[col])
// Both write through an LDS repack (stride 264) -> full-line f16x8 stores.
template <int EPI, int NT, bool WRAPA, int GX>
__global__ __launch_bounds__(512, 2) void g8p(
    const f16* __restrict__ A, const f16* __restrict__ B,
    void* __restrict__ Cv, const float* __restrict__ aux,
    float* __restrict__ mout, float* __restrict__ lout, long sA, long sB,
    long sC, int lda, int ldb, int ldc) {
  constexpr int BUF = 65536;  // 64KB per dbuf: A(32KB)+B(32KB)
  __shared__ __align__(16) char smem[256 * 264 * 2];  // >= 2*BUF; repack space
  __shared__ float red[EPI == 6 ? 4 : 1][EPI == 6 ? 256 : 1];
  // XCD-bijective swizzle over the 256 (tm,tn) blocks
  int lin = blockIdx.x + blockIdx.y * GX;
  lin = ((lin & 7) << 5) | (lin >> 3);
  const int tn = lin % GX, tm = lin / GX;
  const int z = blockIdx.z;
  const int t = threadIdx.x, w = t >> 6, l = t & 63;
  const int l4 = l >> 4, l15 = l & 15;
  const int wm = w >> 2, wn = w & 3;  // 2 x 4 waves; wave out = 128 x 64
  f32x4 acc[8][4] = {};
  const f16* Az = A + (long)z * sA;
  const f16* Bz = B + (long)z * sB;

  // half-tile stage: ht 0=A0,1=A1,2=B0,3=B1 ; 1024 chunks, 2 per thread
  auto STAGE_HT = [&](int buf, int tt, int ht) {
    const bool isA = (ht < 2);
    const f16* src = isA ? Az : Bz;
    const int ld = isA ? lda : ldb;
    const int row0 = (isA ? tm : tn) * 256 + (ht & 1) * 128;
    char* base = smem + buf * BUF + (ht >> 1) * 32768 + (ht & 1) * 16384;
    int kk = tt * 64;
    if (WRAPA && isA) kk &= 1023;
#pragma unroll
    for (int j = 0; j < 2; ++j) {
      const int cb = j * 512 + w * 64;  // wave-uniform chunk base
      const int c = cb + l;
      const int r = c >> 3, s = c & 7;
      async_copy16(base + cb * 16,
                   src + (long)(row0 + r) * ld + kk + (s ^ (r & 7)) * 8);
    }
  };

  // prologue: tile0 full + B halves of tile1;  vmcnt(4) -> tile0 resident
  STAGE_HT(0, 0, 0);
  STAGE_HT(0, 0, 1);
  STAGE_HT(0, 0, 2);
  STAGE_HT(0, 0, 3);
  STAGE_HT(1, 1, 2);
  STAGE_HT(1, 1, 3);
  asm volatile("s_waitcnt vmcnt(4)" ::: "memory");
  __builtin_amdgcn_s_barrier();

  for (int it = 0; it < NT / 2; ++it) {
    const int tt = 2 * it;
    const bool more = (tt + 2) < NT;
    // ---- phases 1-4: compute tile tt from buf0 ----
    {
      const f16* Ab = (const f16*)(smem);
      const f16* Bb = Ab + 16384;  // +32KB
      f16x8 bfp[4][2];
#pragma unroll
      for (int q = 0; q < 4; ++q) {
        if (q == 0) {
#pragma unroll
          for (int jn = 0; jn < 4; ++jn)
#pragma unroll
            for (int ks = 0; ks < 2; ++ks) {
              const int rb = wn * 64 + jn * 16 + l15;
              const int p = ks * 4 + l4;
              bfp[jn][ks] = *(const f16x8*)&Bb[rb * 64 + (p ^ (rb & 7)) * 8];
            }
        }
        f16x8 af[2][2];
#pragma unroll
        for (int i2 = 0; i2 < 2; ++i2)
#pragma unroll
          for (int ks = 0; ks < 2; ++ks) {
            const int ra = wm * 128 + (q * 2 + i2) * 16 + l15;
            const int p = ks * 4 + l4;
            af[i2][ks] = *(const f16x8*)&Ab[ra * 64 + (p ^ (ra & 7)) * 8];
          }
        if (q == 0) STAGE_HT(1, tt + 1, 0);
        if (q == 1) STAGE_HT(1, tt + 1, 1);
        if (q == 2 && more) STAGE_HT(0, tt + 2, 2);
        if (q == 3) {
          if (more) {
            STAGE_HT(0, tt + 2, 3);
            asm volatile("s_waitcnt vmcnt(4)" ::: "memory");
          } else {
            asm volatile("s_waitcnt vmcnt(0)" ::: "memory");
          }
        }
        __builtin_amdgcn_s_barrier();
        asm volatile("s_waitcnt lgkmcnt(0)" ::: "memory");
        __builtin_amdgcn_s_setprio(1);
#pragma unroll
        for (int i2 = 0; i2 < 2; ++i2)
#pragma unroll
          for (int jn = 0; jn < 4; ++jn)
#pragma unroll
            for (int ks = 0; ks < 2; ++ks)
              acc[q * 2 + i2][jn] = __builtin_amdgcn_mfma_f32_16x16x32_f16(
                  af[i2][ks], bfp[jn][ks], acc[q * 2 + i2][jn], 0, 0, 0);
        __builtin_amdgcn_s_setprio(0);
        __builtin_amdgcn_s_barrier();
      }
    }
    // ---- phases 5-8: compute tile tt+1 from buf1 ----
    {
      const f16* Ab = (const f16*)(smem + BUF);
      const f16* Bb = Ab + 16384;
      f16x8 bfp[4][2];
#pragma unroll
      for (int q = 0; q < 4; ++q) {
        if (q == 0) {
#pragma unroll
          for (int jn = 0; jn < 4; ++jn)
#pragma unroll
            for (int ks = 0; ks < 2; ++ks) {
              const int rb = wn * 64 + jn * 16 + l15;
              const int p = ks * 4 + l4;
              bfp[jn][ks] = *(const f16x8*)&Bb[rb * 64 + (p ^ (rb & 7)) * 8];
            }
        }
        f16x8 af[2][2];
#pragma unroll
        for (int i2 = 0; i2 < 2; ++i2)
#pragma unroll
          for (int ks = 0; ks < 2; ++ks) {
            const int ra = wm * 128 + (q * 2 + i2) * 16 + l15;
            const int p = ks * 4 + l4;
            af[i2][ks] = *(const f16x8*)&Ab[ra * 64 + (p ^ (ra & 7)) * 8];
          }
        if (q == 0 && more) STAGE_HT(0, tt + 2, 0);
        if (q == 1 && more) STAGE_HT(0, tt + 2, 1);
        if (q == 2 && more) STAGE_HT(1, tt + 3, 2);
        if (q == 3) {
          if (more) {
            STAGE_HT(1, tt + 3, 3);
            asm volatile("s_waitcnt vmcnt(4)" ::: "memory");
          } else {
            asm volatile("s_waitcnt vmcnt(0)" ::: "memory");
          }
        }
        __builtin_amdgcn_s_barrier();
        asm volatile("s_waitcnt lgkmcnt(0)" ::: "memory");
        __builtin_amdgcn_s_setprio(1);
#pragma unroll
        for (int i2 = 0; i2 < 2; ++i2)
#pragma unroll
          for (int jn = 0; jn < 4; ++jn)
#pragma unroll
            for (int ks = 0; ks < 2; ++ks)
              acc[q * 2 + i2][jn] = __builtin_amdgcn_mfma_f32_16x16x32_f16(
                  af[i2][ks], bfp[jn][ks], acc[q * 2 + i2][jn], 0, 0, 0);
        __builtin_amdgcn_s_setprio(0);
        __builtin_amdgcn_s_barrier();
      }
    }
  }

  if constexpr (EPI == 6) {
    // ---- tile-local softmax over this 256-col tile ----
    float mrow[32];
#pragma unroll
    for (int i = 0; i < 8; ++i)
#pragma unroll
      for (int r = 0; r < 4; ++r) {
        float v = fmaxf(fmaxf(acc[i][0][r], acc[i][1][r]),
                        fmaxf(acc[i][2][r], acc[i][3][r]));
        v = fmaxf(v, __shfl_xor(v, 1));
        v = fmaxf(v, __shfl_xor(v, 2));
        v = fmaxf(v, __shfl_xor(v, 4));
        v = fmaxf(v, __shfl_xor(v, 8));
        if (l15 == 0) red[wn][wm * 128 + i * 16 + l4 * 4 + r] = v;
      }
    __syncthreads();
#pragma unroll
    for (int i = 0; i < 8; ++i)
#pragma unroll
      for (int r = 0; r < 4; ++r) {
        const int rin = wm * 128 + i * 16 + l4 * 4 + r;
        mrow[i * 4 + r] = fmaxf(fmaxf(red[0][rin], red[1][rin]),
                                fmaxf(red[2][rin], red[3][rin]));
      }
    __syncthreads();
#pragma unroll
    for (int i = 0; i < 8; ++i)
#pragma unroll
      for (int r = 0; r < 4; ++r) {
        const float mn = mrow[i * 4 + r];
        float s = 0.f;
#pragma unroll
        for (int jn = 0; jn < 4; ++jn) {
          float e = __expf(acc[i][jn][r] - mn);
          acc[i][jn][r] = e;
          s += e;
        }
        s += __shfl_xor(s, 1);
        s += __shfl_xor(s, 2);
        s += __shfl_xor(s, 4);
        s += __shfl_xor(s, 8);
        if (l15 == 0) red[wn][wm * 128 + i * 16 + l4 * 4 + r] = s;
      }
    __syncthreads();
    if (wn == 0 && l15 == 0) {
#pragma unroll
      for (int i = 0; i < 8; ++i)
#pragma unroll
        for (int r = 0; r < 4; ++r) {
          const int rin = wm * 128 + i * 16 + l4 * 4 + r;
          const int gidx = z * 65536 + tn * 4096 + tm * 256 + rin;
          mout[gidx] = mrow[i * 4 + r];
          lout[gidx] = red[0][rin] + red[1][rin] + red[2][rin] + red[3][rin];
        }
    }
  }

  // ---- vectorized output: LDS repack (stride 264) -> f16x8 stores ----
  f16* rep = (f16*)smem;
#pragma unroll
  for (int i = 0; i < 8; ++i) {
    const int row0 = wm * 128 + i * 16 + l4 * 4;
#pragma unroll
    for (int jn = 0; jn < 4; ++jn) {
      const int col = wn * 64 + jn * 16 + l15;
#pragma unroll
      for (int r = 0; r < 4; ++r) {
        float v = acc[i][jn][r];
        f16 hv;
        if constexpr (EPI == 1)
          hv = (f16)__cosf(v + aux[tn * 256 + col]);
        else
          hv = (f16)v;
        rep[(row0 + r) * 264 + col] = hv;
      }
    }
  }
  __syncthreads();
#pragma unroll
  for (int k = 0; k < 16; ++k) {
    const int orow = k * 16 + (t >> 5);
    const int oc = (t & 31) * 8;
    *(f16x8*)&((f16*)Cv)[(long)z * sC + (long)(tm * 256 + orow) * ldc +
                         tn * 256 + oc] = *(const f16x8*)&rep[orow * 264 + oc];
  }
}

// ------------------------------- main GEMM --------------------------------
// C[M,N] = epilogue( A@B^T [+ A@Bl^T if DB] [+ Al@B^T if DA] )
// B stored row-major [N,K].  128x128 tile, 4 waves, 4x4 16x16x32 frags/wave.
// Double-buffered LDS, 2-phase pipeline, counted vmcnt (never 0 in loop).
// EPI: 2 f16 v+aux[row] | 5 f32 plain
//      7 f32 plain, A-fragments scaled by ascl[ktile256][arow] (LDS-staged)
template <int EPI, bool DA, bool DB, int BK>
__global__ __launch_bounds__(256) void gemm_bt(
    const f16* __restrict__ Ah, const f16* __restrict__ Al,
    const f16* __restrict__ Bh, const f16* __restrict__ Bl,
    void* __restrict__ Cv, const float* __restrict__ aux,
    const f16* __restrict__ ascl, long sAscl, int M, int N, int K, int lda,
    int ldb, int ldc, long sC, long sA, long sB, int sAux) {
  constexpr int NSTAGE = 2 + (DA ? 1 : 0) + (DB ? 1 : 0);
  constexpr int TILE = 128 * BK * 2;    // bytes per operand tile
  constexpr int CPR = BK / 8;           // 16B chunks per row
  constexpr int CH = 128 * CPR;         // chunks per operand tile
  constexpr int NL = NSTAGE * BK / 16;  // per-thread vmem issues per tile
  static_assert(NL == 6 || NL == 8, "vmcnt literal");
  constexpr int SCLB = (EPI == 7) ? 4096 : 0;
  __shared__ __align__(16) char smem[2 * NSTAGE * TILE + SCLB];

  const int z = blockIdx.z;
  const int tn = blockIdx.x, tm = blockIdx.y;
  const int t = threadIdx.x, w = t >> 6, l = t & 63;
  const int l4 = l >> 4, l15 = l & 15;
  const int wm = w & 1, wn = w >> 1;
  f32x4 acc[4][4] = {};

  const f16* Az = Ah + (long)z * sA;
  const f16* Bz = Bh + (long)z * sB;
  const f16* Alz = nullptr;
  const f16* Blz = nullptr;
  if constexpr (DA) Alz = Al + (long)z * sA;
  if constexpr (DB) Blz = Bl + (long)z * sB;
  f16* sclLds = (f16*)(smem + 2 * NSTAGE * TILE);

  auto swz = [](int r, int p) -> int {
    if constexpr (BK == 64) return p ^ (r & 7);
    else return p ^ ((r >> 1) & 3);
  };

  auto STAGE = [&](int buf, int kk) {
    char* base = smem + buf * (NSTAGE * TILE);
#pragma unroll
    for (int j = 0; j < CH / 256; ++j) {
      const int cb = j * 256 + w * 64;  // wave-uniform chunk base
      const int c = cb + l;
      const int r = c / CPR, pp = c % CPR;
      const int sc = swz(r, pp);
      const long ra = (long)(tm * 128 + r) * lda + kk + sc * 8;
      const long rb = (long)(tn * 128 + r) * ldb + kk + sc * 8;
      async_copy16(base + cb * 16, Az + ra);
      async_copy16(base + TILE + cb * 16, Bz + rb);
      if constexpr (DA) async_copy16(base + 2 * TILE + cb * 16, Alz + ra);
      if constexpr (DB)
        async_copy16(base + (2 + (DA ? 1 : 0)) * TILE + cb * 16, Blz + rb);
    }
  };

  // ---- prologue: stage tile 0 (+ scl table for EPI 7), drain, barrier ----
  STAGE(0, 0);
  if constexpr (EPI == 7) {
    const f16* asclz = ascl + (long)z * sAscl;
    // 16 k-tiles x 128 rows f16 -> 256 chunks; LDS idx c*8 = tile*128 + row
    const int cb = w * 64;
    const int c = cb + l;
    async_copy16(sclLds + cb * 8,
                 asclz + (long)(c >> 4) * M + tm * 128 + (c & 15) * 8);
  }
  asm volatile("s_waitcnt vmcnt(0)" ::: "memory");
  __syncthreads();

  const int nt = K / BK;
  int cur = 0;
  for (int tt = 0; tt < nt; ++tt) {
    const int kk = tt * BK;
    if (tt + 1 < nt) {
      STAGE(cur ^ 1, kk + BK);
      if constexpr (NL == 6)
        asm volatile("s_waitcnt vmcnt(6)" ::: "memory");
      else
        asm volatile("s_waitcnt vmcnt(8)" ::: "memory");
    } else {
      asm volatile("s_waitcnt vmcnt(0)" ::: "memory");
    }
    __syncthreads();

    const f16* As = (const f16*)(smem + cur * (NSTAGE * TILE));
    const f16* Bs = As + TILE / 2;
    const f16* Als = Bs + TILE / 2;
    const f16* Bls = Als + (DA ? TILE / 2 : 0);

    f16 sA4[4];
    if constexpr (EPI == 7) {
      const int tile = kk >> 8;  // 256-wide k-tiles
#pragma unroll
      for (int i = 0; i < 4; ++i)
        sA4[i] = sclLds[tile * 128 + wm * 64 + i * 16 + l15];
    }

#pragma unroll
    for (int ks = 0; ks < BK / 32; ++ks) {
      f16x8 af[4], bf[4];
#pragma unroll
      for (int i = 0; i < 4; ++i) {
        const int ra = wm * 64 + i * 16 + l15;
        const int rb = wn * 64 + i * 16 + l15;
        af[i] = *(const f16x8*)&As[ra * BK + swz(ra, ks * 4 + l4) * 8];
        bf[i] = *(const f16x8*)&Bs[rb * BK + swz(rb, ks * 4 + l4) * 8];
      }
      if constexpr (EPI == 7) {
#pragma unroll
        for (int i = 0; i < 4; ++i) af[i] = af[i] * sA4[i];
      }
#pragma unroll
      for (int i = 0; i < 4; ++i)
#pragma unroll
        for (int jn = 0; jn < 4; ++jn)
          acc[i][jn] = __builtin_amdgcn_mfma_f32_16x16x32_f16(af[i], bf[jn],
                                                              acc[i][jn], 0, 0, 0);
      if constexpr (DB) {
        f16x8 bl[4];
#pragma unroll
        for (int i = 0; i < 4; ++i) {
          const int rb = wn * 64 + i * 16 + l15;
          bl[i] = *(const f16x8*)&Bls[rb * BK + swz(rb, ks * 4 + l4) * 8];
        }
#pragma unroll
        for (int i = 0; i < 4; ++i)
#pragma unroll
          for (int jn = 0; jn < 4; ++jn)
            acc[i][jn] = __builtin_amdgcn_mfma_f32_16x16x32_f16(
                af[i], bl[jn], acc[i][jn], 0, 0, 0);
      }
      if constexpr (DA) {
        f16x8 al[4];
#pragma unroll
        for (int i = 0; i < 4; ++i) {
          const int ra = wm * 64 + i * 16 + l15;
          al[i] = *(const f16x8*)&Als[ra * BK + swz(ra, ks * 4 + l4) * 8];
        }
#pragma unroll
        for (int i = 0; i < 4; ++i)
#pragma unroll
          for (int jn = 0; jn < 4; ++jn)
            acc[i][jn] = __builtin_amdgcn_mfma_f32_16x16x32_f16(
                al[i], bf[jn], acc[i][jn], 0, 0, 0);
      }
    }
    __syncthreads();
    cur ^= 1;
  }

  const float* auxp = aux + (long)z * sAux;

  if constexpr (EPI == 2) {
    // ---- f16 output via LDS repack: [64][136] per half ----
    f16* rep = (f16*)smem;
#pragma unroll
    for (int hh = 0; hh < 2; ++hh) {
      __syncthreads();
#pragma unroll
      for (int ii = 0; ii < 2; ++ii) {
        const int i = hh * 2 + ii;
        const int lrow0 = wm * 32 + ii * 16 + l4 * 4;
#pragma unroll
        for (int jn = 0; jn < 4; ++jn) {
          const int col = wn * 64 + jn * 16 + l15;
#pragma unroll
          for (int r = 0; r < 4; ++r) {
            float v = acc[i][jn][r];
            f16 hv = (f16)(v + auxp[tm * 128 + wm * 64 + i * 16 + l4 * 4 + r]);
            rep[(lrow0 + r) * 136 + col] = hv;
          }
        }
      }
      __syncthreads();
#pragma unroll
      for (int pp = 0; pp < 4; ++pp) {
        const int lrow = pp * 16 + (t >> 4);
        const int grow = tm * 128 + (lrow >> 5) * 64 + hh * 32 + (lrow & 31);
        const int gcol = tn * 128 + (t & 15) * 8;
        *(f16x8*)&((f16*)Cv)[(long)z * sC + (long)grow * ldc + gcol] =
            *(const f16x8*)&rep[lrow * 136 + (t & 15) * 8];
      }
    }
  } else {
    // ---- f32 output via LDS repack: [32][132] per i-group ----
    float* rep = (float*)smem;
#pragma unroll
    for (int i = 0; i < 4; ++i) {
      __syncthreads();
      const int lrow0 = wm * 16 + l4 * 4;
#pragma unroll
      for (int jn = 0; jn < 4; ++jn) {
        const int col = wn * 64 + jn * 16 + l15;
#pragma unroll
        for (int r = 0; r < 4; ++r) rep[(lrow0 + r) * 132 + col] = acc[i][jn][r];
      }
      __syncthreads();
#pragma unroll
      for (int pp = 0; pp < 4; ++pp) {
        const int lrow = pp * 8 + (t >> 5);
        const int grow = tm * 128 + (lrow >> 4) * 64 + i * 16 + (lrow & 15);
        const int gcol = tn * 128 + (t & 31) * 4;
        *(float4*)&((float*)Cv)[(long)z * sC + (long)grow * ldc + gcol] =
            *(const float4*)&rep[lrow * 132 + (t & 31) * 4];
      }
    }
  }
}

// --------------------------------- driver ----------------------------------

extern "C" void kernel_launch(void* const* d_in, const int* in_sizes, int n_in,
                              void* d_out, int out_size, void* d_ws,
                              size_t ws_size, hipStream_t stream) {
  const float* query = (const float*)d_in[0];
  const float* value = (const float*)d_in[1];
  const float* Wq = (const float*)d_in[2];
  const float* bq = (const float*)d_in[3];
  const float* Wk = (const float*)d_in[4];
  const float* bk = (const float*)d_in[5];
  const float* Wv = (const float*)d_in[6];
  const float* bv = (const float*)d_in[7];
  const float* Wr = (const float*)d_in[8];
  const float* br = (const float*)d_in[9];
  float* out = (float*)d_out;

  if (ws_size < 169000000ull) {
    sentinel<<<1, 1, 0, stream>>>(out);
    return;
  }

  char* p = (char*)d_ws;
  auto alloc = [&](size_t bytes) {
    char* r = p;
    p += (bytes + 255) & ~(size_t)255;
    return r;
  };
  const size_t QV = 16777216ull;  // B*S*D elements
  const size_t WW = 1048576ull;   // 1024*1024 elements
  char* bufA = alloc(QV * 2);  // q16 -> Khat
  char* bufB = alloc(QV * 2);  // v16 -> probs z-even (32MB)
  char* bufC = alloc(QV * 2);  // Qhat
  char* bufD = alloc(QV * 2);  // VT
  f16* q16 = (f16*)bufA;
  f16* Khat = (f16*)bufA;
  f16* v16 = (f16*)bufB;
  f16* probs0 = (f16*)bufB;  // pair slot 0; slot 1 = weights region (+96MB)
  f16* Qhat = (f16*)bufC;
  f16* VT = (f16*)bufD;
  // weights region: 32 MB from Wq_h onward is reused as probs slot 1
  f16* Wq_h = (f16*)alloc(WW * 2);
  f16* Wq_l = (f16*)alloc(WW * 2);
  f16* Wk_h = (f16*)alloc(WW * 2);
  f16* Wk_l = (f16*)alloc(WW * 2);
  f16* Wr_h = (f16*)alloc(WW * 2);
  f16* Wr_l = (f16*)alloc(WW * 2);
  f16* Wv16 = (f16*)alloc(WW * 2);
  f16* WrT_h = (f16*)alloc(WW * 2);
  f16* WrT_l = (f16*)alloc(WW * 2);
  f16* WvT = (f16*)alloc(WW * 2);
  float* Wtmp32 = (float*)alloc(WW * 8);   // [2][1024][1024] f32
  f16* WqrT2 = (f16*)alloc(WW * 4);        // [1024][2048] hi|lo concat
  f16* WkrT2 = (f16*)alloc(WW * 4);
  float* brq = (float*)alloc(1024 * 4);
  float* brk = (float*)alloc(1024 * 4);
  float* bpart = (float*)alloc(2 * 16 * 1024 * 4);
  float* m_loc = (float*)alloc(2 * 16 * 4096 * 4);  // [z2][tn256][row]
  float* l_loc = (float*)alloc(2 * 16 * 4096 * 4);
  f16* scl = (f16*)alloc(2 * 16 * 4096 * 2);  // [z2][tile256][row] = alpha/l
  const long PSTRIDE = 50331648;  // f16 elems between probs slot 0 and slot 1

  // fp32 -> fp16 conversions (split for W matrices feeding Wqr/Wkr)
  f2h_qv<<<32768, 256, 0, stream>>>(query, value, q16, v16);
  f2h_split<<<1024, 256, 0, stream>>>(Wq, Wq_h, Wq_l, 262144);
  f2h_split<<<1024, 256, 0, stream>>>(Wk, Wk_h, Wk_l, 262144);
  f2h_split<<<1024, 256, 0, stream>>>(Wr, Wr_h, Wr_l, 262144);
  f2h<<<1024, 256, 0, stream>>>(Wv, Wv16, 262144);
  tr3<<<dim3(32, 32, 3), dim3(32, 32), 0, stream>>>(Wr_h, WrT_h, Wr_l, WrT_l,
                                                    Wv16, WvT);
  bias_part<<<dim3(4, 16, 2), 256, 0, stream>>>(bq, bk, Wr, bpart);
  bias_red<<<dim3(4, 1, 2), 256, 0, stream>>>(br, bpart, brq, brk);

  // W{q,k}rT = Wr^T @ W{q,k}^T in ~fp32 (Ah@Bh + Ah@Bl + Al@Bh), one z=2 pass
  gemm_bt<5, true, true, 32><<<dim3(8, 8, 2), 256, 0, stream>>>(
      WrT_h, WrT_l, Wq_h, Wq_l, Wtmp32, nullptr, nullptr, 0, 1024, 1024, 1024,
      1024, 1024, 1024, 1048576, 0, 2097152, 0);
  f2h_split2<<<1024, 256, 0, stream>>>(Wtmp32, WqrT2, 262144);
  f2h_split2<<<1024, 256, 0, stream>>>(Wtmp32 + 1048576, WkrT2, 262144);

  // Qhat = cos(query @ Wqr + brq)   [bufC]  (K-concat dual-B, K'=2048)
  g8p<1, 32, true, 4><<<dim3(4, 64, 1), 512, 0, stream>>>(
      q16, WqrT2, Qhat, brq, nullptr, nullptr, 0, 0, 0, 1024, 2048, 1024);
  // Khat = cos(value @ Wkr + brk)   [bufA — q16 dead from here]
  g8p<1, 32, true, 4><<<dim3(4, 64, 1), 512, 0, stream>>>(
      v16, WkrT2, Khat, brk, nullptr, nullptr, 0, 0, 0, 1024, 2048, 1024);
  // VT[u][s] = (value @ Wv + bv)^T = Wv^T @ value^T  (row bias bv)  [bufD]
  gemm_bt<2, false, false, 64><<<dim3(128, 8, 1), 256, 0, stream>>>(
      WvT, nullptr, v16, nullptr, VT, bv, nullptr, 0, 1024, 16384, 1024, 1024,
      1024, 16384, 0, 0, 0, 0);

  // per batch-pair: probs = exp(S - m_tile) + stats; merge; PV (scale folded)
  for (int zb = 0; zb < NB; zb += 2) {
    g8p<6, 16, false, 16><<<dim3(16, 16, 2), 512, 0, stream>>>(
        Qhat + (long)zb * 4194304, Khat + (long)zb * 4194304, probs0, nullptr,
        m_loc, l_loc, 4194304, 4194304, PSTRIDE, 1024, 1024, 4096);
    merge_pair<<<32, 256, 0, stream>>>(m_loc, l_loc, scl);
    gemm_bt<7, false, false, 64><<<dim3(8, 32, 2), 256, 0, stream>>>(
        probs0, nullptr, VT + (long)zb * 4096, nullptr, out + (long)zb * 4194304,
        nullptr, scl, 65536, 4096, 1024, 4096, 4096, 16384, 1024, 4194304,
        PSTRIDE, 4096, 0);
  }
}

// Round 12
// 613.307 us; speedup vs baseline: 1.2508x; 1.0129x over previous
//
#include <hip/hip_runtime.h>
#include <hip/hip_bf16.h>
#include <hip/hip_fp16.h>
#include <cstdint>

// ---------------------------------------------------------------------------
// LinearAttention (random-feature cos kernel + softmax attention), MI355X.
// out = softmax(cos(q@Wq@Wr + br) @ cos(v@Wk@Wr + br)^T) @ (v@Wv + bv)
// B=4, S=4096, D=U=F=1024.  All heavy math in fp16 MFMA with fp32 accum.
// qk + Qhat/Khat: 256x256 / 8 waves / BK=64 / 8-phase, counted vmcnt(4),
//   rect-XCD block swizzle for L2 locality, LDS-repack vectorized epilogue.
// PV/VT/Wqr: 128x128 2-phase counted-vmcnt.
// Softmax: tile-local max in QK^T epilogue + alpha/l folded into PV.
// ---------------------------------------------------------------------------

typedef _Float16 f16;
typedef _Float16 f16x8 __attribute__((ext_vector_type(8)));
typedef _Float16 f16x4 __attribute__((ext_vector_type(4)));
typedef float f32x4 __attribute__((ext_vector_type(4)));

typedef __attribute__((address_space(1))) unsigned int uas1;
typedef __attribute__((address_space(3))) unsigned int uas3;

#define NB 4
#define SEQ 4096
#define DIM 1024

// async 16B/lane global->LDS. LDS dest must be wave-uniform base (+lane*16).
__device__ __forceinline__ void async_copy16(void* lds, const void* g) {
  __builtin_amdgcn_global_load_lds((uas1*)(uintptr_t)g, (uas3*)(uintptr_t)lds,
                                   16, 0, 0);
}

// ----------------------------- small kernels ------------------------------

// query+value -> f16 in one dispatch (grid 32768)
__global__ __launch_bounds__(256) void f2h_qv(const float* __restrict__ a,
                                              const float* __restrict__ b,
                                              f16* __restrict__ oa,
                                              f16* __restrict__ ob) {
  const int bid = blockIdx.x;
  const float* in = bid < 16384 ? a : b;
  f16* out = bid < 16384 ? oa : ob;
  const int i = (bid & 16383) * 256 + threadIdx.x;
  float4 v = ((const float4*)in)[i];
  f16x4 h = {(f16)v.x, (f16)v.y, (f16)v.z, (f16)v.w};
  ((f16x4*)out)[i] = h;
}

// all four weight conversions in one dispatch: y=0 Wq, 1 Wk, 2 Wr (hi/lo),
// y=3 Wv (plain f16)
__global__ __launch_bounds__(256) void w_conv(
    const float* __restrict__ Wq, const float* __restrict__ Wk,
    const float* __restrict__ Wr, const float* __restrict__ Wv,
    f16* __restrict__ Wq_h, f16* __restrict__ Wq_l, f16* __restrict__ Wk_h,
    f16* __restrict__ Wk_l, f16* __restrict__ Wr_h, f16* __restrict__ Wr_l,
    f16* __restrict__ Wv16) {
  const int which = blockIdx.y;
  const int i = blockIdx.x * 256 + threadIdx.x;
  const float* in = which == 0 ? Wq : which == 1 ? Wk : which == 2 ? Wr : Wv;
  float4 v = ((const float4*)in)[i];
  f16 h0 = (f16)v.x, h1 = (f16)v.y, h2 = (f16)v.z, h3 = (f16)v.w;
  f16x4 hv = {h0, h1, h2, h3};
  if (which == 3) {
    ((f16x4*)Wv16)[i] = hv;
    return;
  }
  f16x4 lv = {(f16)(v.x - (float)h0), (f16)(v.y - (float)h1),
              (f16)(v.z - (float)h2), (f16)(v.w - (float)h3)};
  f16* hi = which == 0 ? Wq_h : which == 1 ? Wk_h : Wr_h;
  f16* lo = which == 0 ? Wq_l : which == 1 ? Wk_l : Wr_l;
  ((f16x4*)hi)[i] = hv;
  ((f16x4*)lo)[i] = lv;
}

// split to hi/lo CONCATENATED along K (two inputs in one dispatch)
__global__ __launch_bounds__(256) void f2h_split2b(const float* __restrict__ i0,
                                                   f16* __restrict__ o0,
                                                   const float* __restrict__ i1,
                                                   f16* __restrict__ o1) {
  const float* in = blockIdx.y ? i1 : i0;
  f16* w2 = blockIdx.y ? o1 : o0;
  int i = blockIdx.x * 256 + threadIdx.x;
  float4 v = ((const float4*)in)[i];
  f16 h0 = (f16)v.x, h1 = (f16)v.y, h2 = (f16)v.z, h3 = (f16)v.w;
  f16x4 hv = {h0, h1, h2, h3};
  f16x4 lv = {(f16)(v.x - (float)h0), (f16)(v.y - (float)h1),
              (f16)(v.z - (float)h2), (f16)(v.w - (float)h3)};
  const int n = i >> 8, k4 = i & 255;
  ((f16x4*)(w2 + (long)n * 2048))[k4] = hv;
  ((f16x4*)(w2 + (long)n * 2048 + 1024))[k4] = lv;
}

// 3 transposes (1024x1024 f16) in one dispatch; z selects pair
__global__ void tr3(const f16* __restrict__ i0, f16* __restrict__ o0,
                    const f16* __restrict__ i1, f16* __restrict__ o1,
                    const f16* __restrict__ i2, f16* __restrict__ o2) {
  __shared__ f16 tile[32][33];
  const f16* in = blockIdx.z == 0 ? i0 : blockIdx.z == 1 ? i1 : i2;
  f16* out = blockIdx.z == 0 ? o0 : blockIdx.z == 1 ? o1 : o2;
  int c0 = blockIdx.x * 32, r0 = blockIdx.y * 32;
  tile[threadIdx.y][threadIdx.x] =
      in[(long)(r0 + threadIdx.y) * 1024 + c0 + threadIdx.x];
  __syncthreads();
  out[(long)(c0 + threadIdx.y) * 1024 + r0 + threadIdx.x] =
      tile[threadIdx.x][threadIdx.y];
}

// bias_eff = br + bvec @ Wr, deterministic 2-stage (partials then reduce)
__global__ __launch_bounds__(256) void bias_part(const float* __restrict__ bq,
                                                 const float* __restrict__ bk,
                                                 const float* __restrict__ Wr,
                                                 float* __restrict__ part) {
  const float* bvec = blockIdx.z ? bk : bq;
  const int f = blockIdx.x * 256 + threadIdx.x;
  const int u0 = blockIdx.y * 64;
  float s = 0.f;
#pragma unroll 8
  for (int u = 0; u < 64; ++u)
    s = fmaf(bvec[u0 + u], Wr[(long)(u0 + u) * DIM + f], s);
  part[(blockIdx.z * 16 + blockIdx.y) * 1024 + f] = s;
}

__global__ __launch_bounds__(256) void bias_red(const float* __restrict__ br,
                                                const float* __restrict__ part,
                                                float* __restrict__ brq,
                                                float* __restrict__ brk) {
  const int f = blockIdx.x * 256 + threadIdx.x;
  float* outb = blockIdx.z ? brk : brq;
  float s = br[f];
#pragma unroll 16
  for (int j = 0; j < 16; ++j) s += part[(blockIdx.z * 16 + j) * 1024 + f];
  outb[f] = s;
}

// per (z2,row): m = max_t m_t; l = sum_t l_t exp(m_t-m);
// scl[t][row] = exp(m_t-m)/l  (f16).  16 tiles of 256 cols.
__global__ __launch_bounds__(256) void merge_pair(const float* __restrict__ ml,
                                                  const float* __restrict__ ll,
                                                  f16* __restrict__ scl) {
  int i = blockIdx.x * 256 + threadIdx.x;  // 0..8191 = z2*4096 + row
  int z2 = i >> 12, row = i & 4095;
  const float* m = ml + z2 * 65536 + row;
  const float* lp = ll + z2 * 65536 + row;
  float a[16];
  float mg = -1e30f;
#pragma unroll 16
  for (int t = 0; t < 16; ++t) mg = fmaxf(mg, m[t * 4096]);
  float l = 0.f;
#pragma unroll 16
  for (int t = 0; t < 16; ++t) {
    a[t] = __expf(m[t * 4096] - mg);
    l += lp[t * 4096] * a[t];
  }
  float li = 1.0f / l;
#pragma unroll 16
  for (int t = 0; t < 16; ++t)
    scl[z2 * 65536 + t * 4096 + row] = (f16)(a[t] * li);
}

__global__ void sentinel(float* out) { out[0] = 12345.0f; }

// ------------- 8-phase 256x256 GEMM template (8 waves, BK=64) --------------
// C = epi(A @ B^T), B row-major [N][ldb].  NT = K/64 tiles.  If WRAPA, A's
// k-index wraps mod 1024 (K-concat dual-precision B).  GX = gridDim.x.
// Rect XCD swizzle: GX==16 -> each XCD owns a 4tm x 8tn rectangle;
//                   GX==4  -> each XCD owns one tn column strip (32 tm).
// EPI 6: probs = exp(S - rowmax_tile) f16 + mout/lout per (z,tn,row)
// EPI 1: f16 __cosf(v + aux[col])
// Both write through an LDS repack (stride 264) -> full-line f16x8 stores.
template <int EPI, int NT, bool WRAPA, int GX>
__global__ __launch_bounds__(512, 2) void g8p(
    const f16* __restrict__ A, const f16* __restrict__ B,
    void* __restrict__ Cv, const float* __restrict__ aux,
    float* __restrict__ mout, float* __restrict__ lout, long sA, long sB,
    long sC, int lda, int ldb, int ldc) {
  constexpr int BUF = 65536;  // 64KB per dbuf: A(32KB)+B(32KB)
  __shared__ __align__(16) char smem[256 * 264 * 2];  // >= 2*BUF; repack space
  __shared__ float red[EPI == 6 ? 4 : 1][EPI == 6 ? 256 : 1];
  // rect XCD swizzle over the 256 (tm,tn) blocks (XCD = linear id % 8)
  const int lin = blockIdx.x + blockIdx.y * GX;
  const int c = lin & 7, j = lin >> 3;
  int tm, tn;
  if constexpr (GX == 16) {  // 4tm x 8tn rect per XCD (6MB working set)
    tm = (c & 3) * 4 + (j & 3);
    tn = (c >> 2) * 8 + (j >> 2);
  } else {  // GX==4: tn column strip per XCD (B panel L2-resident)
    tn = c & 3;
    tm = (c >> 2) * 32 + j;
  }
  const int z = blockIdx.z;
  const int t = threadIdx.x, w = t >> 6, l = t & 63;
  const int l4 = l >> 4, l15 = l & 15;
  const int wm = w >> 2, wn = w & 3;  // 2 x 4 waves; wave out = 128 x 64
  f32x4 acc[8][4] = {};
  const f16* Az = A + (long)z * sA;
  const f16* Bz = B + (long)z * sB;

  // half-tile stage: ht 0=A0,1=A1,2=B0,3=B1 ; 1024 chunks, 2 per thread
  auto STAGE_HT = [&](int buf, int tt, int ht) {
    const bool isA = (ht < 2);
    const f16* src = isA ? Az : Bz;
    const int ld = isA ? lda : ldb;
    const int row0 = (isA ? tm : tn) * 256 + (ht & 1) * 128;
    char* base = smem + buf * BUF + (ht >> 1) * 32768 + (ht & 1) * 16384;
    int kk = tt * 64;
    if (WRAPA && isA) kk &= 1023;
#pragma unroll
    for (int jj = 0; jj < 2; ++jj) {
      const int cb = jj * 512 + w * 64;  // wave-uniform chunk base
      const int cc = cb + l;
      const int r = cc >> 3, s = cc & 7;
      async_copy16(base + cb * 16,
                   src + (long)(row0 + r) * ld + kk + (s ^ (r & 7)) * 8);
    }
  };

  // prologue: tile0 full + B halves of tile1;  vmcnt(4) -> tile0 resident
  STAGE_HT(0, 0, 0);
  STAGE_HT(0, 0, 1);
  STAGE_HT(0, 0, 2);
  STAGE_HT(0, 0, 3);
  STAGE_HT(1, 1, 2);
  STAGE_HT(1, 1, 3);
  asm volatile("s_waitcnt vmcnt(4)" ::: "memory");
  __builtin_amdgcn_s_barrier();

  for (int it = 0; it < NT / 2; ++it) {
    const int tt = 2 * it;
    const bool more = (tt + 2) < NT;
    // ---- phases 1-4: compute tile tt from buf0 ----
    {
      const f16* Ab = (const f16*)(smem);
      const f16* Bb = Ab + 16384;  // +32KB
      f16x8 bfp[4][2];
#pragma unroll
      for (int q = 0; q < 4; ++q) {
        if (q == 0) {
#pragma unroll
          for (int jn = 0; jn < 4; ++jn)
#pragma unroll
            for (int ks = 0; ks < 2; ++ks) {
              const int rb = wn * 64 + jn * 16 + l15;
              const int p = ks * 4 + l4;
              bfp[jn][ks] = *(const f16x8*)&Bb[rb * 64 + (p ^ (rb & 7)) * 8];
            }
        }
        f16x8 af[2][2];
#pragma unroll
        for (int i2 = 0; i2 < 2; ++i2)
#pragma unroll
          for (int ks = 0; ks < 2; ++ks) {
            const int ra = wm * 128 + (q * 2 + i2) * 16 + l15;
            const int p = ks * 4 + l4;
            af[i2][ks] = *(const f16x8*)&Ab[ra * 64 + (p ^ (ra & 7)) * 8];
          }
        if (q == 0) STAGE_HT(1, tt + 1, 0);
        if (q == 1) STAGE_HT(1, tt + 1, 1);
        if (q == 2 && more) STAGE_HT(0, tt + 2, 2);
        if (q == 3) {
          if (more) {
            STAGE_HT(0, tt + 2, 3);
            asm volatile("s_waitcnt vmcnt(4)" ::: "memory");
          } else {
            asm volatile("s_waitcnt vmcnt(0)" ::: "memory");
          }
        }
        __builtin_amdgcn_s_barrier();
        asm volatile("s_waitcnt lgkmcnt(0)" ::: "memory");
        __builtin_amdgcn_s_setprio(1);
#pragma unroll
        for (int i2 = 0; i2 < 2; ++i2)
#pragma unroll
          for (int jn = 0; jn < 4; ++jn)
#pragma unroll
            for (int ks = 0; ks < 2; ++ks)
              acc[q * 2 + i2][jn] = __builtin_amdgcn_mfma_f32_16x16x32_f16(
                  af[i2][ks], bfp[jn][ks], acc[q * 2 + i2][jn], 0, 0, 0);
        __builtin_amdgcn_s_setprio(0);
        __builtin_amdgcn_s_barrier();
      }
    }
    // ---- phases 5-8: compute tile tt+1 from buf1 ----
    {
      const f16* Ab = (const f16*)(smem + BUF);
      const f16* Bb = Ab + 16384;
      f16x8 bfp[4][2];
#pragma unroll
      for (int q = 0; q < 4; ++q) {
        if (q == 0) {
#pragma unroll
          for (int jn = 0; jn < 4; ++jn)
#pragma unroll
            for (int ks = 0; ks < 2; ++ks) {
              const int rb = wn * 64 + jn * 16 + l15;
              const int p = ks * 4 + l4;
              bfp[jn][ks] = *(const f16x8*)&Bb[rb * 64 + (p ^ (rb & 7)) * 8];
            }
        }
        f16x8 af[2][2];
#pragma unroll
        for (int i2 = 0; i2 < 2; ++i2)
#pragma unroll
          for (int ks = 0; ks < 2; ++ks) {
            const int ra = wm * 128 + (q * 2 + i2) * 16 + l15;
            const int p = ks * 4 + l4;
            af[i2][ks] = *(const f16x8*)&Ab[ra * 64 + (p ^ (ra & 7)) * 8];
          }
        if (q == 0 && more) STAGE_HT(0, tt + 2, 0);
        if (q == 1 && more) STAGE_HT(0, tt + 2, 1);
        if (q == 2 && more) STAGE_HT(1, tt + 3, 2);
        if (q == 3) {
          if (more) {
            STAGE_HT(1, tt + 3, 3);
            asm volatile("s_waitcnt vmcnt(4)" ::: "memory");
          } else {
            asm volatile("s_waitcnt vmcnt(0)" ::: "memory");
          }
        }
        __builtin_amdgcn_s_barrier();
        asm volatile("s_waitcnt lgkmcnt(0)" ::: "memory");
        __builtin_amdgcn_s_setprio(1);
#pragma unroll
        for (int i2 = 0; i2 < 2; ++i2)
#pragma unroll
          for (int jn = 0; jn < 4; ++jn)
#pragma unroll
            for (int ks = 0; ks < 2; ++ks)
              acc[q * 2 + i2][jn] = __builtin_amdgcn_mfma_f32_16x16x32_f16(
                  af[i2][ks], bfp[jn][ks], acc[q * 2 + i2][jn], 0, 0, 0);
        __builtin_amdgcn_s_setprio(0);
        __builtin_amdgcn_s_barrier();
      }
    }
  }

  if constexpr (EPI == 6) {
    // ---- tile-local softmax over this 256-col tile ----
    float mrow[32];
#pragma unroll
    for (int i = 0; i < 8; ++i)
#pragma unroll
      for (int r = 0; r < 4; ++r) {
        float v = fmaxf(fmaxf(acc[i][0][r], acc[i][1][r]),
                        fmaxf(acc[i][2][r], acc[i][3][r]));
        v = fmaxf(v, __shfl_xor(v, 1));
        v = fmaxf(v, __shfl_xor(v, 2));
        v = fmaxf(v, __shfl_xor(v, 4));
        v = fmaxf(v, __shfl_xor(v, 8));
        if (l15 == 0) red[wn][wm * 128 + i * 16 + l4 * 4 + r] = v;
      }
    __syncthreads();
#pragma unroll
    for (int i = 0; i < 8; ++i)
#pragma unroll
      for (int r = 0; r < 4; ++r) {
        const int rin = wm * 128 + i * 16 + l4 * 4 + r;
        mrow[i * 4 + r] = fmaxf(fmaxf(red[0][rin], red[1][rin]),
                                fmaxf(red[2][rin], red[3][rin]));
      }
    __syncthreads();
#pragma unroll
    for (int i = 0; i < 8; ++i)
#pragma unroll
      for (int r = 0; r < 4; ++r) {
        const float mn = mrow[i * 4 + r];
        float s = 0.f;
#pragma unroll
        for (int jn = 0; jn < 4; ++jn) {
          float e = __expf(acc[i][jn][r] - mn);
          acc[i][jn][r] = e;
          s += e;
        }
        s += __shfl_xor(s, 1);
        s += __shfl_xor(s, 2);
        s += __shfl_xor(s, 4);
        s += __shfl_xor(s, 8);
        if (l15 == 0) red[wn][wm * 128 + i * 16 + l4 * 4 + r] = s;
      }
    __syncthreads();
    if (wn == 0 && l15 == 0) {
#pragma unroll
      for (int i = 0; i < 8; ++i)
#pragma unroll
        for (int r = 0; r < 4; ++r) {
          const int rin = wm * 128 + i * 16 + l4 * 4 + r;
          const int gidx = z * 65536 + tn * 4096 + tm * 256 + rin;
          mout[gidx] = mrow[i * 4 + r];
          lout[gidx] = red[0][rin] + red[1][rin] + red[2][rin] + red[3][rin];
        }
    }
  }

  // ---- vectorized output: LDS repack (stride 264) -> f16x8 stores ----
  f16* rep = (f16*)smem;
#pragma unroll
  for (int i = 0; i < 8; ++i) {
    const int row0 = wm * 128 + i * 16 + l4 * 4;
#pragma unroll
    for (int jn = 0; jn < 4; ++jn) {
      const int col = wn * 64 + jn * 16 + l15;
#pragma unroll
      for (int r = 0; r < 4; ++r) {
        float v = acc[i][jn][r];
        f16 hv;
        if constexpr (EPI == 1)
          hv = (f16)__cosf(v + aux[tn * 256 + col]);
        else
          hv = (f16)v;
        rep[(row0 + r) * 264 + col] = hv;
      }
    }
  }
  __syncthreads();
#pragma unroll
  for (int k = 0; k < 16; ++k) {
    const int orow = k * 16 + (t >> 5);
    const int oc = (t & 31) * 8;
    *(f16x8*)&((f16*)Cv)[(long)z * sC + (long)(tm * 256 + orow) * ldc +
                         tn * 256 + oc] = *(const f16x8*)&rep[orow * 264 + oc];
  }
}

// ------------------------------- main GEMM --------------------------------
// C[M,N] = epilogue( A@B^T [+ A@Bl^T if DB] [+ Al@B^T if DA] )
// B stored row-major [N,K].  128x128 tile, 4 waves, 4x4 16x16x32 frags/wave.
// Double-buffered LDS, 2-phase pipeline, counted vmcnt (never 0 in loop).
// EPI: 2 f16 v+aux[row] | 5 f32 plain
//      7 f32 plain, A-fragments scaled by ascl[ktile256][arow] (LDS-staged)
template <int EPI, bool DA, bool DB, int BK>
__global__ __launch_bounds__(256) void gemm_bt(
    const f16* __restrict__ Ah, const f16* __restrict__ Al,
    const f16* __restrict__ Bh, const f16* __restrict__ Bl,
    void* __restrict__ Cv, const float* __restrict__ aux,
    const f16* __restrict__ ascl, long sAscl, int M, int N, int K, int lda,
    int ldb, int ldc, long sC, long sA, long sB, int sAux) {
  constexpr int NSTAGE = 2 + (DA ? 1 : 0) + (DB ? 1 : 0);
  constexpr int TILE = 128 * BK * 2;    // bytes per operand tile
  constexpr int CPR = BK / 8;           // 16B chunks per row
  constexpr int CH = 128 * CPR;         // chunks per operand tile
  constexpr int NL = NSTAGE * BK / 16;  // per-thread vmem issues per tile
  static_assert(NL == 6 || NL == 8, "vmcnt literal");
  constexpr int SCLB = (EPI == 7) ? 4096 : 0;
  __shared__ __align__(16) char smem[2 * NSTAGE * TILE + SCLB];

  const int z = blockIdx.z;
  const int tn = blockIdx.x, tm = blockIdx.y;
  const int t = threadIdx.x, w = t >> 6, l = t & 63;
  const int l4 = l >> 4, l15 = l & 15;
  const int wm = w & 1, wn = w >> 1;
  f32x4 acc[4][4] = {};

  const f16* Az = Ah + (long)z * sA;
  const f16* Bz = Bh + (long)z * sB;
  const f16* Alz = nullptr;
  const f16* Blz = nullptr;
  if constexpr (DA) Alz = Al + (long)z * sA;
  if constexpr (DB) Blz = Bl + (long)z * sB;
  f16* sclLds = (f16*)(smem + 2 * NSTAGE * TILE);

  auto swz = [](int r, int p) -> int {
    if constexpr (BK == 64) return p ^ (r & 7);
    else return p ^ ((r >> 1) & 3);
  };

  auto STAGE = [&](int buf, int kk) {
    char* base = smem + buf * (NSTAGE * TILE);
#pragma unroll
    for (int j = 0; j < CH / 256; ++j) {
      const int cb = j * 256 + w * 64;  // wave-uniform chunk base
      const int c = cb + l;
      const int r = c / CPR, pp = c % CPR;
      const int sc = swz(r, pp);
      const long ra = (long)(tm * 128 + r) * lda + kk + sc * 8;
      const long rb = (long)(tn * 128 + r) * ldb + kk + sc * 8;
      async_copy16(base + cb * 16, Az + ra);
      async_copy16(base + TILE + cb * 16, Bz + rb);
      if constexpr (DA) async_copy16(base + 2 * TILE + cb * 16, Alz + ra);
      if constexpr (DB)
        async_copy16(base + (2 + (DA ? 1 : 0)) * TILE + cb * 16, Blz + rb);
    }
  };

  // ---- prologue: stage tile 0 (+ scl table for EPI 7), drain, barrier ----
  STAGE(0, 0);
  if constexpr (EPI == 7) {
    const f16* asclz = ascl + (long)z * sAscl;
    // 16 k-tiles x 128 rows f16 -> 256 chunks; LDS idx c*8 = tile*128 + row
    const int cb = w * 64;
    const int c = cb + l;
    async_copy16(sclLds + cb * 8,
                 asclz + (long)(c >> 4) * M + tm * 128 + (c & 15) * 8);
  }
  asm volatile("s_waitcnt vmcnt(0)" ::: "memory");
  __syncthreads();

  const int nt = K / BK;
  int cur = 0;
  for (int tt = 0; tt < nt; ++tt) {
    const int kk = tt * BK;
    if (tt + 1 < nt) {
      STAGE(cur ^ 1, kk + BK);
      if constexpr (NL == 6)
        asm volatile("s_waitcnt vmcnt(6)" ::: "memory");
      else
        asm volatile("s_waitcnt vmcnt(8)" ::: "memory");
    } else {
      asm volatile("s_waitcnt vmcnt(0)" ::: "memory");
    }
    __syncthreads();

    const f16* As = (const f16*)(smem + cur * (NSTAGE * TILE));
    const f16* Bs = As + TILE / 2;
    const f16* Als = Bs + TILE / 2;
    const f16* Bls = Als + (DA ? TILE / 2 : 0);

    f16 sA4[4];
    if constexpr (EPI == 7) {
      const int tile = kk >> 8;  // 256-wide k-tiles
#pragma unroll
      for (int i = 0; i < 4; ++i)
        sA4[i] = sclLds[tile * 128 + wm * 64 + i * 16 + l15];
    }

#pragma unroll
    for (int ks = 0; ks < BK / 32; ++ks) {
      f16x8 af[4], bf[4];
#pragma unroll
      for (int i = 0; i < 4; ++i) {
        const int ra = wm * 64 + i * 16 + l15;
        const int rb = wn * 64 + i * 16 + l15;
        af[i] = *(const f16x8*)&As[ra * BK + swz(ra, ks * 4 + l4) * 8];
        bf[i] = *(const f16x8*)&Bs[rb * BK + swz(rb, ks * 4 + l4) * 8];
      }
      if constexpr (EPI == 7) {
#pragma unroll
        for (int i = 0; i < 4; ++i) af[i] = af[i] * sA4[i];
      }
#pragma unroll
      for (int i = 0; i < 4; ++i)
#pragma unroll
        for (int jn = 0; jn < 4; ++jn)
          acc[i][jn] = __builtin_amdgcn_mfma_f32_16x16x32_f16(af[i], bf[jn],
                                                              acc[i][jn], 0, 0, 0);
      if constexpr (DB) {
        f16x8 bl[4];
#pragma unroll
        for (int i = 0; i < 4; ++i) {
          const int rb = wn * 64 + i * 16 + l15;
          bl[i] = *(const f16x8*)&Bls[rb * BK + swz(rb, ks * 4 + l4) * 8];
        }
#pragma unroll
        for (int i = 0; i < 4; ++i)
#pragma unroll
          for (int jn = 0; jn < 4; ++jn)
            acc[i][jn] = __builtin_amdgcn_mfma_f32_16x16x32_f16(
                af[i], bl[jn], acc[i][jn], 0, 0, 0);
      }
      if constexpr (DA) {
        f16x8 al[4];
#pragma unroll
        for (int i = 0; i < 4; ++i) {
          const int ra = wm * 64 + i * 16 + l15;
          al[i] = *(const f16x8*)&Als[ra * BK + swz(ra, ks * 4 + l4) * 8];
        }
#pragma unroll
        for (int i = 0; i < 4; ++i)
#pragma unroll
          for (int jn = 0; jn < 4; ++jn)
            acc[i][jn] = __builtin_amdgcn_mfma_f32_16x16x32_f16(
                al[i], bf[jn], acc[i][jn], 0, 0, 0);
      }
    }
    __syncthreads();
    cur ^= 1;
  }

  const float* auxp = aux + (long)z * sAux;

  if constexpr (EPI == 2) {
    // ---- f16 output via LDS repack: [64][136] per half ----
    f16* rep = (f16*)smem;
#pragma unroll
    for (int hh = 0; hh < 2; ++hh) {
      __syncthreads();
#pragma unroll
      for (int ii = 0; ii < 2; ++ii) {
        const int i = hh * 2 + ii;
        const int lrow0 = wm * 32 + ii * 16 + l4 * 4;
#pragma unroll
        for (int jn = 0; jn < 4; ++jn) {
          const int col = wn * 64 + jn * 16 + l15;
#pragma unroll
          for (int r = 0; r < 4; ++r) {
            float v = acc[i][jn][r];
            f16 hv = (f16)(v + auxp[tm * 128 + wm * 64 + i * 16 + l4 * 4 + r]);
            rep[(lrow0 + r) * 136 + col] = hv;
          }
        }
      }
      __syncthreads();
#pragma unroll
      for (int pp = 0; pp < 4; ++pp) {
        const int lrow = pp * 16 + (t >> 4);
        const int grow = tm * 128 + (lrow >> 5) * 64 + hh * 32 + (lrow & 31);
        const int gcol = tn * 128 + (t & 15) * 8;
        *(f16x8*)&((f16*)Cv)[(long)z * sC + (long)grow * ldc + gcol] =
            *(const f16x8*)&rep[lrow * 136 + (t & 15) * 8];
      }
    }
  } else {
    // ---- f32 output via LDS repack: [32][132] per i-group ----
    float* rep = (float*)smem;
#pragma unroll
    for (int i = 0; i < 4; ++i) {
      __syncthreads();
      const int lrow0 = wm * 16 + l4 * 4;
#pragma unroll
      for (int jn = 0; jn < 4; ++jn) {
        const int col = wn * 64 + jn * 16 + l15;
#pragma unroll
        for (int r = 0; r < 4; ++r) rep[(lrow0 + r) * 132 + col] = acc[i][jn][r];
      }
      __syncthreads();
#pragma unroll
      for (int pp = 0; pp < 4; ++pp) {
        const int lrow = pp * 8 + (t >> 5);
        const int grow = tm * 128 + (lrow >> 4) * 64 + i * 16 + (lrow & 15);
        const int gcol = tn * 128 + (t & 31) * 4;
        *(float4*)&((float*)Cv)[(long)z * sC + (long)grow * ldc + gcol] =
            *(const float4*)&rep[lrow * 132 + (t & 31) * 4];
      }
    }
  }
}

// --------------------------------- driver ----------------------------------

extern "C" void kernel_launch(void* const* d_in, const int* in_sizes, int n_in,
                              void* d_out, int out_size, void* d_ws,
                              size_t ws_size, hipStream_t stream) {
  const float* query = (const float*)d_in[0];
  const float* value = (const float*)d_in[1];
  const float* Wq = (const float*)d_in[2];
  const float* bq = (const float*)d_in[3];
  const float* Wk = (const float*)d_in[4];
  const float* bk = (const float*)d_in[5];
  const float* Wv = (const float*)d_in[6];
  const float* bv = (const float*)d_in[7];
  const float* Wr = (const float*)d_in[8];
  const float* br = (const float*)d_in[9];
  float* out = (float*)d_out;

  if (ws_size < 169000000ull) {
    sentinel<<<1, 1, 0, stream>>>(out);
    return;
  }

  char* p = (char*)d_ws;
  auto alloc = [&](size_t bytes) {
    char* r = p;
    p += (bytes + 255) & ~(size_t)255;
    return r;
  };
  const size_t QV = 16777216ull;  // B*S*D elements
  const size_t WW = 1048576ull;   // 1024*1024 elements
  char* bufA = alloc(QV * 2);  // q16 -> Khat
  char* bufB = alloc(QV * 2);  // v16 -> probs z-even (32MB)
  char* bufC = alloc(QV * 2);  // Qhat
  char* bufD = alloc(QV * 2);  // VT
  f16* q16 = (f16*)bufA;
  f16* Khat = (f16*)bufA;
  f16* v16 = (f16*)bufB;
  f16* probs0 = (f16*)bufB;  // pair slot 0; slot 1 = weights region (+96MB)
  f16* Qhat = (f16*)bufC;
  f16* VT = (f16*)bufD;
  // weights region: 32 MB from Wq_h onward is reused as probs slot 1
  f16* Wq_h = (f16*)alloc(WW * 2);
  f16* Wq_l = (f16*)alloc(WW * 2);
  f16* Wk_h = (f16*)alloc(WW * 2);
  f16* Wk_l = (f16*)alloc(WW * 2);
  f16* Wr_h = (f16*)alloc(WW * 2);
  f16* Wr_l = (f16*)alloc(WW * 2);
  f16* Wv16 = (f16*)alloc(WW * 2);
  f16* WrT_h = (f16*)alloc(WW * 2);
  f16* WrT_l = (f16*)alloc(WW * 2);
  f16* WvT = (f16*)alloc(WW * 2);
  float* Wtmp32 = (float*)alloc(WW * 8);   // [2][1024][1024] f32
  f16* WqrT2 = (f16*)alloc(WW * 4);        // [1024][2048] hi|lo concat
  f16* WkrT2 = (f16*)alloc(WW * 4);
  float* brq = (float*)alloc(1024 * 4);
  float* brk = (float*)alloc(1024 * 4);
  float* bpart = (float*)alloc(2 * 16 * 1024 * 4);
  float* m_loc = (float*)alloc(2 * 16 * 4096 * 4);  // [z2][tn256][row]
  float* l_loc = (float*)alloc(2 * 16 * 4096 * 4);
  f16* scl = (f16*)alloc(2 * 16 * 4096 * 2);  // [z2][tile256][row] = alpha/l
  const long PSTRIDE = 50331648;  // f16 elems between probs slot 0 and slot 1

  // fp32 -> fp16 conversions (fused dispatches)
  f2h_qv<<<32768, 256, 0, stream>>>(query, value, q16, v16);
  w_conv<<<dim3(1024, 4), 256, 0, stream>>>(Wq, Wk, Wr, Wv, Wq_h, Wq_l, Wk_h,
                                            Wk_l, Wr_h, Wr_l, Wv16);
  tr3<<<dim3(32, 32, 3), dim3(32, 32), 0, stream>>>(Wr_h, WrT_h, Wr_l, WrT_l,
                                                    Wv16, WvT);
  bias_part<<<dim3(4, 16, 2), 256, 0, stream>>>(bq, bk, Wr, bpart);
  bias_red<<<dim3(4, 1, 2), 256, 0, stream>>>(br, bpart, brq, brk);

  // W{q,k}rT = Wr^T @ W{q,k}^T in ~fp32 (Ah@Bh + Ah@Bl + Al@Bh), one z=2 pass
  gemm_bt<5, true, true, 32><<<dim3(8, 8, 2), 256, 0, stream>>>(
      WrT_h, WrT_l, Wq_h, Wq_l, Wtmp32, nullptr, nullptr, 0, 1024, 1024, 1024,
      1024, 1024, 1024, 1048576, 0, 2097152, 0);
  f2h_split2b<<<dim3(1024, 2), 256, 0, stream>>>(Wtmp32, WqrT2,
                                                 Wtmp32 + 1048576, WkrT2);

  // Qhat = cos(query @ Wqr + brq)   [bufC]  (K-concat dual-B, K'=2048)
  g8p<1, 32, true, 4><<<dim3(4, 64, 1), 512, 0, stream>>>(
      q16, WqrT2, Qhat, brq, nullptr, nullptr, 0, 0, 0, 1024, 2048, 1024);
  // Khat = cos(value @ Wkr + brk)   [bufA — q16 dead from here]
  g8p<1, 32, true, 4><<<dim3(4, 64, 1), 512, 0, stream>>>(
      v16, WkrT2, Khat, brk, nullptr, nullptr, 0, 0, 0, 1024, 2048, 1024);
  // VT[u][s] = (value @ Wv + bv)^T = Wv^T @ value^T  (row bias bv)  [bufD]
  gemm_bt<2, false, false, 64><<<dim3(128, 8, 1), 256, 0, stream>>>(
      WvT, nullptr, v16, nullptr, VT, bv, nullptr, 0, 1024, 16384, 1024, 1024,
      1024, 16384, 0, 0, 0, 0);

  // per batch-pair: probs = exp(S - m_tile) + stats; merge; PV (scale folded)
  for (int zb = 0; zb < NB; zb += 2) {
    g8p<6, 16, false, 16><<<dim3(16, 16, 2), 512, 0, stream>>>(
        Qhat + (long)zb * 4194304, Khat + (long)zb * 4194304, probs0, nullptr,
        m_loc, l_loc, 4194304, 4194304, PSTRIDE, 1024, 1024, 4096);
    merge_pair<<<32, 256, 0, stream>>>(m_loc, l_loc, scl);
    gemm_bt<7, false, false, 64><<<dim3(8, 32, 2), 256, 0, stream>>>(
        probs0, nullptr, VT + (long)zb * 4096, nullptr, out + (long)zb * 4194304,
        nullptr, scl, 65536, 4096, 1024, 4096, 4096, 16384, 1024, 4194304,
        PSTRIDE, 4096, 0);
  }
}

// Round 13
// 566.544 us; speedup vs baseline: 1.3541x; 1.0825x over previous
//
#include <hip/hip_runtime.h>
#include <hip/hip_bf16.h>
#include <hip/hip_fp16.h>
#include <cstdint>

// ---------------------------------------------------------------------------
// LinearAttention (random-feature cos kernel + softmax attention), MI355X.
// out = softmax(cos(q@Wq@Wr + br) @ cos(v@Wk@Wr + br)^T) @ (v@Wv + bv)
// B=4, S=4096, D=U=F=1024.  All heavy math in fp16 MFMA with fp32 accum.
// qk + Qhat/Khat: 256x256 / 8 waves / BK=64 / 8-phase, counted vmcnt(4),
//   rect-XCD block swizzle for L2 locality, LDS-repack vectorized epilogue.
//   Wqr stored plain f16 (product computed in ~fp32; storage rounding is
//   comparable to the f16 quantization of Qhat/Khat themselves).
// PV/VT/Wqr: 128x128 2-phase counted-vmcnt.
// Softmax: tile-local max in QK^T epilogue + alpha/l folded into PV.
// ---------------------------------------------------------------------------

typedef _Float16 f16;
typedef _Float16 f16x8 __attribute__((ext_vector_type(8)));
typedef _Float16 f16x4 __attribute__((ext_vector_type(4)));
typedef float f32x4 __attribute__((ext_vector_type(4)));

typedef __attribute__((address_space(1))) unsigned int uas1;
typedef __attribute__((address_space(3))) unsigned int uas3;

#define NB 4
#define SEQ 4096
#define DIM 1024

// async 16B/lane global->LDS. LDS dest must be wave-uniform base (+lane*16).
__device__ __forceinline__ void async_copy16(void* lds, const void* g) {
  __builtin_amdgcn_global_load_lds((uas1*)(uintptr_t)g, (uas3*)(uintptr_t)lds,
                                   16, 0, 0);
}

// ----------------------------- small kernels ------------------------------

// query+value -> f16 in one dispatch (grid 32768)
__global__ __launch_bounds__(256) void f2h_qv(const float* __restrict__ a,
                                              const float* __restrict__ b,
                                              f16* __restrict__ oa,
                                              f16* __restrict__ ob) {
  const int bid = blockIdx.x;
  const float* in = bid < 16384 ? a : b;
  f16* out = bid < 16384 ? oa : ob;
  const int i = (bid & 16383) * 256 + threadIdx.x;
  float4 v = ((const float4*)in)[i];
  f16x4 h = {(f16)v.x, (f16)v.y, (f16)v.z, (f16)v.w};
  ((f16x4*)out)[i] = h;
}

__global__ __launch_bounds__(256) void f2h(const float* __restrict__ in,
                                           f16* __restrict__ out, int n4) {
  int i = blockIdx.x * 256 + threadIdx.x;
  if (i < n4) {
    float4 v = ((const float4*)in)[i];
    f16x4 h = {(f16)v.x, (f16)v.y, (f16)v.z, (f16)v.w};
    ((f16x4*)out)[i] = h;
  }
}

// all four weight conversions in one dispatch: y=0 Wq, 1 Wk, 2 Wr (hi/lo),
// y=3 Wv (plain f16)
__global__ __launch_bounds__(256) void w_conv(
    const float* __restrict__ Wq, const float* __restrict__ Wk,
    const float* __restrict__ Wr, const float* __restrict__ Wv,
    f16* __restrict__ Wq_h, f16* __restrict__ Wq_l, f16* __restrict__ Wk_h,
    f16* __restrict__ Wk_l, f16* __restrict__ Wr_h, f16* __restrict__ Wr_l,
    f16* __restrict__ Wv16) {
  const int which = blockIdx.y;
  const int i = blockIdx.x * 256 + threadIdx.x;
  const float* in = which == 0 ? Wq : which == 1 ? Wk : which == 2 ? Wr : Wv;
  float4 v = ((const float4*)in)[i];
  f16 h0 = (f16)v.x, h1 = (f16)v.y, h2 = (f16)v.z, h3 = (f16)v.w;
  f16x4 hv = {h0, h1, h2, h3};
  if (which == 3) {
    ((f16x4*)Wv16)[i] = hv;
    return;
  }
  f16x4 lv = {(f16)(v.x - (float)h0), (f16)(v.y - (float)h1),
              (f16)(v.z - (float)h2), (f16)(v.w - (float)h3)};
  f16* hi = which == 0 ? Wq_h : which == 1 ? Wk_h : Wr_h;
  f16* lo = which == 0 ? Wq_l : which == 1 ? Wk_l : Wr_l;
  ((f16x4*)hi)[i] = hv;
  ((f16x4*)lo)[i] = lv;
}

// 3 transposes (1024x1024 f16) in one dispatch; z selects pair
__global__ void tr3(const f16* __restrict__ i0, f16* __restrict__ o0,
                    const f16* __restrict__ i1, f16* __restrict__ o1,
                    const f16* __restrict__ i2, f16* __restrict__ o2) {
  __shared__ f16 tile[32][33];
  const f16* in = blockIdx.z == 0 ? i0 : blockIdx.z == 1 ? i1 : i2;
  f16* out = blockIdx.z == 0 ? o0 : blockIdx.z == 1 ? o1 : o2;
  int c0 = blockIdx.x * 32, r0 = blockIdx.y * 32;
  tile[threadIdx.y][threadIdx.x] =
      in[(long)(r0 + threadIdx.y) * 1024 + c0 + threadIdx.x];
  __syncthreads();
  out[(long)(c0 + threadIdx.y) * 1024 + r0 + threadIdx.x] =
      tile[threadIdx.x][threadIdx.y];
}

// bias_eff = br + bvec @ Wr, deterministic 2-stage (partials then reduce)
__global__ __launch_bounds__(256) void bias_part(const float* __restrict__ bq,
                                                 const float* __restrict__ bk,
                                                 const float* __restrict__ Wr,
                                                 float* __restrict__ part) {
  const float* bvec = blockIdx.z ? bk : bq;
  const int f = blockIdx.x * 256 + threadIdx.x;
  const int u0 = blockIdx.y * 64;
  float s = 0.f;
#pragma unroll 8
  for (int u = 0; u < 64; ++u)
    s = fmaf(bvec[u0 + u], Wr[(long)(u0 + u) * DIM + f], s);
  part[(blockIdx.z * 16 + blockIdx.y) * 1024 + f] = s;
}

__global__ __launch_bounds__(256) void bias_red(const float* __restrict__ br,
                                                const float* __restrict__ part,
                                                float* __restrict__ brq,
                                                float* __restrict__ brk) {
  const int f = blockIdx.x * 256 + threadIdx.x;
  float* outb = blockIdx.z ? brk : brq;
  float s = br[f];
#pragma unroll 16
  for (int j = 0; j < 16; ++j) s += part[(blockIdx.z * 16 + j) * 1024 + f];
  outb[f] = s;
}

// per (z2,row): m = max_t m_t; l = sum_t l_t exp(m_t-m);
// scl[t][row] = exp(m_t-m)/l  (f16).  16 tiles of 256 cols.
__global__ __launch_bounds__(256) void merge_pair(const float* __restrict__ ml,
                                                  const float* __restrict__ ll,
                                                  f16* __restrict__ scl) {
  int i = blockIdx.x * 256 + threadIdx.x;  // 0..8191 = z2*4096 + row
  int z2 = i >> 12, row = i & 4095;
  const float* m = ml + z2 * 65536 + row;
  const float* lp = ll + z2 * 65536 + row;
  float a[16];
  float mg = -1e30f;
#pragma unroll 16
  for (int t = 0; t < 16; ++t) mg = fmaxf(mg, m[t * 4096]);
  float l = 0.f;
#pragma unroll 16
  for (int t = 0; t < 16; ++t) {
    a[t] = __expf(m[t * 4096] - mg);
    l += lp[t * 4096] * a[t];
  }
  float li = 1.0f / l;
#pragma unroll 16
  for (int t = 0; t < 16; ++t)
    scl[z2 * 65536 + t * 4096 + row] = (f16)(a[t] * li);
}

__global__ void sentinel(float* out) { out[0] = 12345.0f; }

// ------------- 8-phase 256x256 GEMM template (8 waves, BK=64) --------------
// C = epi(A @ B^T), B row-major [N][ldb].  NT = K/64 tiles.  If WRAPA, A's
// k-index wraps mod 1024 (K-concat dual-precision B).  GX = gridDim.x.
// Rect XCD swizzle: GX==16 -> each XCD owns a 4tm x 8tn rectangle;
//                   GX==4  -> each XCD owns one tn column strip (32 tm).
// EPI 6: probs = exp(S - rowmax_tile) f16 + mout/lout per (z,tn,row)
// EPI 1: f16 __cosf(v + aux[col])
// Both write through an LDS repack (stride 264) -> full-line f16x8 stores.
template <int EPI, int NT, bool WRAPA, int GX>
__global__ __launch_bounds__(512, 2) void g8p(
    const f16* __restrict__ A, const f16* __restrict__ B,
    void* __restrict__ Cv, const float* __restrict__ aux,
    float* __restrict__ mout, float* __restrict__ lout, long sA, long sB,
    long sC, int lda, int ldb, int ldc) {
  constexpr int BUF = 65536;  // 64KB per dbuf: A(32KB)+B(32KB)
  __shared__ __align__(16) char smem[256 * 264 * 2];  // >= 2*BUF; repack space
  __shared__ float red[EPI == 6 ? 4 : 1][EPI == 6 ? 256 : 1];
  // rect XCD swizzle over the 256 (tm,tn) blocks (XCD = linear id % 8)
  const int lin = blockIdx.x + blockIdx.y * GX;
  const int c = lin & 7, j = lin >> 3;
  int tm, tn;
  if constexpr (GX == 16) {  // 4tm x 8tn rect per XCD (6MB working set)
    tm = (c & 3) * 4 + (j & 3);
    tn = (c >> 2) * 8 + (j >> 2);
  } else {  // GX==4: tn column strip per XCD (B panel L2-resident)
    tn = c & 3;
    tm = (c >> 2) * 32 + j;
  }
  const int z = blockIdx.z;
  const int t = threadIdx.x, w = t >> 6, l = t & 63;
  const int l4 = l >> 4, l15 = l & 15;
  const int wm = w >> 2, wn = w & 3;  // 2 x 4 waves; wave out = 128 x 64
  f32x4 acc[8][4] = {};
  const f16* Az = A + (long)z * sA;
  const f16* Bz = B + (long)z * sB;

  // half-tile stage: ht 0=A0,1=A1,2=B0,3=B1 ; 1024 chunks, 2 per thread
  auto STAGE_HT = [&](int buf, int tt, int ht) {
    const bool isA = (ht < 2);
    const f16* src = isA ? Az : Bz;
    const int ld = isA ? lda : ldb;
    const int row0 = (isA ? tm : tn) * 256 + (ht & 1) * 128;
    char* base = smem + buf * BUF + (ht >> 1) * 32768 + (ht & 1) * 16384;
    int kk = tt * 64;
    if (WRAPA && isA) kk &= 1023;
#pragma unroll
    for (int jj = 0; jj < 2; ++jj) {
      const int cb = jj * 512 + w * 64;  // wave-uniform chunk base
      const int cc = cb + l;
      const int r = cc >> 3, s = cc & 7;
      async_copy16(base + cb * 16,
                   src + (long)(row0 + r) * ld + kk + (s ^ (r & 7)) * 8);
    }
  };

  // prologue: tile0 full + B halves of tile1;  vmcnt(4) -> tile0 resident
  STAGE_HT(0, 0, 0);
  STAGE_HT(0, 0, 1);
  STAGE_HT(0, 0, 2);
  STAGE_HT(0, 0, 3);
  STAGE_HT(1, 1, 2);
  STAGE_HT(1, 1, 3);
  asm volatile("s_waitcnt vmcnt(4)" ::: "memory");
  __builtin_amdgcn_s_barrier();

  for (int it = 0; it < NT / 2; ++it) {
    const int tt = 2 * it;
    const bool more = (tt + 2) < NT;
    // ---- phases 1-4: compute tile tt from buf0 ----
    {
      const f16* Ab = (const f16*)(smem);
      const f16* Bb = Ab + 16384;  // +32KB
      f16x8 bfp[4][2];
#pragma unroll
      for (int q = 0; q < 4; ++q) {
        if (q == 0) {
#pragma unroll
          for (int jn = 0; jn < 4; ++jn)
#pragma unroll
            for (int ks = 0; ks < 2; ++ks) {
              const int rb = wn * 64 + jn * 16 + l15;
              const int p = ks * 4 + l4;
              bfp[jn][ks] = *(const f16x8*)&Bb[rb * 64 + (p ^ (rb & 7)) * 8];
            }
        }
        f16x8 af[2][2];
#pragma unroll
        for (int i2 = 0; i2 < 2; ++i2)
#pragma unroll
          for (int ks = 0; ks < 2; ++ks) {
            const int ra = wm * 128 + (q * 2 + i2) * 16 + l15;
            const int p = ks * 4 + l4;
            af[i2][ks] = *(const f16x8*)&Ab[ra * 64 + (p ^ (ra & 7)) * 8];
          }
        if (q == 0) STAGE_HT(1, tt + 1, 0);
        if (q == 1) STAGE_HT(1, tt + 1, 1);
        if (q == 2 && more) STAGE_HT(0, tt + 2, 2);
        if (q == 3) {
          if (more) {
            STAGE_HT(0, tt + 2, 3);
            asm volatile("s_waitcnt vmcnt(4)" ::: "memory");
          } else {
            asm volatile("s_waitcnt vmcnt(0)" ::: "memory");
          }
        }
        __builtin_amdgcn_s_barrier();
        asm volatile("s_waitcnt lgkmcnt(0)" ::: "memory");
        __builtin_amdgcn_s_setprio(1);
#pragma unroll
        for (int i2 = 0; i2 < 2; ++i2)
#pragma unroll
          for (int jn = 0; jn < 4; ++jn)
#pragma unroll
            for (int ks = 0; ks < 2; ++ks)
              acc[q * 2 + i2][jn] = __builtin_amdgcn_mfma_f32_16x16x32_f16(
                  af[i2][ks], bfp[jn][ks], acc[q * 2 + i2][jn], 0, 0, 0);
        __builtin_amdgcn_s_setprio(0);
        __builtin_amdgcn_s_barrier();
      }
    }
    // ---- phases 5-8: compute tile tt+1 from buf1 ----
    {
      const f16* Ab = (const f16*)(smem + BUF);
      const f16* Bb = Ab + 16384;
      f16x8 bfp[4][2];
#pragma unroll
      for (int q = 0; q < 4; ++q) {
        if (q == 0) {
#pragma unroll
          for (int jn = 0; jn < 4; ++jn)
#pragma unroll
            for (int ks = 0; ks < 2; ++ks) {
              const int rb = wn * 64 + jn * 16 + l15;
              const int p = ks * 4 + l4;
              bfp[jn][ks] = *(const f16x8*)&Bb[rb * 64 + (p ^ (rb & 7)) * 8];
            }
        }
        f16x8 af[2][2];
#pragma unroll
        for (int i2 = 0; i2 < 2; ++i2)
#pragma unroll
          for (int ks = 0; ks < 2; ++ks) {
            const int ra = wm * 128 + (q * 2 + i2) * 16 + l15;
            const int p = ks * 4 + l4;
            af[i2][ks] = *(const f16x8*)&Ab[ra * 64 + (p ^ (ra & 7)) * 8];
          }
        if (q == 0 && more) STAGE_HT(0, tt + 2, 0);
        if (q == 1 && more) STAGE_HT(0, tt + 2, 1);
        if (q == 2 && more) STAGE_HT(1, tt + 3, 2);
        if (q == 3) {
          if (more) {
            STAGE_HT(1, tt + 3, 3);
            asm volatile("s_waitcnt vmcnt(4)" ::: "memory");
          } else {
            asm volatile("s_waitcnt vmcnt(0)" ::: "memory");
          }
        }
        __builtin_amdgcn_s_barrier();
        asm volatile("s_waitcnt lgkmcnt(0)" ::: "memory");
        __builtin_amdgcn_s_setprio(1);
#pragma unroll
        for (int i2 = 0; i2 < 2; ++i2)
#pragma unroll
          for (int jn = 0; jn < 4; ++jn)
#pragma unroll
            for (int ks = 0; ks < 2; ++ks)
              acc[q * 2 + i2][jn] = __builtin_amdgcn_mfma_f32_16x16x32_f16(
                  af[i2][ks], bfp[jn][ks], acc[q * 2 + i2][jn], 0, 0, 0);
        __builtin_amdgcn_s_setprio(0);
        __builtin_amdgcn_s_barrier();
      }
    }
  }

  if constexpr (EPI == 6) {
    // ---- tile-local softmax over this 256-col tile ----
    float mrow[32];
#pragma unroll
    for (int i = 0; i < 8; ++i)
#pragma unroll
      for (int r = 0; r < 4; ++r) {
        float v = fmaxf(fmaxf(acc[i][0][r], acc[i][1][r]),
                        fmaxf(acc[i][2][r], acc[i][3][r]));
        v = fmaxf(v, __shfl_xor(v, 1));
        v = fmaxf(v, __shfl_xor(v, 2));
        v = fmaxf(v, __shfl_xor(v, 4));
        v = fmaxf(v, __shfl_xor(v, 8));
        if (l15 == 0) red[wn][wm * 128 + i * 16 + l4 * 4 + r] = v;
      }
    __syncthreads();
#pragma unroll
    for (int i = 0; i < 8; ++i)
#pragma unroll
      for (int r = 0; r < 4; ++r) {
        const int rin = wm * 128 + i * 16 + l4 * 4 + r;
        mrow[i * 4 + r] = fmaxf(fmaxf(red[0][rin], red[1][rin]),
                                fmaxf(red[2][rin], red[3][rin]));
      }
    __syncthreads();
#pragma unroll
    for (int i = 0; i < 8; ++i)
#pragma unroll
      for (int r = 0; r < 4; ++r) {
        const float mn = mrow[i * 4 + r];
        float s = 0.f;
#pragma unroll
        for (int jn = 0; jn < 4; ++jn) {
          float e = __expf(acc[i][jn][r] - mn);
          acc[i][jn][r] = e;
          s += e;
        }
        s += __shfl_xor(s, 1);
        s += __shfl_xor(s, 2);
        s += __shfl_xor(s, 4);
        s += __shfl_xor(s, 8);
        if (l15 == 0) red[wn][wm * 128 + i * 16 + l4 * 4 + r] = s;
      }
    __syncthreads();
    if (wn == 0 && l15 == 0) {
#pragma unroll
      for (int i = 0; i < 8; ++i)
#pragma unroll
        for (int r = 0; r < 4; ++r) {
          const int rin = wm * 128 + i * 16 + l4 * 4 + r;
          const int gidx = z * 65536 + tn * 4096 + tm * 256 + rin;
          mout[gidx] = mrow[i * 4 + r];
          lout[gidx] = red[0][rin] + red[1][rin] + red[2][rin] + red[3][rin];
        }
    }
  }

  // ---- vectorized output: LDS repack (stride 264) -> f16x8 stores ----
  f16* rep = (f16*)smem;
#pragma unroll
  for (int i = 0; i < 8; ++i) {
    const int row0 = wm * 128 + i * 16 + l4 * 4;
#pragma unroll
    for (int jn = 0; jn < 4; ++jn) {
      const int col = wn * 64 + jn * 16 + l15;
#pragma unroll
      for (int r = 0; r < 4; ++r) {
        float v = acc[i][jn][r];
        f16 hv;
        if constexpr (EPI == 1)
          hv = (f16)__cosf(v + aux[tn * 256 + col]);
        else
          hv = (f16)v;
        rep[(row0 + r) * 264 + col] = hv;
      }
    }
  }
  __syncthreads();
#pragma unroll
  for (int k = 0; k < 16; ++k) {
    const int orow = k * 16 + (t >> 5);
    const int oc = (t & 31) * 8;
    *(f16x8*)&((f16*)Cv)[(long)z * sC + (long)(tm * 256 + orow) * ldc +
                         tn * 256 + oc] = *(const f16x8*)&rep[orow * 264 + oc];
  }
}

// ------------------------------- main GEMM --------------------------------
// C[M,N] = epilogue( A@B^T [+ A@Bl^T if DB] [+ Al@B^T if DA] )
// B stored row-major [N,K].  128x128 tile, 4 waves, 4x4 16x16x32 frags/wave.
// Double-buffered LDS, 2-phase pipeline, counted vmcnt (never 0 in loop).
// EPI: 2 f16 v+aux[row] | 5 f32 plain
//      7 f32 plain, A-fragments scaled by ascl[ktile256][arow] (LDS-staged)
template <int EPI, bool DA, bool DB, int BK>
__global__ __launch_bounds__(256) void gemm_bt(
    const f16* __restrict__ Ah, const f16* __restrict__ Al,
    const f16* __restrict__ Bh, const f16* __restrict__ Bl,
    void* __restrict__ Cv, const float* __restrict__ aux,
    const f16* __restrict__ ascl, long sAscl, int M, int N, int K, int lda,
    int ldb, int ldc, long sC, long sA, long sB, int sAux) {
  constexpr int NSTAGE = 2 + (DA ? 1 : 0) + (DB ? 1 : 0);
  constexpr int TILE = 128 * BK * 2;    // bytes per operand tile
  constexpr int CPR = BK / 8;           // 16B chunks per row
  constexpr int CH = 128 * CPR;         // chunks per operand tile
  constexpr int NL = NSTAGE * BK / 16;  // per-thread vmem issues per tile
  static_assert(NL == 6 || NL == 8, "vmcnt literal");
  constexpr int SCLB = (EPI == 7) ? 4096 : 0;
  __shared__ __align__(16) char smem[2 * NSTAGE * TILE + SCLB];

  const int z = blockIdx.z;
  const int tn = blockIdx.x, tm = blockIdx.y;
  const int t = threadIdx.x, w = t >> 6, l = t & 63;
  const int l4 = l >> 4, l15 = l & 15;
  const int wm = w & 1, wn = w >> 1;
  f32x4 acc[4][4] = {};

  const f16* Az = Ah + (long)z * sA;
  const f16* Bz = Bh + (long)z * sB;
  const f16* Alz = nullptr;
  const f16* Blz = nullptr;
  if constexpr (DA) Alz = Al + (long)z * sA;
  if constexpr (DB) Blz = Bl + (long)z * sB;
  f16* sclLds = (f16*)(smem + 2 * NSTAGE * TILE);

  auto swz = [](int r, int p) -> int {
    if constexpr (BK == 64) return p ^ (r & 7);
    else return p ^ ((r >> 1) & 3);
  };

  auto STAGE = [&](int buf, int kk) {
    char* base = smem + buf * (NSTAGE * TILE);
#pragma unroll
    for (int j = 0; j < CH / 256; ++j) {
      const int cb = j * 256 + w * 64;  // wave-uniform chunk base
      const int c = cb + l;
      const int r = c / CPR, pp = c % CPR;
      const int sc = swz(r, pp);
      const long ra = (long)(tm * 128 + r) * lda + kk + sc * 8;
      const long rb = (long)(tn * 128 + r) * ldb + kk + sc * 8;
      async_copy16(base + cb * 16, Az + ra);
      async_copy16(base + TILE + cb * 16, Bz + rb);
      if constexpr (DA) async_copy16(base + 2 * TILE + cb * 16, Alz + ra);
      if constexpr (DB)
        async_copy16(base + (2 + (DA ? 1 : 0)) * TILE + cb * 16, Blz + rb);
    }
  };

  // ---- prologue: stage tile 0 (+ scl table for EPI 7), drain, barrier ----
  STAGE(0, 0);
  if constexpr (EPI == 7) {
    const f16* asclz = ascl + (long)z * sAscl;
    // 16 k-tiles x 128 rows f16 -> 256 chunks; LDS idx c*8 = tile*128 + row
    const int cb = w * 64;
    const int c = cb + l;
    async_copy16(sclLds + cb * 8,
                 asclz + (long)(c >> 4) * M + tm * 128 + (c & 15) * 8);
  }
  asm volatile("s_waitcnt vmcnt(0)" ::: "memory");
  __syncthreads();

  const int nt = K / BK;
  int cur = 0;
  for (int tt = 0; tt < nt; ++tt) {
    const int kk = tt * BK;
    if (tt + 1 < nt) {
      STAGE(cur ^ 1, kk + BK);
      if constexpr (NL == 6)
        asm volatile("s_waitcnt vmcnt(6)" ::: "memory");
      else
        asm volatile("s_waitcnt vmcnt(8)" ::: "memory");
    } else {
      asm volatile("s_waitcnt vmcnt(0)" ::: "memory");
    }
    __syncthreads();

    const f16* As = (const f16*)(smem + cur * (NSTAGE * TILE));
    const f16* Bs = As + TILE / 2;
    const f16* Als = Bs + TILE / 2;
    const f16* Bls = Als + (DA ? TILE / 2 : 0);

    f16 sA4[4];
    if constexpr (EPI == 7) {
      const int tile = kk >> 8;  // 256-wide k-tiles
#pragma unroll
      for (int i = 0; i < 4; ++i)
        sA4[i] = sclLds[tile * 128 + wm * 64 + i * 16 + l15];
    }

#pragma unroll
    for (int ks = 0; ks < BK / 32; ++ks) {
      f16x8 af[4], bf[4];
#pragma unroll
      for (int i = 0; i < 4; ++i) {
        const int ra = wm * 64 + i * 16 + l15;
        const int rb = wn * 64 + i * 16 + l15;
        af[i] = *(const f16x8*)&As[ra * BK + swz(ra, ks * 4 + l4) * 8];
        bf[i] = *(const f16x8*)&Bs[rb * BK + swz(rb, ks * 4 + l4) * 8];
      }
      if constexpr (EPI == 7) {
#pragma unroll
        for (int i = 0; i < 4; ++i) af[i] = af[i] * sA4[i];
      }
#pragma unroll
      for (int i = 0; i < 4; ++i)
#pragma unroll
        for (int jn = 0; jn < 4; ++jn)
          acc[i][jn] = __builtin_amdgcn_mfma_f32_16x16x32_f16(af[i], bf[jn],
                                                              acc[i][jn], 0, 0, 0);
      if constexpr (DB) {
        f16x8 bl[4];
#pragma unroll
        for (int i = 0; i < 4; ++i) {
          const int rb = wn * 64 + i * 16 + l15;
          bl[i] = *(const f16x8*)&Bls[rb * BK + swz(rb, ks * 4 + l4) * 8];
        }
#pragma unroll
        for (int i = 0; i < 4; ++i)
#pragma unroll
          for (int jn = 0; jn < 4; ++jn)
            acc[i][jn] = __builtin_amdgcn_mfma_f32_16x16x32_f16(
                af[i], bl[jn], acc[i][jn], 0, 0, 0);
      }
      if constexpr (DA) {
        f16x8 al[4];
#pragma unroll
        for (int i = 0; i < 4; ++i) {
          const int ra = wm * 64 + i * 16 + l15;
          al[i] = *(const f16x8*)&Als[ra * BK + swz(ra, ks * 4 + l4) * 8];
        }
#pragma unroll
        for (int i = 0; i < 4; ++i)
#pragma unroll
          for (int jn = 0; jn < 4; ++jn)
            acc[i][jn] = __builtin_amdgcn_mfma_f32_16x16x32_f16(
                al[i], bf[jn], acc[i][jn], 0, 0, 0);
      }
    }
    __syncthreads();
    cur ^= 1;
  }

  const float* auxp = aux + (long)z * sAux;

  if constexpr (EPI == 2) {
    // ---- f16 output via LDS repack: [64][136] per half ----
    f16* rep = (f16*)smem;
#pragma unroll
    for (int hh = 0; hh < 2; ++hh) {
      __syncthreads();
#pragma unroll
      for (int ii = 0; ii < 2; ++ii) {
        const int i = hh * 2 + ii;
        const int lrow0 = wm * 32 + ii * 16 + l4 * 4;
#pragma unroll
        for (int jn = 0; jn < 4; ++jn) {
          const int col = wn * 64 + jn * 16 + l15;
#pragma unroll
          for (int r = 0; r < 4; ++r) {
            float v = acc[i][jn][r];
            f16 hv = (f16)(v + auxp[tm * 128 + wm * 64 + i * 16 + l4 * 4 + r]);
            rep[(lrow0 + r) * 136 + col] = hv;
          }
        }
      }
      __syncthreads();
#pragma unroll
      for (int pp = 0; pp < 4; ++pp) {
        const int lrow = pp * 16 + (t >> 4);
        const int grow = tm * 128 + (lrow >> 5) * 64 + hh * 32 + (lrow & 31);
        const int gcol = tn * 128 + (t & 15) * 8;
        *(f16x8*)&((f16*)Cv)[(long)z * sC + (long)grow * ldc + gcol] =
            *(const f16x8*)&rep[lrow * 136 + (t & 15) * 8];
      }
    }
  } else {
    // ---- f32 output via LDS repack: [32][132] per i-group ----
    float* rep = (float*)smem;
#pragma unroll
    for (int i = 0; i < 4; ++i) {
      __syncthreads();
      const int lrow0 = wm * 16 + l4 * 4;
#pragma unroll
      for (int jn = 0; jn < 4; ++jn) {
        const int col = wn * 64 + jn * 16 + l15;
#pragma unroll
        for (int r = 0; r < 4; ++r) rep[(lrow0 + r) * 132 + col] = acc[i][jn][r];
      }
      __syncthreads();
#pragma unroll
      for (int pp = 0; pp < 4; ++pp) {
        const int lrow = pp * 8 + (t >> 5);
        const int grow = tm * 128 + (lrow >> 4) * 64 + i * 16 + (lrow & 15);
        const int gcol = tn * 128 + (t & 31) * 4;
        *(float4*)&((float*)Cv)[(long)z * sC + (long)grow * ldc + gcol] =
            *(const float4*)&rep[lrow * 132 + (t & 31) * 4];
      }
    }
  }
}

// --------------------------------- driver ----------------------------------

extern "C" void kernel_launch(void* const* d_in, const int* in_sizes, int n_in,
                              void* d_out, int out_size, void* d_ws,
                              size_t ws_size, hipStream_t stream) {
  const float* query = (const float*)d_in[0];
  const float* value = (const float*)d_in[1];
  const float* Wq = (const float*)d_in[2];
  const float* bq = (const float*)d_in[3];
  const float* Wk = (const float*)d_in[4];
  const float* bk = (const float*)d_in[5];
  const float* Wv = (const float*)d_in[6];
  const float* bv = (const float*)d_in[7];
  const float* Wr = (const float*)d_in[8];
  const float* br = (const float*)d_in[9];
  float* out = (float*)d_out;

  if (ws_size < 169000000ull) {
    sentinel<<<1, 1, 0, stream>>>(out);
    return;
  }

  char* p = (char*)d_ws;
  auto alloc = [&](size_t bytes) {
    char* r = p;
    p += (bytes + 255) & ~(size_t)255;
    return r;
  };
  const size_t QV = 16777216ull;  // B*S*D elements
  const size_t WW = 1048576ull;   // 1024*1024 elements
  char* bufA = alloc(QV * 2);  // q16 -> Khat
  char* bufB = alloc(QV * 2);  // v16 -> probs z-even (32MB)
  char* bufC = alloc(QV * 2);  // Qhat
  char* bufD = alloc(QV * 2);  // VT
  f16* q16 = (f16*)bufA;
  f16* Khat = (f16*)bufA;
  f16* v16 = (f16*)bufB;
  f16* probs0 = (f16*)bufB;  // pair slot 0; slot 1 = weights region (+96MB)
  f16* Qhat = (f16*)bufC;
  f16* VT = (f16*)bufD;
  // weights region: 32 MB from Wq_h onward is reused as probs slot 1
  f16* Wq_h = (f16*)alloc(WW * 2);
  f16* Wq_l = (f16*)alloc(WW * 2);
  f16* Wk_h = (f16*)alloc(WW * 2);
  f16* Wk_l = (f16*)alloc(WW * 2);
  f16* Wr_h = (f16*)alloc(WW * 2);
  f16* Wr_l = (f16*)alloc(WW * 2);
  f16* Wv16 = (f16*)alloc(WW * 2);
  f16* WrT_h = (f16*)alloc(WW * 2);
  f16* WrT_l = (f16*)alloc(WW * 2);
  f16* WvT = (f16*)alloc(WW * 2);
  float* Wtmp32 = (float*)alloc(WW * 8);  // [2][1024][1024] f32
  f16* Wqr2h = (f16*)alloc(WW * 4);       // [2][1024][1024] plain f16
  float* brq = (float*)alloc(1024 * 4);
  float* brk = (float*)alloc(1024 * 4);
  float* bpart = (float*)alloc(2 * 16 * 1024 * 4);
  float* m_loc = (float*)alloc(2 * 16 * 4096 * 4);  // [z2][tn256][row]
  float* l_loc = (float*)alloc(2 * 16 * 4096 * 4);
  f16* scl = (f16*)alloc(2 * 16 * 4096 * 2);  // [z2][tile256][row] = alpha/l
  const long PSTRIDE = 50331648;  // f16 elems between probs slot 0 and slot 1

  // fp32 -> fp16 conversions (fused dispatches)
  f2h_qv<<<32768, 256, 0, stream>>>(query, value, q16, v16);
  w_conv<<<dim3(1024, 4), 256, 0, stream>>>(Wq, Wk, Wr, Wv, Wq_h, Wq_l, Wk_h,
                                            Wk_l, Wr_h, Wr_l, Wv16);
  tr3<<<dim3(32, 32, 3), dim3(32, 32), 0, stream>>>(Wr_h, WrT_h, Wr_l, WrT_l,
                                                    Wv16, WvT);
  bias_part<<<dim3(4, 16, 2), 256, 0, stream>>>(bq, bk, Wr, bpart);
  bias_red<<<dim3(4, 1, 2), 256, 0, stream>>>(br, bpart, brq, brk);

  // W{q,k}rT = Wr^T @ W{q,k}^T in ~fp32 (Ah@Bh + Ah@Bl + Al@Bh), one z=2 pass
  gemm_bt<5, true, true, 32><<<dim3(8, 8, 2), 256, 0, stream>>>(
      WrT_h, WrT_l, Wq_h, Wq_l, Wtmp32, nullptr, nullptr, 0, 1024, 1024, 1024,
      1024, 1024, 1024, 1048576, 0, 2097152, 0);
  // plain f16 storage of Wqr/Wkr (product stays fp32-accurate; storage
  // rounding ~ the f16 quantization already accepted on Qhat/Khat)
  f2h<<<2048, 256, 0, stream>>>(Wtmp32, Wqr2h, 524288);

  // Qhat = cos(query @ Wqr + brq)   [bufC]
  g8p<1, 16, false, 4><<<dim3(4, 64, 1), 512, 0, stream>>>(
      q16, Wqr2h, Qhat, brq, nullptr, nullptr, 0, 0, 0, 1024, 1024, 1024);
  // Khat = cos(value @ Wkr + brk)   [bufA — q16 dead from here]
  g8p<1, 16, false, 4><<<dim3(4, 64, 1), 512, 0, stream>>>(
      v16, Wqr2h + 1048576, Khat, brk, nullptr, nullptr, 0, 0, 0, 1024, 1024,
      1024);
  // VT[u][s] = (value @ Wv + bv)^T = Wv^T @ value^T  (row bias bv)  [bufD]
  gemm_bt<2, false, false, 64><<<dim3(128, 8, 1), 256, 0, stream>>>(
      WvT, nullptr, v16, nullptr, VT, bv, nullptr, 0, 1024, 16384, 1024, 1024,
      1024, 16384, 0, 0, 0, 0);

  // per batch-pair: probs = exp(S - m_tile) + stats; merge; PV (scale folded)
  for (int zb = 0; zb < NB; zb += 2) {
    g8p<6, 16, false, 16><<<dim3(16, 16, 2), 512, 0, stream>>>(
        Qhat + (long)zb * 4194304, Khat + (long)zb * 4194304, probs0, nullptr,
        m_loc, l_loc, 4194304, 4194304, PSTRIDE, 1024, 1024, 4096);
    merge_pair<<<32, 256, 0, stream>>>(m_loc, l_loc, scl);
    gemm_bt<7, false, false, 64><<<dim3(8, 32, 2), 256, 0, stream>>>(
        probs0, nullptr, VT + (long)zb * 4096, nullptr, out + (long)zb * 4194304,
        nullptr, scl, 65536, 4096, 1024, 4096, 4096, 16384, 1024, 4194304,
        PSTRIDE, 4096, 0);
  }
}

// Round 14
// 565.325 us; speedup vs baseline: 1.3570x; 1.0022x over previous
//
#include <hip/hip_runtime.h>
#include <hip/hip_bf16.h>
#include <hip/hip_fp16.h>
#include <cstdint>

// ---------------------------------------------------------------------------
// LinearAttention (random-feature cos kernel + softmax attention), MI355X.
// out = softmax(cos(q@Wq@Wr + br) @ cos(v@Wk@Wr + br)^T) @ (v@Wv + bv)
// B=4, S=4096, D=U=F=1024.  All heavy math in fp16 MFMA with fp32 accum.
// qk + Qhat/Khat: 256x256 / 8 waves / BK=64 / 4-PHASE schedule (32 MFMA per
//   wave per phase), counted vmcnt(4), rect-XCD swizzle, LDS-repack epilogue.
// PV/VT/Wqr: 128x128 2-phase counted-vmcnt.
// Softmax: tile-local max in QK^T epilogue + alpha/l folded into PV.
// ---------------------------------------------------------------------------

typedef _Float16 f16;
typedef _Float16 f16x8 __attribute__((ext_vector_type(8)));
typedef _Float16 f16x4 __attribute__((ext_vector_type(4)));
typedef float f32x4 __attribute__((ext_vector_type(4)));

typedef __attribute__((address_space(1))) unsigned int uas1;
typedef __attribute__((address_space(3))) unsigned int uas3;

#define NB 4
#define SEQ 4096
#define DIM 1024

// async 16B/lane global->LDS. LDS dest must be wave-uniform base (+lane*16).
__device__ __forceinline__ void async_copy16(void* lds, const void* g) {
  __builtin_amdgcn_global_load_lds((uas1*)(uintptr_t)g, (uas3*)(uintptr_t)lds,
                                   16, 0, 0);
}

// ----------------------------- small kernels ------------------------------

// query+value -> f16 in one dispatch (grid 32768)
__global__ __launch_bounds__(256) void f2h_qv(const float* __restrict__ a,
                                              const float* __restrict__ b,
                                              f16* __restrict__ oa,
                                              f16* __restrict__ ob) {
  const int bid = blockIdx.x;
  const float* in = bid < 16384 ? a : b;
  f16* out = bid < 16384 ? oa : ob;
  const int i = (bid & 16383) * 256 + threadIdx.x;
  float4 v = ((const float4*)in)[i];
  f16x4 h = {(f16)v.x, (f16)v.y, (f16)v.z, (f16)v.w};
  ((f16x4*)out)[i] = h;
}

__global__ __launch_bounds__(256) void f2h(const float* __restrict__ in,
                                           f16* __restrict__ out, int n4) {
  int i = blockIdx.x * 256 + threadIdx.x;
  if (i < n4) {
    float4 v = ((const float4*)in)[i];
    f16x4 h = {(f16)v.x, (f16)v.y, (f16)v.z, (f16)v.w};
    ((f16x4*)out)[i] = h;
  }
}

// all four weight conversions in one dispatch: y=0 Wq, 1 Wk, 2 Wr (hi/lo),
// y=3 Wv (plain f16)
__global__ __launch_bounds__(256) void w_conv(
    const float* __restrict__ Wq, const float* __restrict__ Wk,
    const float* __restrict__ Wr, const float* __restrict__ Wv,
    f16* __restrict__ Wq_h, f16* __restrict__ Wq_l, f16* __restrict__ Wk_h,
    f16* __restrict__ Wk_l, f16* __restrict__ Wr_h, f16* __restrict__ Wr_l,
    f16* __restrict__ Wv16) {
  const int which = blockIdx.y;
  const int i = blockIdx.x * 256 + threadIdx.x;
  const float* in = which == 0 ? Wq : which == 1 ? Wk : which == 2 ? Wr : Wv;
  float4 v = ((const float4*)in)[i];
  f16 h0 = (f16)v.x, h1 = (f16)v.y, h2 = (f16)v.z, h3 = (f16)v.w;
  f16x4 hv = {h0, h1, h2, h3};
  if (which == 3) {
    ((f16x4*)Wv16)[i] = hv;
    return;
  }
  f16x4 lv = {(f16)(v.x - (float)h0), (f16)(v.y - (float)h1),
              (f16)(v.z - (float)h2), (f16)(v.w - (float)h3)};
  f16* hi = which == 0 ? Wq_h : which == 1 ? Wk_h : Wr_h;
  f16* lo = which == 0 ? Wq_l : which == 1 ? Wk_l : Wr_l;
  ((f16x4*)hi)[i] = hv;
  ((f16x4*)lo)[i] = lv;
}

// 3 transposes (1024x1024 f16) in one dispatch; z selects pair
__global__ void tr3(const f16* __restrict__ i0, f16* __restrict__ o0,
                    const f16* __restrict__ i1, f16* __restrict__ o1,
                    const f16* __restrict__ i2, f16* __restrict__ o2) {
  __shared__ f16 tile[32][33];
  const f16* in = blockIdx.z == 0 ? i0 : blockIdx.z == 1 ? i1 : i2;
  f16* out = blockIdx.z == 0 ? o0 : blockIdx.z == 1 ? o1 : o2;
  int c0 = blockIdx.x * 32, r0 = blockIdx.y * 32;
  tile[threadIdx.y][threadIdx.x] =
      in[(long)(r0 + threadIdx.y) * 1024 + c0 + threadIdx.x];
  __syncthreads();
  out[(long)(c0 + threadIdx.y) * 1024 + r0 + threadIdx.x] =
      tile[threadIdx.x][threadIdx.y];
}

// bias_eff = br + bvec @ Wr, deterministic 2-stage (partials then reduce)
__global__ __launch_bounds__(256) void bias_part(const float* __restrict__ bq,
                                                 const float* __restrict__ bk,
                                                 const float* __restrict__ Wr,
                                                 float* __restrict__ part) {
  const float* bvec = blockIdx.z ? bk : bq;
  const int f = blockIdx.x * 256 + threadIdx.x;
  const int u0 = blockIdx.y * 64;
  float s = 0.f;
#pragma unroll 8
  for (int u = 0; u < 64; ++u)
    s = fmaf(bvec[u0 + u], Wr[(long)(u0 + u) * DIM + f], s);
  part[(blockIdx.z * 16 + blockIdx.y) * 1024 + f] = s;
}

__global__ __launch_bounds__(256) void bias_red(const float* __restrict__ br,
                                                const float* __restrict__ part,
                                                float* __restrict__ brq,
                                                float* __restrict__ brk) {
  const int f = blockIdx.x * 256 + threadIdx.x;
  float* outb = blockIdx.z ? brk : brq;
  float s = br[f];
#pragma unroll 16
  for (int j = 0; j < 16; ++j) s += part[(blockIdx.z * 16 + j) * 1024 + f];
  outb[f] = s;
}

// per (z2,row): m = max_t m_t; l = sum_t l_t exp(m_t-m);
// scl[t][row] = exp(m_t-m)/l  (f16).  16 tiles of 256 cols.
__global__ __launch_bounds__(256) void merge_pair(const float* __restrict__ ml,
                                                  const float* __restrict__ ll,
                                                  f16* __restrict__ scl) {
  int i = blockIdx.x * 256 + threadIdx.x;  // 0..8191 = z2*4096 + row
  int z2 = i >> 12, row = i & 4095;
  const float* m = ml + z2 * 65536 + row;
  const float* lp = ll + z2 * 65536 + row;
  float a[16];
  float mg = -1e30f;
#pragma unroll 16
  for (int t = 0; t < 16; ++t) mg = fmaxf(mg, m[t * 4096]);
  float l = 0.f;
#pragma unroll 16
  for (int t = 0; t < 16; ++t) {
    a[t] = __expf(m[t * 4096] - mg);
    l += lp[t * 4096] * a[t];
  }
  float li = 1.0f / l;
#pragma unroll 16
  for (int t = 0; t < 16; ++t)
    scl[z2 * 65536 + t * 4096 + row] = (f16)(a[t] * li);
}

__global__ void sentinel(float* out) { out[0] = 12345.0f; }

// ------------- 4-phase 256x256 GEMM template (8 waves, BK=64) --------------
// C = epi(A @ B^T), B row-major [N][ldb].  NT = K/64 tiles.  GX = gridDim.x.
// Per iteration (2 K-tiles): 4 phases, 32 MFMA/wave each.
// Stage ledger (per-thread issues, HT=2): invariant entering iter =
// {B(t+1):4}.  p0:+A(t+1); p1:+B(t+2),vmcnt(4); p2:+A(t+2); p3:+B(t+3),
// vmcnt(4).  Tail: vmcnt(0) at p1.
// EPI 6: probs = exp(S - rowmax_tile) f16 + mout/lout per (z,tn,row)
// EPI 1: f16 __cosf(v + aux[col])
// Both write through an LDS repack (stride 264) -> full-line f16x8 stores.
template <int EPI, int NT, bool WRAPA, int GX>
__global__ __launch_bounds__(512, 2) void g8p(
    const f16* __restrict__ A, const f16* __restrict__ B,
    void* __restrict__ Cv, const float* __restrict__ aux,
    float* __restrict__ mout, float* __restrict__ lout, long sA, long sB,
    long sC, int lda, int ldb, int ldc) {
  constexpr int BUF = 65536;  // 64KB per dbuf: A(32KB)+B(32KB)
  __shared__ __align__(16) char smem[256 * 264 * 2];  // >= 2*BUF; repack space
  __shared__ float red[EPI == 6 ? 4 : 1][EPI == 6 ? 256 : 1];
  // rect XCD swizzle over the 256 (tm,tn) blocks (XCD = linear id % 8)
  const int lin = blockIdx.x + blockIdx.y * GX;
  const int c = lin & 7, j = lin >> 3;
  int tm, tn;
  if constexpr (GX == 16) {  // 4tm x 8tn rect per XCD (6MB working set)
    tm = (c & 3) * 4 + (j & 3);
    tn = (c >> 2) * 8 + (j >> 2);
  } else {  // GX==4: tn column strip per XCD (B panel L2-resident)
    tn = c & 3;
    tm = (c >> 2) * 32 + j;
  }
  const int z = blockIdx.z;
  const int t = threadIdx.x, w = t >> 6, l = t & 63;
  const int l4 = l >> 4, l15 = l & 15;
  const int wm = w >> 2, wn = w & 3;  // 2 x 4 waves; wave out = 128 x 64
  f32x4 acc[8][4] = {};
  const f16* Az = A + (long)z * sA;
  const f16* Bz = B + (long)z * sB;

  // half-tile stage: ht 0=A0,1=A1,2=B0,3=B1 ; 1024 chunks, 2 per thread
  auto STAGE_HT = [&](int buf, int tt, int ht) {
    const bool isA = (ht < 2);
    const f16* src = isA ? Az : Bz;
    const int ld = isA ? lda : ldb;
    const int row0 = (isA ? tm : tn) * 256 + (ht & 1) * 128;
    char* base = smem + buf * BUF + (ht >> 1) * 32768 + (ht & 1) * 16384;
    int kk = tt * 64;
    if (WRAPA && isA) kk &= 1023;
#pragma unroll
    for (int jj = 0; jj < 2; ++jj) {
      const int cb = jj * 512 + w * 64;  // wave-uniform chunk base
      const int cc = cb + l;
      const int r = cc >> 3, s = cc & 7;
      async_copy16(base + cb * 16,
                   src + (long)(row0 + r) * ld + kk + (s ^ (r & 7)) * 8);
    }
  };

  // prologue: tile0 full + B halves of tile1;  vmcnt(4) -> tile0 resident
  STAGE_HT(0, 0, 0);
  STAGE_HT(0, 0, 1);
  STAGE_HT(0, 0, 2);
  STAGE_HT(0, 0, 3);
  STAGE_HT(1, 1, 2);
  STAGE_HT(1, 1, 3);
  asm volatile("s_waitcnt vmcnt(4)" ::: "memory");
  __builtin_amdgcn_s_barrier();

  for (int it = 0; it < NT / 2; ++it) {
    const int tt = 2 * it;
    const bool more = (tt + 2) < NT;  // == (tt+3) < NT for even NT
    // ---- tile tt from buf0: phases p0 (rows 0-3), p1 (rows 4-7) ----
    {
      const f16* Ab = (const f16*)(smem);
      const f16* Bb = Ab + 16384;  // +32KB
      f16x8 bfp[4][2];
#pragma unroll
      for (int jn = 0; jn < 4; ++jn)
#pragma unroll
        for (int ks = 0; ks < 2; ++ks) {
          const int rb = wn * 64 + jn * 16 + l15;
          const int p = ks * 4 + l4;
          bfp[jn][ks] = *(const f16x8*)&Bb[rb * 64 + (p ^ (rb & 7)) * 8];
        }
      {  // p0
        f16x8 af[4][2];
#pragma unroll
        for (int i2 = 0; i2 < 4; ++i2)
#pragma unroll
          for (int ks = 0; ks < 2; ++ks) {
            const int ra = wm * 128 + i2 * 16 + l15;
            const int p = ks * 4 + l4;
            af[i2][ks] = *(const f16x8*)&Ab[ra * 64 + (p ^ (ra & 7)) * 8];
          }
        STAGE_HT(1, tt + 1, 0);
        STAGE_HT(1, tt + 1, 1);
        __builtin_amdgcn_s_barrier();
        asm volatile("s_waitcnt lgkmcnt(0)" ::: "memory");
        __builtin_amdgcn_s_setprio(1);
#pragma unroll
        for (int i2 = 0; i2 < 4; ++i2)
#pragma unroll
          for (int jn = 0; jn < 4; ++jn)
#pragma unroll
            for (int ks = 0; ks < 2; ++ks)
              acc[i2][jn] = __builtin_amdgcn_mfma_f32_16x16x32_f16(
                  af[i2][ks], bfp[jn][ks], acc[i2][jn], 0, 0, 0);
        __builtin_amdgcn_s_setprio(0);
        __builtin_amdgcn_s_barrier();
      }
      {  // p1
        f16x8 af[4][2];
#pragma unroll
        for (int i2 = 0; i2 < 4; ++i2)
#pragma unroll
          for (int ks = 0; ks < 2; ++ks) {
            const int ra = wm * 128 + (4 + i2) * 16 + l15;
            const int p = ks * 4 + l4;
            af[i2][ks] = *(const f16x8*)&Ab[ra * 64 + (p ^ (ra & 7)) * 8];
          }
        if (more) {
          STAGE_HT(0, tt + 2, 2);
          STAGE_HT(0, tt + 2, 3);
          asm volatile("s_waitcnt vmcnt(4)" ::: "memory");
        } else {
          asm volatile("s_waitcnt vmcnt(0)" ::: "memory");
        }
        __builtin_amdgcn_s_barrier();
        asm volatile("s_waitcnt lgkmcnt(0)" ::: "memory");
        __builtin_amdgcn_s_setprio(1);
#pragma unroll
        for (int i2 = 0; i2 < 4; ++i2)
#pragma unroll
          for (int jn = 0; jn < 4; ++jn)
#pragma unroll
            for (int ks = 0; ks < 2; ++ks)
              acc[4 + i2][jn] = __builtin_amdgcn_mfma_f32_16x16x32_f16(
                  af[i2][ks], bfp[jn][ks], acc[4 + i2][jn], 0, 0, 0);
        __builtin_amdgcn_s_setprio(0);
        __builtin_amdgcn_s_barrier();
      }
    }
    // ---- tile tt+1 from buf1: phases p2 (rows 0-3), p3 (rows 4-7) ----
    {
      const f16* Ab = (const f16*)(smem + BUF);
      const f16* Bb = Ab + 16384;
      f16x8 bfp[4][2];
#pragma unroll
      for (int jn = 0; jn < 4; ++jn)
#pragma unroll
        for (int ks = 0; ks < 2; ++ks) {
          const int rb = wn * 64 + jn * 16 + l15;
          const int p = ks * 4 + l4;
          bfp[jn][ks] = *(const f16x8*)&Bb[rb * 64 + (p ^ (rb & 7)) * 8];
        }
      {  // p2
        f16x8 af[4][2];
#pragma unroll
        for (int i2 = 0; i2 < 4; ++i2)
#pragma unroll
          for (int ks = 0; ks < 2; ++ks) {
            const int ra = wm * 128 + i2 * 16 + l15;
            const int p = ks * 4 + l4;
            af[i2][ks] = *(const f16x8*)&Ab[ra * 64 + (p ^ (ra & 7)) * 8];
          }
        if (more) {
          STAGE_HT(0, tt + 2, 0);
          STAGE_HT(0, tt + 2, 1);
        }
        __builtin_amdgcn_s_barrier();
        asm volatile("s_waitcnt lgkmcnt(0)" ::: "memory");
        __builtin_amdgcn_s_setprio(1);
#pragma unroll
        for (int i2 = 0; i2 < 4; ++i2)
#pragma unroll
          for (int jn = 0; jn < 4; ++jn)
#pragma unroll
            for (int ks = 0; ks < 2; ++ks)
              acc[i2][jn] = __builtin_amdgcn_mfma_f32_16x16x32_f16(
                  af[i2][ks], bfp[jn][ks], acc[i2][jn], 0, 0, 0);
        __builtin_amdgcn_s_setprio(0);
        __builtin_amdgcn_s_barrier();
      }
      {  // p3
        f16x8 af[4][2];
#pragma unroll
        for (int i2 = 0; i2 < 4; ++i2)
#pragma unroll
          for (int ks = 0; ks < 2; ++ks) {
            const int ra = wm * 128 + (4 + i2) * 16 + l15;
            const int p = ks * 4 + l4;
            af[i2][ks] = *(const f16x8*)&Ab[ra * 64 + (p ^ (ra & 7)) * 8];
          }
        if (more) {
          STAGE_HT(1, tt + 3, 2);
          STAGE_HT(1, tt + 3, 3);
          asm volatile("s_waitcnt vmcnt(4)" ::: "memory");
        }
        __builtin_amdgcn_s_barrier();
        asm volatile("s_waitcnt lgkmcnt(0)" ::: "memory");
        __builtin_amdgcn_s_setprio(1);
#pragma unroll
        for (int i2 = 0; i2 < 4; ++i2)
#pragma unroll
          for (int jn = 0; jn < 4; ++jn)
#pragma unroll
            for (int ks = 0; ks < 2; ++ks)
              acc[4 + i2][jn] = __builtin_amdgcn_mfma_f32_16x16x32_f16(
                  af[i2][ks], bfp[jn][ks], acc[4 + i2][jn], 0, 0, 0);
        __builtin_amdgcn_s_setprio(0);
        __builtin_amdgcn_s_barrier();
      }
    }
  }

  if constexpr (EPI == 6) {
    // ---- tile-local softmax over this 256-col tile ----
    float mrow[32];
#pragma unroll
    for (int i = 0; i < 8; ++i)
#pragma unroll
      for (int r = 0; r < 4; ++r) {
        float v = fmaxf(fmaxf(acc[i][0][r], acc[i][1][r]),
                        fmaxf(acc[i][2][r], acc[i][3][r]));
        v = fmaxf(v, __shfl_xor(v, 1));
        v = fmaxf(v, __shfl_xor(v, 2));
        v = fmaxf(v, __shfl_xor(v, 4));
        v = fmaxf(v, __shfl_xor(v, 8));
        if (l15 == 0) red[wn][wm * 128 + i * 16 + l4 * 4 + r] = v;
      }
    __syncthreads();
#pragma unroll
    for (int i = 0; i < 8; ++i)
#pragma unroll
      for (int r = 0; r < 4; ++r) {
        const int rin = wm * 128 + i * 16 + l4 * 4 + r;
        mrow[i * 4 + r] = fmaxf(fmaxf(red[0][rin], red[1][rin]),
                                fmaxf(red[2][rin], red[3][rin]));
      }
    __syncthreads();
#pragma unroll
    for (int i = 0; i < 8; ++i)
#pragma unroll
      for (int r = 0; r < 4; ++r) {
        const float mn = mrow[i * 4 + r];
        float s = 0.f;
#pragma unroll
        for (int jn = 0; jn < 4; ++jn) {
          float e = __expf(acc[i][jn][r] - mn);
          acc[i][jn][r] = e;
          s += e;
        }
        s += __shfl_xor(s, 1);
        s += __shfl_xor(s, 2);
        s += __shfl_xor(s, 4);
        s += __shfl_xor(s, 8);
        if (l15 == 0) red[wn][wm * 128 + i * 16 + l4 * 4 + r] = s;
      }
    __syncthreads();
    if (wn == 0 && l15 == 0) {
#pragma unroll
      for (int i = 0; i < 8; ++i)
#pragma unroll
        for (int r = 0; r < 4; ++r) {
          const int rin = wm * 128 + i * 16 + l4 * 4 + r;
          const int gidx = z * 65536 + tn * 4096 + tm * 256 + rin;
          mout[gidx] = mrow[i * 4 + r];
          lout[gidx] = red[0][rin] + red[1][rin] + red[2][rin] + red[3][rin];
        }
    }
  }

  // ---- vectorized output: LDS repack (stride 264) -> f16x8 stores ----
  f16* rep = (f16*)smem;
#pragma unroll
  for (int i = 0; i < 8; ++i) {
    const int row0 = wm * 128 + i * 16 + l4 * 4;
#pragma unroll
    for (int jn = 0; jn < 4; ++jn) {
      const int col = wn * 64 + jn * 16 + l15;
#pragma unroll
      for (int r = 0; r < 4; ++r) {
        float v = acc[i][jn][r];
        f16 hv;
        if constexpr (EPI == 1)
          hv = (f16)__cosf(v + aux[tn * 256 + col]);
        else
          hv = (f16)v;
        rep[(row0 + r) * 264 + col] = hv;
      }
    }
  }
  __syncthreads();
#pragma unroll
  for (int k = 0; k < 16; ++k) {
    const int orow = k * 16 + (t >> 5);
    const int oc = (t & 31) * 8;
    *(f16x8*)&((f16*)Cv)[(long)z * sC + (long)(tm * 256 + orow) * ldc +
                         tn * 256 + oc] = *(const f16x8*)&rep[orow * 264 + oc];
  }
}

// ------------------------------- main GEMM --------------------------------
// C[M,N] = epilogue( A@B^T [+ A@Bl^T if DB] [+ Al@B^T if DA] )
// B stored row-major [N,K].  128x128 tile, 4 waves, 4x4 16x16x32 frags/wave.
// Double-buffered LDS, 2-phase pipeline, counted vmcnt (never 0 in loop).
// EPI: 2 f16 v+aux[row] | 5 f32 plain
//      7 f32 plain, A-fragments scaled by ascl[ktile256][arow] (LDS-staged)
template <int EPI, bool DA, bool DB, int BK>
__global__ __launch_bounds__(256) void gemm_bt(
    const f16* __restrict__ Ah, const f16* __restrict__ Al,
    const f16* __restrict__ Bh, const f16* __restrict__ Bl,
    void* __restrict__ Cv, const float* __restrict__ aux,
    const f16* __restrict__ ascl, long sAscl, int M, int N, int K, int lda,
    int ldb, int ldc, long sC, long sA, long sB, int sAux) {
  constexpr int NSTAGE = 2 + (DA ? 1 : 0) + (DB ? 1 : 0);
  constexpr int TILE = 128 * BK * 2;    // bytes per operand tile
  constexpr int CPR = BK / 8;           // 16B chunks per row
  constexpr int CH = 128 * CPR;         // chunks per operand tile
  constexpr int NL = NSTAGE * BK / 16;  // per-thread vmem issues per tile
  static_assert(NL == 6 || NL == 8, "vmcnt literal");
  constexpr int SCLB = (EPI == 7) ? 4096 : 0;
  __shared__ __align__(16) char smem[2 * NSTAGE * TILE + SCLB];

  const int z = blockIdx.z;
  const int tn = blockIdx.x, tm = blockIdx.y;
  const int t = threadIdx.x, w = t >> 6, l = t & 63;
  const int l4 = l >> 4, l15 = l & 15;
  const int wm = w & 1, wn = w >> 1;
  f32x4 acc[4][4] = {};

  const f16* Az = Ah + (long)z * sA;
  const f16* Bz = Bh + (long)z * sB;
  const f16* Alz = nullptr;
  const f16* Blz = nullptr;
  if constexpr (DA) Alz = Al + (long)z * sA;
  if constexpr (DB) Blz = Bl + (long)z * sB;
  f16* sclLds = (f16*)(smem + 2 * NSTAGE * TILE);

  auto swz = [](int r, int p) -> int {
    if constexpr (BK == 64) return p ^ (r & 7);
    else return p ^ ((r >> 1) & 3);
  };

  auto STAGE = [&](int buf, int kk) {
    char* base = smem + buf * (NSTAGE * TILE);
#pragma unroll
    for (int j = 0; j < CH / 256; ++j) {
      const int cb = j * 256 + w * 64;  // wave-uniform chunk base
      const int c = cb + l;
      const int r = c / CPR, pp = c % CPR;
      const int sc = swz(r, pp);
      const long ra = (long)(tm * 128 + r) * lda + kk + sc * 8;
      const long rb = (long)(tn * 128 + r) * ldb + kk + sc * 8;
      async_copy16(base + cb * 16, Az + ra);
      async_copy16(base + TILE + cb * 16, Bz + rb);
      if constexpr (DA) async_copy16(base + 2 * TILE + cb * 16, Alz + ra);
      if constexpr (DB)
        async_copy16(base + (2 + (DA ? 1 : 0)) * TILE + cb * 16, Blz + rb);
    }
  };

  // ---- prologue: stage tile 0 (+ scl table for EPI 7), drain, barrier ----
  STAGE(0, 0);
  if constexpr (EPI == 7) {
    const f16* asclz = ascl + (long)z * sAscl;
    // 16 k-tiles x 128 rows f16 -> 256 chunks; LDS idx c*8 = tile*128 + row
    const int cb = w * 64;
    const int c = cb + l;
    async_copy16(sclLds + cb * 8,
                 asclz + (long)(c >> 4) * M + tm * 128 + (c & 15) * 8);
  }
  asm volatile("s_waitcnt vmcnt(0)" ::: "memory");
  __syncthreads();

  const int nt = K / BK;
  int cur = 0;
  for (int tt = 0; tt < nt; ++tt) {
    const int kk = tt * BK;
    if (tt + 1 < nt) {
      STAGE(cur ^ 1, kk + BK);
      if constexpr (NL == 6)
        asm volatile("s_waitcnt vmcnt(6)" ::: "memory");
      else
        asm volatile("s_waitcnt vmcnt(8)" ::: "memory");
    } else {
      asm volatile("s_waitcnt vmcnt(0)" ::: "memory");
    }
    __syncthreads();

    const f16* As = (const f16*)(smem + cur * (NSTAGE * TILE));
    const f16* Bs = As + TILE / 2;
    const f16* Als = Bs + TILE / 2;
    const f16* Bls = Als + (DA ? TILE / 2 : 0);

    f16 sA4[4];
    if constexpr (EPI == 7) {
      const int tile = kk >> 8;  // 256-wide k-tiles
#pragma unroll
      for (int i = 0; i < 4; ++i)
        sA4[i] = sclLds[tile * 128 + wm * 64 + i * 16 + l15];
    }

#pragma unroll
    for (int ks = 0; ks < BK / 32; ++ks) {
      f16x8 af[4], bf[4];
#pragma unroll
      for (int i = 0; i < 4; ++i) {
        const int ra = wm * 64 + i * 16 + l15;
        const int rb = wn * 64 + i * 16 + l15;
        af[i] = *(const f16x8*)&As[ra * BK + swz(ra, ks * 4 + l4) * 8];
        bf[i] = *(const f16x8*)&Bs[rb * BK + swz(rb, ks * 4 + l4) * 8];
      }
      if constexpr (EPI == 7) {
#pragma unroll
        for (int i = 0; i < 4; ++i) af[i] = af[i] * sA4[i];
      }
#pragma unroll
      for (int i = 0; i < 4; ++i)
#pragma unroll
        for (int jn = 0; jn < 4; ++jn)
          acc[i][jn] = __builtin_amdgcn_mfma_f32_16x16x32_f16(af[i], bf[jn],
                                                              acc[i][jn], 0, 0, 0);
      if constexpr (DB) {
        f16x8 bl[4];
#pragma unroll
        for (int i = 0; i < 4; ++i) {
          const int rb = wn * 64 + i * 16 + l15;
          bl[i] = *(const f16x8*)&Bls[rb * BK + swz(rb, ks * 4 + l4) * 8];
        }
#pragma unroll
        for (int i = 0; i < 4; ++i)
#pragma unroll
          for (int jn = 0; jn < 4; ++jn)
            acc[i][jn] = __builtin_amdgcn_mfma_f32_16x16x32_f16(
                af[i], bl[jn], acc[i][jn], 0, 0, 0);
      }
      if constexpr (DA) {
        f16x8 al[4];
#pragma unroll
        for (int i = 0; i < 4; ++i) {
          const int ra = wm * 64 + i * 16 + l15;
          al[i] = *(const f16x8*)&Als[ra * BK + swz(ra, ks * 4 + l4) * 8];
        }
#pragma unroll
        for (int i = 0; i < 4; ++i)
#pragma unroll
          for (int jn = 0; jn < 4; ++jn)
            acc[i][jn] = __builtin_amdgcn_mfma_f32_16x16x32_f16(
                al[i], bf[jn], acc[i][jn], 0, 0, 0);
      }
    }
    __syncthreads();
    cur ^= 1;
  }

  const float* auxp = aux + (long)z * sAux;

  if constexpr (EPI == 2) {
    // ---- f16 output via LDS repack: [64][136] per half ----
    f16* rep = (f16*)smem;
#pragma unroll
    for (int hh = 0; hh < 2; ++hh) {
      __syncthreads();
#pragma unroll
      for (int ii = 0; ii < 2; ++ii) {
        const int i = hh * 2 + ii;
        const int lrow0 = wm * 32 + ii * 16 + l4 * 4;
#pragma unroll
        for (int jn = 0; jn < 4; ++jn) {
          const int col = wn * 64 + jn * 16 + l15;
#pragma unroll
          for (int r = 0; r < 4; ++r) {
            float v = acc[i][jn][r];
            f16 hv = (f16)(v + auxp[tm * 128 + wm * 64 + i * 16 + l4 * 4 + r]);
            rep[(lrow0 + r) * 136 + col] = hv;
          }
        }
      }
      __syncthreads();
#pragma unroll
      for (int pp = 0; pp < 4; ++pp) {
        const int lrow = pp * 16 + (t >> 4);
        const int grow = tm * 128 + (lrow >> 5) * 64 + hh * 32 + (lrow & 31);
        const int gcol = tn * 128 + (t & 15) * 8;
        *(f16x8*)&((f16*)Cv)[(long)z * sC + (long)grow * ldc + gcol] =
            *(const f16x8*)&rep[lrow * 136 + (t & 15) * 8];
      }
    }
  } else {
    // ---- f32 output via LDS repack: [32][132] per i-group ----
    float* rep = (float*)smem;
#pragma unroll
    for (int i = 0; i < 4; ++i) {
      __syncthreads();
      const int lrow0 = wm * 16 + l4 * 4;
#pragma unroll
      for (int jn = 0; jn < 4; ++jn) {
        const int col = wn * 64 + jn * 16 + l15;
#pragma unroll
        for (int r = 0; r < 4; ++r) rep[(lrow0 + r) * 132 + col] = acc[i][jn][r];
      }
      __syncthreads();
#pragma unroll
      for (int pp = 0; pp < 4; ++pp) {
        const int lrow = pp * 8 + (t >> 5);
        const int grow = tm * 128 + (lrow >> 4) * 64 + i * 16 + (lrow & 15);
        const int gcol = tn * 128 + (t & 31) * 4;
        *(float4*)&((float*)Cv)[(long)z * sC + (long)grow * ldc + gcol] =
            *(const float4*)&rep[lrow * 132 + (t & 31) * 4];
      }
    }
  }
}

// --------------------------------- driver ----------------------------------

extern "C" void kernel_launch(void* const* d_in, const int* in_sizes, int n_in,
                              void* d_out, int out_size, void* d_ws,
                              size_t ws_size, hipStream_t stream) {
  const float* query = (const float*)d_in[0];
  const float* value = (const float*)d_in[1];
  const float* Wq = (const float*)d_in[2];
  const float* bq = (const float*)d_in[3];
  const float* Wk = (const float*)d_in[4];
  const float* bk = (const float*)d_in[5];
  const float* Wv = (const float*)d_in[6];
  const float* bv = (const float*)d_in[7];
  const float* Wr = (const float*)d_in[8];
  const float* br = (const float*)d_in[9];
  float* out = (float*)d_out;

  if (ws_size < 169000000ull) {
    sentinel<<<1, 1, 0, stream>>>(out);
    return;
  }

  char* p = (char*)d_ws;
  auto alloc = [&](size_t bytes) {
    char* r = p;
    p += (bytes + 255) & ~(size_t)255;
    return r;
  };
  const size_t QV = 16777216ull;  // B*S*D elements
  const size_t WW = 1048576ull;   // 1024*1024 elements
  char* bufA = alloc(QV * 2);  // q16 -> Khat
  char* bufB = alloc(QV * 2);  // v16 -> probs z-even (32MB)
  char* bufC = alloc(QV * 2);  // Qhat
  char* bufD = alloc(QV * 2);  // VT
  f16* q16 = (f16*)bufA;
  f16* Khat = (f16*)bufA;
  f16* v16 = (f16*)bufB;
  f16* probs0 = (f16*)bufB;  // pair slot 0; slot 1 = weights region (+96MB)
  f16* Qhat = (f16*)bufC;
  f16* VT = (f16*)bufD;
  // weights region: 32 MB from Wq_h onward is reused as probs slot 1
  f16* Wq_h = (f16*)alloc(WW * 2);
  f16* Wq_l = (f16*)alloc(WW * 2);
  f16* Wk_h = (f16*)alloc(WW * 2);
  f16* Wk_l = (f16*)alloc(WW * 2);
  f16* Wr_h = (f16*)alloc(WW * 2);
  f16* Wr_l = (f16*)alloc(WW * 2);
  f16* Wv16 = (f16*)alloc(WW * 2);
  f16* WrT_h = (f16*)alloc(WW * 2);
  f16* WrT_l = (f16*)alloc(WW * 2);
  f16* WvT = (f16*)alloc(WW * 2);
  float* Wtmp32 = (float*)alloc(WW * 8);  // [2][1024][1024] f32
  f16* Wqr2h = (f16*)alloc(WW * 4);       // [2][1024][1024] plain f16
  float* brq = (float*)alloc(1024 * 4);
  float* brk = (float*)alloc(1024 * 4);
  float* bpart = (float*)alloc(2 * 16 * 1024 * 4);
  float* m_loc = (float*)alloc(2 * 16 * 4096 * 4);  // [z2][tn256][row]
  float* l_loc = (float*)alloc(2 * 16 * 4096 * 4);
  f16* scl = (f16*)alloc(2 * 16 * 4096 * 2);  // [z2][tile256][row] = alpha/l
  const long PSTRIDE = 50331648;  // f16 elems between probs slot 0 and slot 1

  // fp32 -> fp16 conversions (fused dispatches)
  f2h_qv<<<32768, 256, 0, stream>>>(query, value, q16, v16);
  w_conv<<<dim3(1024, 4), 256, 0, stream>>>(Wq, Wk, Wr, Wv, Wq_h, Wq_l, Wk_h,
                                            Wk_l, Wr_h, Wr_l, Wv16);
  tr3<<<dim3(32, 32, 3), dim3(32, 32), 0, stream>>>(Wr_h, WrT_h, Wr_l, WrT_l,
                                                    Wv16, WvT);
  bias_part<<<dim3(4, 16, 2), 256, 0, stream>>>(bq, bk, Wr, bpart);
  bias_red<<<dim3(4, 1, 2), 256, 0, stream>>>(br, bpart, brq, brk);

  // W{q,k}rT = Wr^T @ W{q,k}^T in ~fp32 (Ah@Bh + Ah@Bl + Al@Bh), one z=2 pass
  gemm_bt<5, true, true, 32><<<dim3(8, 8, 2), 256, 0, stream>>>(
      WrT_h, WrT_l, Wq_h, Wq_l, Wtmp32, nullptr, nullptr, 0, 1024, 1024, 1024,
      1024, 1024, 1024, 1048576, 0, 2097152, 0);
  // plain f16 storage of Wqr/Wkr (product stays fp32-accurate; storage
  // rounding ~ the f16 quantization already accepted on Qhat/Khat)
  f2h<<<2048, 256, 0, stream>>>(Wtmp32, Wqr2h, 524288);

  // Qhat = cos(query @ Wqr + brq)   [bufC]
  g8p<1, 16, false, 4><<<dim3(4, 64, 1), 512, 0, stream>>>(
      q16, Wqr2h, Qhat, brq, nullptr, nullptr, 0, 0, 0, 1024, 1024, 1024);
  // Khat = cos(value @ Wkr + brk)   [bufA — q16 dead from here]
  g8p<1, 16, false, 4><<<dim3(4, 64, 1), 512, 0, stream>>>(
      v16, Wqr2h + 1048576, Khat, brk, nullptr, nullptr, 0, 0, 0, 1024, 1024,
      1024);
  // VT[u][s] = (value @ Wv + bv)^T = Wv^T @ value^T  (row bias bv)  [bufD]
  gemm_bt<2, false, false, 64><<<dim3(128, 8, 1), 256, 0, stream>>>(
      WvT, nullptr, v16, nullptr, VT, bv, nullptr, 0, 1024, 16384, 1024, 1024,
      1024, 16384, 0, 0, 0, 0);

  // per batch-pair: probs = exp(S - m_tile) + stats; merge; PV (scale folded)
  for (int zb = 0; zb < NB; zb += 2) {
    g8p<6, 16, false, 16><<<dim3(16, 16, 2), 512, 0, stream>>>(
        Qhat + (long)zb * 4194304, Khat + (long)zb * 4194304, probs0, nullptr,
        m_loc, l_loc, 4194304, 4194304, PSTRIDE, 1024, 1024, 4096);
    merge_pair<<<32, 256, 0, stream>>>(m_loc, l_loc, scl);
    gemm_bt<7, false, false, 64><<<dim3(8, 32, 2), 256, 0, stream>>>(
        probs0, nullptr, VT + (long)zb * 4096, nullptr, out + (long)zb * 4194304,
        nullptr, scl, 65536, 4096, 1024, 4096, 4096, 16384, 1024, 4194304,
        PSTRIDE, 4096, 0);
  }
}

// Round 15
// 560.598 us; speedup vs baseline: 1.3684x; 1.0084x over previous
//
#include <hip/hip_runtime.h>
#include <hip/hip_bf16.h>
#include <hip/hip_fp16.h>
#include <cstdint>

// ---------------------------------------------------------------------------
// LinearAttention (random-feature cos kernel + softmax attention), MI355X.
// out = softmax(cos(q@Wq@Wr + br) @ cos(v@Wk@Wr + br)^T) @ (v@Wv + bv)
// B=4, S=4096, D=U=F=1024.  All heavy math in fp16 MFMA with fp32 accum.
// qk + Qhat/Khat: 256x256 / 8 waves / BK=64 / 4-phase, counted vmcnt(4),
//   rect-XCD swizzle, LDS-repack vectorized epilogue.
// PV/VT/Wqr: 128x128 2-phase counted-vmcnt.  PV fuses the softmax-merge
//   (alpha/l from per-tile m,l stats) into its prologue — no merge kernel.
// ---------------------------------------------------------------------------

typedef _Float16 f16;
typedef _Float16 f16x8 __attribute__((ext_vector_type(8)));
typedef _Float16 f16x4 __attribute__((ext_vector_type(4)));
typedef float f32x4 __attribute__((ext_vector_type(4)));

typedef __attribute__((address_space(1))) unsigned int uas1;
typedef __attribute__((address_space(3))) unsigned int uas3;

#define NB 4
#define SEQ 4096
#define DIM 1024

// async 16B/lane global->LDS. LDS dest must be wave-uniform base (+lane*16).
__device__ __forceinline__ void async_copy16(void* lds, const void* g) {
  __builtin_amdgcn_global_load_lds((uas1*)(uintptr_t)g, (uas3*)(uintptr_t)lds,
                                   16, 0, 0);
}

// ----------------------------- small kernels ------------------------------

// query+value -> f16 in one dispatch (grid 32768)
__global__ __launch_bounds__(256) void f2h_qv(const float* __restrict__ a,
                                              const float* __restrict__ b,
                                              f16* __restrict__ oa,
                                              f16* __restrict__ ob) {
  const int bid = blockIdx.x;
  const float* in = bid < 16384 ? a : b;
  f16* out = bid < 16384 ? oa : ob;
  const int i = (bid & 16383) * 256 + threadIdx.x;
  float4 v = ((const float4*)in)[i];
  f16x4 h = {(f16)v.x, (f16)v.y, (f16)v.z, (f16)v.w};
  ((f16x4*)out)[i] = h;
}

// all four weight conversions in one dispatch: y=0 Wq, 1 Wk, 2 Wr (hi/lo),
// y=3 Wv (plain f16)
__global__ __launch_bounds__(256) void w_conv(
    const float* __restrict__ Wq, const float* __restrict__ Wk,
    const float* __restrict__ Wr, const float* __restrict__ Wv,
    f16* __restrict__ Wq_h, f16* __restrict__ Wq_l, f16* __restrict__ Wk_h,
    f16* __restrict__ Wk_l, f16* __restrict__ Wr_h, f16* __restrict__ Wr_l,
    f16* __restrict__ Wv16) {
  const int which = blockIdx.y;
  const int i = blockIdx.x * 256 + threadIdx.x;
  const float* in = which == 0 ? Wq : which == 1 ? Wk : which == 2 ? Wr : Wv;
  float4 v = ((const float4*)in)[i];
  f16 h0 = (f16)v.x, h1 = (f16)v.y, h2 = (f16)v.z, h3 = (f16)v.w;
  f16x4 hv = {h0, h1, h2, h3};
  if (which == 3) {
    ((f16x4*)Wv16)[i] = hv;
    return;
  }
  f16x4 lv = {(f16)(v.x - (float)h0), (f16)(v.y - (float)h1),
              (f16)(v.z - (float)h2), (f16)(v.w - (float)h3)};
  f16* hi = which == 0 ? Wq_h : which == 1 ? Wk_h : Wr_h;
  f16* lo = which == 0 ? Wq_l : which == 1 ? Wk_l : Wr_l;
  ((f16x4*)hi)[i] = hv;
  ((f16x4*)lo)[i] = lv;
}

// 3 transposes (1024x1024 f16) in one dispatch; z selects pair
__global__ void tr3(const f16* __restrict__ i0, f16* __restrict__ o0,
                    const f16* __restrict__ i1, f16* __restrict__ o1,
                    const f16* __restrict__ i2, f16* __restrict__ o2) {
  __shared__ f16 tile[32][33];
  const f16* in = blockIdx.z == 0 ? i0 : blockIdx.z == 1 ? i1 : i2;
  f16* out = blockIdx.z == 0 ? o0 : blockIdx.z == 1 ? o1 : o2;
  int c0 = blockIdx.x * 32, r0 = blockIdx.y * 32;
  tile[threadIdx.y][threadIdx.x] =
      in[(long)(r0 + threadIdx.y) * 1024 + c0 + threadIdx.x];
  __syncthreads();
  out[(long)(c0 + threadIdx.y) * 1024 + r0 + threadIdx.x] =
      tile[threadIdx.x][threadIdx.y];
}

// bias_eff = br + bvec @ Wr, deterministic 2-stage (partials then reduce)
__global__ __launch_bounds__(256) void bias_part(const float* __restrict__ bq,
                                                 const float* __restrict__ bk,
                                                 const float* __restrict__ Wr,
                                                 float* __restrict__ part) {
  const float* bvec = blockIdx.z ? bk : bq;
  const int f = blockIdx.x * 256 + threadIdx.x;
  const int u0 = blockIdx.y * 64;
  float s = 0.f;
#pragma unroll 8
  for (int u = 0; u < 64; ++u)
    s = fmaf(bvec[u0 + u], Wr[(long)(u0 + u) * DIM + f], s);
  part[(blockIdx.z * 16 + blockIdx.y) * 1024 + f] = s;
}

__global__ __launch_bounds__(256) void bias_red(const float* __restrict__ br,
                                                const float* __restrict__ part,
                                                float* __restrict__ brq,
                                                float* __restrict__ brk) {
  const int f = blockIdx.x * 256 + threadIdx.x;
  float* outb = blockIdx.z ? brk : brq;
  float s = br[f];
#pragma unroll 16
  for (int j = 0; j < 16; ++j) s += part[(blockIdx.z * 16 + j) * 1024 + f];
  outb[f] = s;
}

__global__ void sentinel(float* out) { out[0] = 12345.0f; }

// ------------- 4-phase 256x256 GEMM template (8 waves, BK=64) --------------
// C = epi(A @ B^T), B row-major [N][ldb].  NT = K/64 tiles.  GX = gridDim.x.
// Per iteration (2 K-tiles): 4 phases, 32 MFMA/wave each.
// Stage ledger (per-thread issues, HT=2): invariant entering iter =
// {B(t+1):4}.  p0:+A(t+1); p1:+B(t+2),vmcnt(4); p2:+A(t+2); p3:+B(t+3),
// vmcnt(4).  Tail: vmcnt(0) at p1.
// EPI 6: probs = exp(S - rowmax_tile) f16 + mout/lout per (z,tn,row)
// EPI 1: f16 __cosf(v + aux[col])
// Both write through an LDS repack (stride 264) -> full-line f16x8 stores.
template <int EPI, int NT, bool WRAPA, int GX>
__global__ __launch_bounds__(512, 2) void g8p(
    const f16* __restrict__ A, const f16* __restrict__ B,
    void* __restrict__ Cv, const float* __restrict__ aux,
    float* __restrict__ mout, float* __restrict__ lout, long sA, long sB,
    long sC, int lda, int ldb, int ldc) {
  constexpr int BUF = 65536;  // 64KB per dbuf: A(32KB)+B(32KB)
  __shared__ __align__(16) char smem[256 * 264 * 2];  // >= 2*BUF; repack space
  __shared__ float red[EPI == 6 ? 4 : 1][EPI == 6 ? 256 : 1];
  // rect XCD swizzle over the 256 (tm,tn) blocks (XCD = linear id % 8)
  const int lin = blockIdx.x + blockIdx.y * GX;
  const int c = lin & 7, j = lin >> 3;
  int tm, tn;
  if constexpr (GX == 16) {  // 4tm x 8tn rect per XCD (6MB working set)
    tm = (c & 3) * 4 + (j & 3);
    tn = (c >> 2) * 8 + (j >> 2);
  } else {  // GX==4: tn column strip per XCD (B panel L2-resident)
    tn = c & 3;
    tm = (c >> 2) * 32 + j;
  }
  const int z = blockIdx.z;
  const int t = threadIdx.x, w = t >> 6, l = t & 63;
  const int l4 = l >> 4, l15 = l & 15;
  const int wm = w >> 2, wn = w & 3;  // 2 x 4 waves; wave out = 128 x 64
  f32x4 acc[8][4] = {};
  const f16* Az = A + (long)z * sA;
  const f16* Bz = B + (long)z * sB;

  // half-tile stage: ht 0=A0,1=A1,2=B0,3=B1 ; 1024 chunks, 2 per thread
  auto STAGE_HT = [&](int buf, int tt, int ht) {
    const bool isA = (ht < 2);
    const f16* src = isA ? Az : Bz;
    const int ld = isA ? lda : ldb;
    const int row0 = (isA ? tm : tn) * 256 + (ht & 1) * 128;
    char* base = smem + buf * BUF + (ht >> 1) * 32768 + (ht & 1) * 16384;
    int kk = tt * 64;
    if (WRAPA && isA) kk &= 1023;
#pragma unroll
    for (int jj = 0; jj < 2; ++jj) {
      const int cb = jj * 512 + w * 64;  // wave-uniform chunk base
      const int cc = cb + l;
      const int r = cc >> 3, s = cc & 7;
      async_copy16(base + cb * 16,
                   src + (long)(row0 + r) * ld + kk + (s ^ (r & 7)) * 8);
    }
  };

  // prologue: tile0 full + B halves of tile1;  vmcnt(4) -> tile0 resident
  STAGE_HT(0, 0, 0);
  STAGE_HT(0, 0, 1);
  STAGE_HT(0, 0, 2);
  STAGE_HT(0, 0, 3);
  STAGE_HT(1, 1, 2);
  STAGE_HT(1, 1, 3);
  asm volatile("s_waitcnt vmcnt(4)" ::: "memory");
  __builtin_amdgcn_s_barrier();

  for (int it = 0; it < NT / 2; ++it) {
    const int tt = 2 * it;
    const bool more = (tt + 2) < NT;  // == (tt+3) < NT for even NT
    // ---- tile tt from buf0: phases p0 (rows 0-3), p1 (rows 4-7) ----
    {
      const f16* Ab = (const f16*)(smem);
      const f16* Bb = Ab + 16384;  // +32KB
      f16x8 bfp[4][2];
#pragma unroll
      for (int jn = 0; jn < 4; ++jn)
#pragma unroll
        for (int ks = 0; ks < 2; ++ks) {
          const int rb = wn * 64 + jn * 16 + l15;
          const int p = ks * 4 + l4;
          bfp[jn][ks] = *(const f16x8*)&Bb[rb * 64 + (p ^ (rb & 7)) * 8];
        }
      {  // p0
        f16x8 af[4][2];
#pragma unroll
        for (int i2 = 0; i2 < 4; ++i2)
#pragma unroll
          for (int ks = 0; ks < 2; ++ks) {
            const int ra = wm * 128 + i2 * 16 + l15;
            const int p = ks * 4 + l4;
            af[i2][ks] = *(const f16x8*)&Ab[ra * 64 + (p ^ (ra & 7)) * 8];
          }
        STAGE_HT(1, tt + 1, 0);
        STAGE_HT(1, tt + 1, 1);
        __builtin_amdgcn_s_barrier();
        asm volatile("s_waitcnt lgkmcnt(0)" ::: "memory");
        __builtin_amdgcn_s_setprio(1);
#pragma unroll
        for (int i2 = 0; i2 < 4; ++i2)
#pragma unroll
          for (int jn = 0; jn < 4; ++jn)
#pragma unroll
            for (int ks = 0; ks < 2; ++ks)
              acc[i2][jn] = __builtin_amdgcn_mfma_f32_16x16x32_f16(
                  af[i2][ks], bfp[jn][ks], acc[i2][jn], 0, 0, 0);
        __builtin_amdgcn_s_setprio(0);
        __builtin_amdgcn_s_barrier();
      }
      {  // p1
        f16x8 af[4][2];
#pragma unroll
        for (int i2 = 0; i2 < 4; ++i2)
#pragma unroll
          for (int ks = 0; ks < 2; ++ks) {
            const int ra = wm * 128 + (4 + i2) * 16 + l15;
            const int p = ks * 4 + l4;
            af[i2][ks] = *(const f16x8*)&Ab[ra * 64 + (p ^ (ra & 7)) * 8];
          }
        if (more) {
          STAGE_HT(0, tt + 2, 2);
          STAGE_HT(0, tt + 2, 3);
          asm volatile("s_waitcnt vmcnt(4)" ::: "memory");
        } else {
          asm volatile("s_waitcnt vmcnt(0)" ::: "memory");
        }
        __builtin_amdgcn_s_barrier();
        asm volatile("s_waitcnt lgkmcnt(0)" ::: "memory");
        __builtin_amdgcn_s_setprio(1);
#pragma unroll
        for (int i2 = 0; i2 < 4; ++i2)
#pragma unroll
          for (int jn = 0; jn < 4; ++jn)
#pragma unroll
            for (int ks = 0; ks < 2; ++ks)
              acc[4 + i2][jn] = __builtin_amdgcn_mfma_f32_16x16x32_f16(
                  af[i2][ks], bfp[jn][ks], acc[4 + i2][jn], 0, 0, 0);
        __builtin_amdgcn_s_setprio(0);
        __builtin_amdgcn_s_barrier();
      }
    }
    // ---- tile tt+1 from buf1: phases p2 (rows 0-3), p3 (rows 4-7) ----
    {
      const f16* Ab = (const f16*)(smem + BUF);
      const f16* Bb = Ab + 16384;
      f16x8 bfp[4][2];
#pragma unroll
      for (int jn = 0; jn < 4; ++jn)
#pragma unroll
        for (int ks = 0; ks < 2; ++ks) {
          const int rb = wn * 64 + jn * 16 + l15;
          const int p = ks * 4 + l4;
          bfp[jn][ks] = *(const f16x8*)&Bb[rb * 64 + (p ^ (rb & 7)) * 8];
        }
      {  // p2
        f16x8 af[4][2];
#pragma unroll
        for (int i2 = 0; i2 < 4; ++i2)
#pragma unroll
          for (int ks = 0; ks < 2; ++ks) {
            const int ra = wm * 128 + i2 * 16 + l15;
            const int p = ks * 4 + l4;
            af[i2][ks] = *(const f16x8*)&Ab[ra * 64 + (p ^ (ra & 7)) * 8];
          }
        if (more) {
          STAGE_HT(0, tt + 2, 0);
          STAGE_HT(0, tt + 2, 1);
        }
        __builtin_amdgcn_s_barrier();
        asm volatile("s_waitcnt lgkmcnt(0)" ::: "memory");
        __builtin_amdgcn_s_setprio(1);
#pragma unroll
        for (int i2 = 0; i2 < 4; ++i2)
#pragma unroll
          for (int jn = 0; jn < 4; ++jn)
#pragma unroll
            for (int ks = 0; ks < 2; ++ks)
              acc[i2][jn] = __builtin_amdgcn_mfma_f32_16x16x32_f16(
                  af[i2][ks], bfp[jn][ks], acc[i2][jn], 0, 0, 0);
        __builtin_amdgcn_s_setprio(0);
        __builtin_amdgcn_s_barrier();
      }
      {  // p3
        f16x8 af[4][2];
#pragma unroll
        for (int i2 = 0; i2 < 4; ++i2)
#pragma unroll
          for (int ks = 0; ks < 2; ++ks) {
            const int ra = wm * 128 + (4 + i2) * 16 + l15;
            const int p = ks * 4 + l4;
            af[i2][ks] = *(const f16x8*)&Ab[ra * 64 + (p ^ (ra & 7)) * 8];
          }
        if (more) {
          STAGE_HT(1, tt + 3, 2);
          STAGE_HT(1, tt + 3, 3);
          asm volatile("s_waitcnt vmcnt(4)" ::: "memory");
        }
        __builtin_amdgcn_s_barrier();
        asm volatile("s_waitcnt lgkmcnt(0)" ::: "memory");
        __builtin_amdgcn_s_setprio(1);
#pragma unroll
        for (int i2 = 0; i2 < 4; ++i2)
#pragma unroll
          for (int jn = 0; jn < 4; ++jn)
#pragma unroll
            for (int ks = 0; ks < 2; ++ks)
              acc[4 + i2][jn] = __builtin_amdgcn_mfma_f32_16x16x32_f16(
                  af[i2][ks], bfp[jn][ks], acc[4 + i2][jn], 0, 0, 0);
        __builtin_amdgcn_s_setprio(0);
        __builtin_amdgcn_s_barrier();
      }
    }
  }

  if constexpr (EPI == 6) {
    // ---- tile-local softmax over this 256-col tile ----
    float mrow[32];
#pragma unroll
    for (int i = 0; i < 8; ++i)
#pragma unroll
      for (int r = 0; r < 4; ++r) {
        float v = fmaxf(fmaxf(acc[i][0][r], acc[i][1][r]),
                        fmaxf(acc[i][2][r], acc[i][3][r]));
        v = fmaxf(v, __shfl_xor(v, 1));
        v = fmaxf(v, __shfl_xor(v, 2));
        v = fmaxf(v, __shfl_xor(v, 4));
        v = fmaxf(v, __shfl_xor(v, 8));
        if (l15 == 0) red[wn][wm * 128 + i * 16 + l4 * 4 + r] = v;
      }
    __syncthreads();
#pragma unroll
    for (int i = 0; i < 8; ++i)
#pragma unroll
      for (int r = 0; r < 4; ++r) {
        const int rin = wm * 128 + i * 16 + l4 * 4 + r;
        mrow[i * 4 + r] = fmaxf(fmaxf(red[0][rin], red[1][rin]),
                                fmaxf(red[2][rin], red[3][rin]));
      }
    __syncthreads();
#pragma unroll
    for (int i = 0; i < 8; ++i)
#pragma unroll
      for (int r = 0; r < 4; ++r) {
        const float mn = mrow[i * 4 + r];
        float s = 0.f;
#pragma unroll
        for (int jn = 0; jn < 4; ++jn) {
          float e = __expf(acc[i][jn][r] - mn);
          acc[i][jn][r] = e;
          s += e;
        }
        s += __shfl_xor(s, 1);
        s += __shfl_xor(s, 2);
        s += __shfl_xor(s, 4);
        s += __shfl_xor(s, 8);
        if (l15 == 0) red[wn][wm * 128 + i * 16 + l4 * 4 + r] = s;
      }
    __syncthreads();
    if (wn == 0 && l15 == 0) {
#pragma unroll
      for (int i = 0; i < 8; ++i)
#pragma unroll
        for (int r = 0; r < 4; ++r) {
          const int rin = wm * 128 + i * 16 + l4 * 4 + r;
          const int gidx = z * 65536 + tn * 4096 + tm * 256 + rin;
          mout[gidx] = mrow[i * 4 + r];
          lout[gidx] = red[0][rin] + red[1][rin] + red[2][rin] + red[3][rin];
        }
    }
  }

  // ---- vectorized output: LDS repack (stride 264) -> f16x8 stores ----
  f16* rep = (f16*)smem;
#pragma unroll
  for (int i = 0; i < 8; ++i) {
    const int row0 = wm * 128 + i * 16 + l4 * 4;
#pragma unroll
    for (int jn = 0; jn < 4; ++jn) {
      const int col = wn * 64 + jn * 16 + l15;
#pragma unroll
      for (int r = 0; r < 4; ++r) {
        float v = acc[i][jn][r];
        f16 hv;
        if constexpr (EPI == 1)
          hv = (f16)__cosf(v + aux[tn * 256 + col]);
        else
          hv = (f16)v;
        rep[(row0 + r) * 264 + col] = hv;
      }
    }
  }
  __syncthreads();
#pragma unroll
  for (int k = 0; k < 16; ++k) {
    const int orow = k * 16 + (t >> 5);
    const int oc = (t & 31) * 8;
    *(f16x8*)&((f16*)Cv)[(long)z * sC + (long)(tm * 256 + orow) * ldc +
                         tn * 256 + oc] = *(const f16x8*)&rep[orow * 264 + oc];
  }
}

// ------------------------------- main GEMM --------------------------------
// C[M,N] = epilogue( A@B^T [+ A@Bl^T if DB] [+ Al@B^T if DA] )
// B stored row-major [N,K].  128x128 tile, 4 waves, 4x4 16x16x32 frags/wave.
// Double-buffered LDS, 2-phase pipeline, counted vmcnt (never 0 in loop).
// EPI: 0 f16 plain | 2 f16 v+aux[row] | 5 f32 plain
//      7 f32 plain, A-fragments scaled by scl[ktile256][arow]; scl computed
//        in the prologue from m/l stats (fused softmax merge, bit-identical
//        to the old merge_pair kernel).
template <int EPI, bool DA, bool DB, int BK>
__global__ __launch_bounds__(256) void gemm_bt(
    const f16* __restrict__ Ah, const f16* __restrict__ Al,
    const f16* __restrict__ Bh, const f16* __restrict__ Bl,
    void* __restrict__ Cv, const float* __restrict__ aux,
    const float* __restrict__ mlo, const float* __restrict__ llo, long sMl,
    int M, int N, int K, int lda, int ldb, int ldc, long sC, long sA, long sB,
    int sAux) {
  constexpr int NSTAGE = 2 + (DA ? 1 : 0) + (DB ? 1 : 0);
  constexpr int TILE = 128 * BK * 2;    // bytes per operand tile
  constexpr int CPR = BK / 8;           // 16B chunks per row
  constexpr int CH = 128 * CPR;         // chunks per operand tile
  constexpr int NL = NSTAGE * BK / 16;  // per-thread vmem issues per tile
  static_assert(NL == 6 || NL == 8, "vmcnt literal");
  constexpr int SCLB = (EPI == 7) ? 4096 : 0;
  __shared__ __align__(16) char smem[2 * NSTAGE * TILE + SCLB];

  const int z = blockIdx.z;
  const int tn = blockIdx.x, tm = blockIdx.y;
  const int t = threadIdx.x, w = t >> 6, l = t & 63;
  const int l4 = l >> 4, l15 = l & 15;
  const int wm = w & 1, wn = w >> 1;
  f32x4 acc[4][4] = {};

  const f16* Az = Ah + (long)z * sA;
  const f16* Bz = Bh + (long)z * sB;
  const f16* Alz = nullptr;
  const f16* Blz = nullptr;
  if constexpr (DA) Alz = Al + (long)z * sA;
  if constexpr (DB) Blz = Bl + (long)z * sB;
  f16* sclLds = (f16*)(smem + 2 * NSTAGE * TILE);

  auto swz = [](int r, int p) -> int {
    if constexpr (BK == 64) return p ^ (r & 7);
    else return p ^ ((r >> 1) & 3);
  };

  auto STAGE = [&](int buf, int kk) {
    char* base = smem + buf * (NSTAGE * TILE);
#pragma unroll
    for (int j = 0; j < CH / 256; ++j) {
      const int cb = j * 256 + w * 64;  // wave-uniform chunk base
      const int c = cb + l;
      const int r = c / CPR, pp = c % CPR;
      const int sc = swz(r, pp);
      const long ra = (long)(tm * 128 + r) * lda + kk + sc * 8;
      const long rb = (long)(tn * 128 + r) * ldb + kk + sc * 8;
      async_copy16(base + cb * 16, Az + ra);
      async_copy16(base + TILE + cb * 16, Bz + rb);
      if constexpr (DA) async_copy16(base + 2 * TILE + cb * 16, Alz + ra);
      if constexpr (DB)
        async_copy16(base + (2 + (DA ? 1 : 0)) * TILE + cb * 16, Blz + rb);
    }
  };

  // ---- prologue: stage tile 0; for EPI 7 compute scl from m/l stats ----
  STAGE(0, 0);
  if constexpr (EPI == 7) {
    if (t < 128) {
      const int row = tm * 128 + t;
      const float* mz = mlo + (long)z * sMl + row;
      const float* lz = llo + (long)z * sMl + row;
      float mv[16];
      float mg = -1e30f;
#pragma unroll 16
      for (int i = 0; i < 16; ++i) {
        mv[i] = mz[i * 4096];
        mg = fmaxf(mg, mv[i]);
      }
      float lsum = 0.f;
#pragma unroll 16
      for (int i = 0; i < 16; ++i) {
        const float a = __expf(mv[i] - mg);
        mv[i] = a;
        lsum += lz[i * 4096] * a;
      }
      const float li = 1.0f / lsum;
#pragma unroll 16
      for (int i = 0; i < 16; ++i) sclLds[i * 128 + t] = (f16)(mv[i] * li);
    }
  }
  asm volatile("s_waitcnt vmcnt(0)" ::: "memory");
  __syncthreads();

  const int nt = K / BK;
  int cur = 0;
  for (int tt = 0; tt < nt; ++tt) {
    const int kk = tt * BK;
    if (tt + 1 < nt) {
      STAGE(cur ^ 1, kk + BK);
      if constexpr (NL == 6)
        asm volatile("s_waitcnt vmcnt(6)" ::: "memory");
      else
        asm volatile("s_waitcnt vmcnt(8)" ::: "memory");
    } else {
      asm volatile("s_waitcnt vmcnt(0)" ::: "memory");
    }
    __syncthreads();

    const f16* As = (const f16*)(smem + cur * (NSTAGE * TILE));
    const f16* Bs = As + TILE / 2;
    const f16* Als = Bs + TILE / 2;
    const f16* Bls = Als + (DA ? TILE / 2 : 0);

    f16 sA4[4];
    if constexpr (EPI == 7) {
      const int tile = kk >> 8;  // 256-wide k-tiles
#pragma unroll
      for (int i = 0; i < 4; ++i)
        sA4[i] = sclLds[tile * 128 + wm * 64 + i * 16 + l15];
    }

#pragma unroll
    for (int ks = 0; ks < BK / 32; ++ks) {
      f16x8 af[4], bf[4];
#pragma unroll
      for (int i = 0; i < 4; ++i) {
        const int ra = wm * 64 + i * 16 + l15;
        const int rb = wn * 64 + i * 16 + l15;
        af[i] = *(const f16x8*)&As[ra * BK + swz(ra, ks * 4 + l4) * 8];
        bf[i] = *(const f16x8*)&Bs[rb * BK + swz(rb, ks * 4 + l4) * 8];
      }
      if constexpr (EPI == 7) {
#pragma unroll
        for (int i = 0; i < 4; ++i) af[i] = af[i] * sA4[i];
      }
#pragma unroll
      for (int i = 0; i < 4; ++i)
#pragma unroll
        for (int jn = 0; jn < 4; ++jn)
          acc[i][jn] = __builtin_amdgcn_mfma_f32_16x16x32_f16(af[i], bf[jn],
                                                              acc[i][jn], 0, 0, 0);
      if constexpr (DB) {
        f16x8 bl[4];
#pragma unroll
        for (int i = 0; i < 4; ++i) {
          const int rb = wn * 64 + i * 16 + l15;
          bl[i] = *(const f16x8*)&Bls[rb * BK + swz(rb, ks * 4 + l4) * 8];
        }
#pragma unroll
        for (int i = 0; i < 4; ++i)
#pragma unroll
          for (int jn = 0; jn < 4; ++jn)
            acc[i][jn] = __builtin_amdgcn_mfma_f32_16x16x32_f16(
                af[i], bl[jn], acc[i][jn], 0, 0, 0);
      }
      if constexpr (DA) {
        f16x8 al[4];
#pragma unroll
        for (int i = 0; i < 4; ++i) {
          const int ra = wm * 64 + i * 16 + l15;
          al[i] = *(const f16x8*)&Als[ra * BK + swz(ra, ks * 4 + l4) * 8];
        }
#pragma unroll
        for (int i = 0; i < 4; ++i)
#pragma unroll
          for (int jn = 0; jn < 4; ++jn)
            acc[i][jn] = __builtin_amdgcn_mfma_f32_16x16x32_f16(
                al[i], bf[jn], acc[i][jn], 0, 0, 0);
      }
    }
    __syncthreads();
    cur ^= 1;
  }

  const float* auxp = aux + (long)z * sAux;

  if constexpr (EPI == 0 || EPI == 2) {
    // ---- f16 output via LDS repack: [64][136] per half ----
    f16* rep = (f16*)smem;
#pragma unroll
    for (int hh = 0; hh < 2; ++hh) {
      __syncthreads();
#pragma unroll
      for (int ii = 0; ii < 2; ++ii) {
        const int i = hh * 2 + ii;
        const int lrow0 = wm * 32 + ii * 16 + l4 * 4;
#pragma unroll
        for (int jn = 0; jn < 4; ++jn) {
          const int col = wn * 64 + jn * 16 + l15;
#pragma unroll
          for (int r = 0; r < 4; ++r) {
            float v = acc[i][jn][r];
            f16 hv;
            if constexpr (EPI == 2)
              hv = (f16)(v + auxp[tm * 128 + wm * 64 + i * 16 + l4 * 4 + r]);
            else
              hv = (f16)v;
            rep[(lrow0 + r) * 136 + col] = hv;
          }
        }
      }
      __syncthreads();
#pragma unroll
      for (int pp = 0; pp < 4; ++pp) {
        const int lrow = pp * 16 + (t >> 4);
        const int grow = tm * 128 + (lrow >> 5) * 64 + hh * 32 + (lrow & 31);
        const int gcol = tn * 128 + (t & 15) * 8;
        *(f16x8*)&((f16*)Cv)[(long)z * sC + (long)grow * ldc + gcol] =
            *(const f16x8*)&rep[lrow * 136 + (t & 15) * 8];
      }
    }
  } else {
    // ---- f32 output via LDS repack: [32][132] per i-group ----
    float* rep = (float*)smem;
#pragma unroll
    for (int i = 0; i < 4; ++i) {
      __syncthreads();
      const int lrow0 = wm * 16 + l4 * 4;
#pragma unroll
      for (int jn = 0; jn < 4; ++jn) {
        const int col = wn * 64 + jn * 16 + l15;
#pragma unroll
        for (int r = 0; r < 4; ++r) rep[(lrow0 + r) * 132 + col] = acc[i][jn][r];
      }
      __syncthreads();
#pragma unroll
      for (int pp = 0; pp < 4; ++pp) {
        const int lrow = pp * 8 + (t >> 5);
        const int grow = tm * 128 + (lrow >> 4) * 64 + i * 16 + (lrow & 15);
        const int gcol = tn * 128 + (t & 31) * 4;
        *(float4*)&((float*)Cv)[(long)z * sC + (long)grow * ldc + gcol] =
            *(const float4*)&rep[lrow * 132 + (t & 31) * 4];
      }
    }
  }
}

// --------------------------------- driver ----------------------------------

extern "C" void kernel_launch(void* const* d_in, const int* in_sizes, int n_in,
                              void* d_out, int out_size, void* d_ws,
                              size_t ws_size, hipStream_t stream) {
  const float* query = (const float*)d_in[0];
  const float* value = (const float*)d_in[1];
  const float* Wq = (const float*)d_in[2];
  const float* bq = (const float*)d_in[3];
  const float* Wk = (const float*)d_in[4];
  const float* bk = (const float*)d_in[5];
  const float* Wv = (const float*)d_in[6];
  const float* bv = (const float*)d_in[7];
  const float* Wr = (const float*)d_in[8];
  const float* br = (const float*)d_in[9];
  float* out = (float*)d_out;

  if (ws_size < 169000000ull) {
    sentinel<<<1, 1, 0, stream>>>(out);
    return;
  }

  char* p = (char*)d_ws;
  auto alloc = [&](size_t bytes) {
    char* r = p;
    p += (bytes + 255) & ~(size_t)255;
    return r;
  };
  const size_t QV = 16777216ull;  // B*S*D elements
  const size_t WW = 1048576ull;   // 1024*1024 elements
  char* bufA = alloc(QV * 2);  // q16 -> Khat
  char* bufB = alloc(QV * 2);  // v16 -> probs z-even (32MB)
  char* bufC = alloc(QV * 2);  // Qhat
  char* bufD = alloc(QV * 2);  // VT
  f16* q16 = (f16*)bufA;
  f16* Khat = (f16*)bufA;
  f16* v16 = (f16*)bufB;
  f16* probs0 = (f16*)bufB;  // pair slot 0; slot 1 = weights region (+96MB)
  f16* Qhat = (f16*)bufC;
  f16* VT = (f16*)bufD;
  // weights region: 32 MB from Wq_h onward is reused as probs slot 1
  f16* Wq_h = (f16*)alloc(WW * 2);
  f16* Wq_l = (f16*)alloc(WW * 2);
  f16* Wk_h = (f16*)alloc(WW * 2);
  f16* Wk_l = (f16*)alloc(WW * 2);
  f16* Wr_h = (f16*)alloc(WW * 2);
  f16* Wr_l = (f16*)alloc(WW * 2);
  f16* Wv16 = (f16*)alloc(WW * 2);
  f16* WrT_h = (f16*)alloc(WW * 2);
  f16* WrT_l = (f16*)alloc(WW * 2);
  f16* WvT = (f16*)alloc(WW * 2);
  f16* pad16 = (f16*)alloc(WW * 12);  // keeps probs slot1 span >= 32MB
  f16* Wqr2h = (f16*)alloc(WW * 4);   // [2][1024][1024] plain f16
  float* brq = (float*)alloc(1024 * 4);
  float* brk = (float*)alloc(1024 * 4);
  float* bpart = (float*)alloc(2 * 16 * 1024 * 4);
  float* m_loc = (float*)alloc(2 * 16 * 4096 * 4);  // [z2][tn256][row]
  float* l_loc = (float*)alloc(2 * 16 * 4096 * 4);
  (void)pad16;
  const long PSTRIDE = 50331648;  // f16 elems between probs slot 0 and slot 1

  // fp32 -> fp16 conversions (fused dispatches)
  f2h_qv<<<32768, 256, 0, stream>>>(query, value, q16, v16);
  w_conv<<<dim3(1024, 4), 256, 0, stream>>>(Wq, Wk, Wr, Wv, Wq_h, Wq_l, Wk_h,
                                            Wk_l, Wr_h, Wr_l, Wv16);
  tr3<<<dim3(32, 32, 3), dim3(32, 32), 0, stream>>>(Wr_h, WrT_h, Wr_l, WrT_l,
                                                    Wv16, WvT);
  bias_part<<<dim3(4, 16, 2), 256, 0, stream>>>(bq, bk, Wr, bpart);
  bias_red<<<dim3(4, 1, 2), 256, 0, stream>>>(br, bpart, brq, brk);

  // W{q,k}rT = Wr^T @ W{q,k}^T (Ah@Bh + Ah@Bl + Al@Bh), f16 out directly
  gemm_bt<0, true, true, 32><<<dim3(8, 8, 2), 256, 0, stream>>>(
      WrT_h, WrT_l, Wq_h, Wq_l, Wqr2h, nullptr, nullptr, nullptr, 0, 1024,
      1024, 1024, 1024, 1024, 1024, 1048576, 0, 2097152, 0);

  // Qhat = cos(query @ Wqr + brq)   [bufC]
  g8p<1, 16, false, 4><<<dim3(4, 64, 1), 512, 0, stream>>>(
      q16, Wqr2h, Qhat, brq, nullptr, nullptr, 0, 0, 0, 1024, 1024, 1024);
  // Khat = cos(value @ Wkr + brk)   [bufA — q16 dead from here]
  g8p<1, 16, false, 4><<<dim3(4, 64, 1), 512, 0, stream>>>(
      v16, Wqr2h + 1048576, Khat, brk, nullptr, nullptr, 0, 0, 0, 1024, 1024,
      1024);
  // VT[u][s] = (value @ Wv + bv)^T = Wv^T @ value^T  (row bias bv)  [bufD]
  gemm_bt<2, false, false, 64><<<dim3(128, 8, 1), 256, 0, stream>>>(
      WvT, nullptr, v16, nullptr, VT, bv, nullptr, nullptr, 0, 1024, 16384,
      1024, 1024, 1024, 16384, 0, 0, 0, 0);

  // per batch-pair: probs = exp(S - m_tile) + stats; PV (merge+scale fused)
  for (int zb = 0; zb < NB; zb += 2) {
    g8p<6, 16, false, 16><<<dim3(16, 16, 2), 512, 0, stream>>>(
        Qhat + (long)zb * 4194304, Khat + (long)zb * 4194304, probs0, nullptr,
        m_loc, l_loc, 4194304, 4194304, PSTRIDE, 1024, 1024, 4096);
    gemm_bt<7, false, false, 64><<<dim3(8, 32, 2), 256, 0, stream>>>(
        probs0, nullptr, VT + (long)zb * 4096, nullptr, out + (long)zb * 4194304,
        nullptr, m_loc, l_loc, 65536, 4096, 1024, 4096, 4096, 16384, 1024,
        4194304, PSTRIDE, 4096, 0);
  }
}